// Round 9
// baseline (5260.716 us; speedup 1.0000x reference)
//
#include <hip/hip_runtime.h>
#include <hip/hip_bf16.h>
#include <math.h>

// AoA Reader v7: 4-wave GRU, 1 wave/SIMD (512-reg budget), ALL 24 weight tiles
// register-resident, LDS holds only h (16 KB). Lane-major gx packing, bias folding.
// V=50000 E=384 H=256 B=32 D=1024 Q=64 C=10.
#define BATCH 32
#define DLEN 1024
#define QLEN 64
#define EMB 384
#define HID 256
#define G3 768   // 3*H
#define NCAND 10

typedef __attribute__((ext_vector_type(8))) short bf16x8;
typedef __attribute__((ext_vector_type(4))) float f32x4;
#define MFMA16 __builtin_amdgcn_mfma_f32_16x16x32_bf16

__device__ __forceinline__ float bf2f(ushort u) {
    union { float f; unsigned v; } x; x.v = ((unsigned)u) << 16; return x.f;
}
__device__ __forceinline__ ushort f2bf(float f) {
    union { float f; unsigned v; } x; x.f = f;
    unsigned r = x.v + 0x7FFF + ((x.v >> 16) & 1);
    return (ushort)(r >> 16);
}
__device__ __forceinline__ float sigf(float x) {
    return __builtin_amdgcn_rcpf(1.f + __expf(-x));
}
__device__ __forceinline__ float tanhf_(float x) {
    return 1.f - 2.f * __builtin_amdgcn_rcpf(1.f + __expf(2.f * x));
}

// ---------------- bias_eff[dir][768]: b_ih + (b_hh for r,z gates only) ----------------
__global__ __launch_bounds__(256) void k_bias(const float* __restrict__ bihf, const float* __restrict__ bhhf,
                                              const float* __restrict__ bihb, const float* __restrict__ bhhb,
                                              float* __restrict__ be) {
    int n = blockIdx.x * 256 + threadIdx.x;
    if (n >= 1536) return;
    int dir = n / G3, c = n - dir * G3;
    const float* bih = dir ? bihb : bihf;
    const float* bhh = dir ? bhhb : bhhf;
    be[n] = bih[c] + (c < 512 ? bhh[c] : 0.f);
}

// ---------------- prep: w_hh (768x256 f32) -> bf16 MFMA B-fragment order ----------------
// layout: [dir][wave(4)][tile(12)][ks(8)][lane(64)][e(8)] bf16; per dir 196608 elems.
// tile = gi*4 + jt; col g = gi*256 + wv*64 + jt*16 + (lane&15); k = ks*32 + (lane>>4)*8 + e.
__global__ __launch_bounds__(256) void k_prep(const float* __restrict__ whf, const float* __restrict__ whb,
                                              ushort* __restrict__ wprep) {
    int idx = blockIdx.x * 256 + threadIdx.x;   // < 393216
    int dir = idx / 196608;
    int r = idx - dir * 196608;
    int wv = r / 49152;   int r2 = r - wv * 49152;
    int tile = r2 / 4096; int r3 = r2 - tile * 4096;
    int ks = r3 / 512;    int r4 = r3 - ks * 512;
    int lane = r4 >> 3;   int e = r4 & 7;
    int gi = tile >> 2, jt = tile & 3;
    int g = gi * 256 + wv * 64 + jt * 16 + (lane & 15);
    int k = ks * 32 + (lane >> 4) * 8 + e;
    const float* w = dir ? whb : whf;
    wprep[idx] = f2bf(w[g * 256 + k]);
}

// ---------------- gx GEMM with gather (fp32 compute, bf16 LANE-MAJOR permuted out) ----------------
// out[m][pidx], pidx = wv*192 + l15*12 + gi*4 + jt for gate-col n = gi*256+wv*64+jt*16+l15.
__global__ __launch_bounds__(256) void k_gx(const int* __restrict__ tokens,
                                            const float* __restrict__ emb,
                                            const float* __restrict__ w0, const float* __restrict__ bias0, ushort* __restrict__ out0,
                                            const float* __restrict__ w1, const float* __restrict__ bias1, ushort* __restrict__ out1) {
    __shared__ float As[16][68];
    __shared__ float Bs[16][68];
    const float* w   = blockIdx.z ? w1 : w0;
    const float* bia = blockIdx.z ? bias1 : bias0;
    ushort* out      = blockIdx.z ? out1 : out0;
    int tid = threadIdx.x;
    int n0 = blockIdx.x * 64;
    long m0 = (long)blockIdx.y * 64;
    int ml = tid >> 2, el = (tid & 3) << 2;
    long tok = tokens[m0 + ml];
    const float* arow = emb + tok * EMB;
    const float* brow = w + (long)(n0 + ml) * EMB;
    int ty = tid >> 4, tx = tid & 15;
    float acc[4][4] = {};
    for (int kt = 0; kt < EMB; kt += 16) {
        float4 av = *(const float4*)(arow + kt + el);
        float4 bv = *(const float4*)(brow + kt + el);
        __syncthreads();
        As[el + 0][ml] = av.x; As[el + 1][ml] = av.y; As[el + 2][ml] = av.z; As[el + 3][ml] = av.w;
        Bs[el + 0][ml] = bv.x; Bs[el + 1][ml] = bv.y; Bs[el + 2][ml] = bv.z; Bs[el + 3][ml] = bv.w;
        __syncthreads();
#pragma unroll
        for (int k = 0; k < 16; ++k) {
            float4 a4 = *(const float4*)&As[k][ty << 2];
            float4 b4 = *(const float4*)&Bs[k][tx << 2];
            float a[4] = {a4.x, a4.y, a4.z, a4.w};
            float bb[4] = {b4.x, b4.y, b4.z, b4.w};
#pragma unroll
            for (int i = 0; i < 4; ++i)
#pragma unroll
                for (int j = 0; j < 4; ++j)
                    acc[i][j] = fmaf(a[i], bb[j], acc[i][j]);
        }
    }
#pragma unroll
    for (int i = 0; i < 4; ++i) {
        long m = m0 + (ty << 2) + i;
        ushort* orow = out + m * G3;
#pragma unroll
        for (int jj = 0; jj < 4; ++jj) {
            int n = n0 + (tx << 2) + jj;
            int gi = n >> 8, wvv = (n >> 6) & 3, jt = (n >> 4) & 3, fl = n & 15;
            orow[wvv * 192 + fl * 12 + gi * 4 + jt] = f2bf(acc[i][jj] + bia[n]);
        }
    }
}

// ---------------- MFMA GRU: grid 8 = (batch-half, dir, seq). 256 thr = 4 waves, 1 wave/SIMD. ----------------
// Wave wv owns 64 hidden units (12 col-tiles, ALL in registers: 384 regs).
// LDS: h only (16 KB dbuf). Plain __syncthreads per step.
__global__ __attribute__((amdgpu_flat_work_group_size(256, 256), amdgpu_waves_per_eu(1, 1)))
void k_gru6(
    const ushort* __restrict__ gxd_f, const ushort* __restrict__ gxd_b,
    const ushort* __restrict__ gxq_f, const ushort* __restrict__ gxq_b,
    const ushort* __restrict__ wprep,
    const float* __restrict__ bhh_f, const float* __restrict__ bhh_b,
    const int* __restrict__ dlens, const int* __restrict__ qlens,
    float* __restrict__ dosb, float* __restrict__ qosb)
{
    int wg = blockIdx.x;
    int bhalf = wg & 1;
    int dir = (wg >> 1) & 1;
    int seq = wg >> 2;                   // 0=doc, 1=query
    int T = seq ? QLEN : DLEN;
    const ushort* gx = seq ? (dir ? gxq_b : gxq_f) : (dir ? gxd_b : gxd_f);
    const float* bhh = dir ? bhh_b : bhh_f;
    const int* lens = seq ? qlens : dlens;
    float* outbase = (seq ? qosb : dosb) + dir * HID;
    int boff = bhalf * 16;

    int tid = threadIdx.x;
    int wv = tid >> 6;
    int lane = tid & 63;
    int l15 = lane & 15;
    int lhi = lane >> 4;                 // 0..3
    int jw = wv * 64;

    __shared__ ushort hbuf[2][4096];     // 16 KB bf16 h, swizzled, dbuf

    // ---- ALL 12 weight tiles in registers (384 VGPR/AGPR) ----
    const ushort* wp = wprep + (size_t)dir * 196608;
    bf16x8 B[12][8];
#pragma unroll
    for (int tl = 0; tl < 12; ++tl)
#pragma unroll
        for (int ks = 0; ks < 8; ++ks)
            B[tl][ks] = *(const bf16x8*)(wp + (((size_t)(wv * 12 + tl) * 8 + ks) * 64 + lane) * 8);

    float bhn[4];
#pragma unroll
    for (int jt = 0; jt < 4; ++jt) bhn[jt] = bhh[512 + jw + jt * 16 + l15];
    int len[4];
#pragma unroll
    for (int i = 0; i < 4; ++i) len[i] = lens[boff + lhi * 4 + i];
    float hp[4][4] = {};                 // [i][jt]

    // t-invariant addresses
    int a_addr[8];
#pragma unroll
    for (int ks = 0; ks < 8; ++ks)
        a_addr[ks] = l15 * 512 + (((ks * 4 + lhi) ^ (l15 & 7)) * 16);
    int wofs[4][4];
#pragma unroll
    for (int i = 0; i < 4; ++i)
#pragma unroll
        for (int jt = 0; jt < 4; ++jt) {
            int row = lhi * 4 + i, j = jw + jt * 16 + l15;
            wofs[i][jt] = (row * 256 + (((j >> 3) ^ (row & 7)) * 8) + (j & 7)) * 2;
        }
    int lbg[4], lbo[4];
#pragma unroll
    for (int i = 0; i < 4; ++i) {
        int b = boff + lhi * 4 + i;
        lbg[i] = b * T * 1536 + wv * 384 + l15 * 24;   // gx byte base (lane-major 12 ushorts)
        lbo[i] = b * T * 2048 + (jw + l15) * 4;        // out byte base
    }

    for (int x = tid; x < 4096; x += 256) hbuf[0][x] = 0;
    __syncthreads();

#define GSTEP(RB, WB, TT)                                                          \
    {                                                                              \
        int voffo[4];                                                              \
        ushort4 gxu[4][3];                                                         \
        _Pragma("unroll")                                                          \
        for (int i = 0; i < 4; ++i) {                                              \
            int p_ = (TT);                                                         \
            if (dir) p_ = ((TT) < len[i]) ? (len[i] - 1 - (TT)) : (TT);            \
            const char* g = (const char*)gx + (lbg[i] + p_ * 1536);                \
            voffo[i] = lbo[i] + p_ * 2048;                                         \
            gxu[i][0] = *(const ushort4*)(g);                                      \
            gxu[i][1] = *(const ushort4*)(g + 8);                                  \
            gxu[i][2] = *(const ushort4*)(g + 16);                                 \
        }                                                                          \
        f32x4 acc[12];                                                             \
        _Pragma("unroll")                                                          \
        for (int tl = 0; tl < 8; ++tl) acc[tl] = (f32x4){0.f, 0.f, 0.f, 0.f};      \
        _Pragma("unroll")                                                          \
        for (int jt = 0; jt < 4; ++jt)                                             \
            acc[8 + jt] = (f32x4){bhn[jt], bhn[jt], bhn[jt], bhn[jt]};             \
        _Pragma("unroll")                                                          \
        for (int ks = 0; ks < 8; ++ks) {                                           \
            bf16x8 a = *(const bf16x8*)((const char*)&hbuf[RB][0] + a_addr[ks]);   \
            _Pragma("unroll")                                                      \
            for (int tl = 0; tl < 12; ++tl)                                        \
                acc[tl] = MFMA16(a, B[tl][ks], acc[tl], 0, 0, 0);                  \
        }                                                                          \
        char* hb = (char*)&hbuf[WB][0];                                            \
        _Pragma("unroll")                                                          \
        for (int i = 0; i < 4; ++i) {                                              \
            float* o = (float*)((char*)outbase + voffo[i]);                        \
            float hv[4];                                                           \
            _Pragma("unroll")                                                      \
            for (int jt = 0; jt < 4; ++jt) {                                       \
                float rx = bf2f(((const ushort*)&gxu[i][0])[jt]);                  \
                float zx = bf2f(((const ushort*)&gxu[i][1])[jt]);                  \
                float nx = bf2f(((const ushort*)&gxu[i][2])[jt]);                  \
                float r = sigf(rx + acc[jt][i]);                                   \
                float z = sigf(zx + acc[4 + jt][i]);                               \
                float nn = tanhf_(nx + r * acc[8 + jt][i]);                        \
                float h = (1.f - z) * nn + z * hp[i][jt];                          \
                hp[i][jt] = h; hv[jt] = h;                                         \
                o[jt * 16] = h;                                                    \
            }                                                                      \
            unsigned pk0, pk1;                                                     \
            asm("v_cvt_pk_bf16_f32 %0, %1, %2" : "=v"(pk0) : "v"(hv[0]), "v"(hv[1])); \
            asm("v_cvt_pk_bf16_f32 %0, %1, %2" : "=v"(pk1) : "v"(hv[2]), "v"(hv[3])); \
            *(ushort*)(hb + wofs[i][0]) = (ushort)(pk0 & 0xffffu);                 \
            *(ushort*)(hb + wofs[i][1]) = (ushort)(pk0 >> 16);                     \
            *(ushort*)(hb + wofs[i][2]) = (ushort)(pk1 & 0xffffu);                 \
            *(ushort*)(hb + wofs[i][3]) = (ushort)(pk1 >> 16);                     \
        }                                                                          \
        __syncthreads();                                                           \
    }

    for (int t = 0; t < T; t += 2) {
        GSTEP(0, 1, t)
        GSTEP(1, 0, t + 1)
    }
#undef GSTEP
}

// ---------------- M[b,d,q] = dos[b,d,:] . qos[b,q,:]  (K=512) ----------------
__global__ __launch_bounds__(256) void k_mgemm(const float* __restrict__ dos, const float* __restrict__ qos,
                                               float* __restrict__ Mm) {
    __shared__ float As[16][68];
    __shared__ float Bs[16][68];
    int tid = threadIdx.x;
    int b = blockIdx.y;
    long m0 = (long)blockIdx.x * 64;
    int ml = tid >> 2, el = (tid & 3) << 2;
    const float* arow = dos + ((long)b * DLEN + m0 + ml) * (2 * HID);
    const float* brow = qos + ((long)b * QLEN + ml) * (2 * HID);
    int ty = tid >> 4, tx = tid & 15;
    float acc[4][4] = {};
    for (int kt = 0; kt < 2 * HID; kt += 16) {
        float4 av = *(const float4*)(arow + kt + el);
        float4 bv = *(const float4*)(brow + kt + el);
        __syncthreads();
        As[el + 0][ml] = av.x; As[el + 1][ml] = av.y; As[el + 2][ml] = av.z; As[el + 3][ml] = av.w;
        Bs[el + 0][ml] = bv.x; Bs[el + 1][ml] = bv.y; Bs[el + 2][ml] = bv.z; Bs[el + 3][ml] = bv.w;
        __syncthreads();
#pragma unroll
        for (int k = 0; k < 16; ++k) {
            float4 a4 = *(const float4*)&As[k][ty << 2];
            float4 b4 = *(const float4*)&Bs[k][tx << 2];
            float a[4] = {a4.x, a4.y, a4.z, a4.w};
            float bb[4] = {b4.x, b4.y, b4.z, b4.w};
#pragma unroll
            for (int i = 0; i < 4; ++i)
#pragma unroll
                for (int j = 0; j < 4; ++j)
                    acc[i][j] = fmaf(a[i], bb[j], acc[i][j]);
        }
    }
#pragma unroll
    for (int i = 0; i < 4; ++i) {
        long m = m0 + (ty << 2) + i;
#pragma unroll
        for (int j = 0; j < 4; ++j) {
            int n = (tx << 2) + j;
            Mm[((long)b * DLEN + m) * QLEN + n] = acc[i][j];
        }
    }
}

// ---------------- avg_beta ----------------
__global__ __launch_bounds__(256) void k_avgbeta(const float* __restrict__ Mm, const float* __restrict__ dmask,
                                                 const float* __restrict__ qmask, const int* __restrict__ dlens,
                                                 float* __restrict__ avgb) {
    int b = blockIdx.x, tid = threadIdx.x;
    int lane = tid & 63, wid = tid >> 6;
    float qm = qmask[b * QLEN + lane];
    float acc = 0.f;
    for (int d = wid; d < DLEN; d += 4) {
        float x = Mm[((long)b * DLEN + d) * QLEN + lane];
        float mx = x;
#pragma unroll
        for (int o = 32; o; o >>= 1) mx = fmaxf(mx, __shfl_xor(mx, o));
        float e = expf(x - mx) * dmask[b * DLEN + d] * qm;
        float sm = e;
#pragma unroll
        for (int o = 32; o; o >>= 1) sm += __shfl_xor(sm, o);
        acc += e / (sm + 1e-12f);
    }
    __shared__ float red[4][QLEN];
    red[wid][lane] = acc;
    __syncthreads();
    if (tid < QLEN) {
        float tot = red[0][tid] + red[1][tid] + red[2][tid] + red[3][tid];
        avgb[b * QLEN + tid] = tot / (float)dlens[b];
    }
}

// ---------------- column stats over d ----------------
__global__ __launch_bounds__(256) void k_colstats(const float* __restrict__ Mm, const float* __restrict__ dmask,
                                                  float* __restrict__ mx, float* __restrict__ cs) {
    int b = blockIdx.x, tid = threadIdx.x;
    int q = tid & 63, dg = tid >> 6;
    float m = -INFINITY, ssum = 0.f;
    for (int d = dg; d < DLEN; d += 4) {
        float x = Mm[((long)b * DLEN + d) * QLEN + q];
        float dm = dmask[b * DLEN + d];
        float mn = fmaxf(m, x);
        ssum = ssum * expf(m - mn) + expf(x - mn) * dm;
        m = mn;
    }
    __shared__ float mS[4][QLEN], sS[4][QLEN];
    mS[dg][q] = m; sS[dg][q] = ssum;
    __syncthreads();
    if (tid < QLEN) {
        float M0 = fmaxf(fmaxf(mS[0][tid], mS[1][tid]), fmaxf(mS[2][tid], mS[3][tid]));
        float S = 0.f;
#pragma unroll
        for (int i = 0; i < 4; ++i) S += sS[i][tid] * expf(mS[i][tid] - M0);
        mx[b * QLEN + tid] = M0;
        cs[b * QLEN + tid] = S;
    }
}

// ---------------- s[b,d] ----------------
__global__ __launch_bounds__(256) void k_s(const float* __restrict__ Mm, const float* __restrict__ mxv, const float* __restrict__ cs,
                                           const float* __restrict__ avgb, const float* __restrict__ qmask, const float* __restrict__ dmask,
                                           float* __restrict__ s) {
    int b = blockIdx.y, tid = threadIdx.x;
    __shared__ float wq[QLEN], mxs[QLEN];
    if (tid < QLEN) {
        float part = cs[b * QLEN + tid];
        wq[tid] = (qmask[b * QLEN + tid] > 0.f) ? (avgb[b * QLEN + tid] / (part + 1e-12f)) : 0.f;
        mxs[tid] = mxv[b * QLEN + tid];
    }
    __syncthreads();
    long d = (long)blockIdx.x * 256 + tid;
    const float* row = Mm + ((long)b * DLEN + d) * QLEN;
    float acc = 0.f;
#pragma unroll
    for (int q = 0; q < QLEN; q += 4) {
        float4 v = *(const float4*)(row + q);
        acc += expf(v.x - mxs[q + 0]) * wq[q + 0];
        acc += expf(v.y - mxs[q + 1]) * wq[q + 1];
        acc += expf(v.z - mxs[q + 2]) * wq[q + 2];
        acc += expf(v.w - mxs[q + 3]) * wq[q + 3];
    }
    s[b * DLEN + d] = dmask[b * DLEN + d] * acc;
}

// ---------------- final ----------------
__global__ __launch_bounds__(256) void k_final(const float* __restrict__ s, const int* __restrict__ doc,
                                               const int* __restrict__ cand, const int* __restrict__ ans,
                                               float* __restrict__ out) {
    int b = blockIdx.x, tid = threadIdx.x;
    __shared__ int lc[NCAND];
    __shared__ int la;
    __shared__ float red[4][NCAND + 1];
    if (tid < NCAND) lc[tid] = cand[b * NCAND + tid];
    if (tid == NCAND) la = ans[b];
    __syncthreads();
    float accs[NCAND + 1] = {};
    for (int d = tid; d < DLEN; d += 256) {
        int tk = doc[b * DLEN + d];
        float sv = s[b * DLEN + d];
#pragma unroll
        for (int c = 0; c < NCAND; ++c)
            if (tk == lc[c]) accs[c] += sv;
        if (tk == la) accs[NCAND] += sv;
    }
    int lane = tid & 63, wid = tid >> 6;
#pragma unroll
    for (int i = 0; i <= NCAND; ++i) {
        float v = accs[i];
#pragma unroll
        for (int o = 32; o; o >>= 1) v += __shfl_xor(v, o);
        if (lane == 0) red[wid][i] = v;
    }
    __syncthreads();
    if (tid == 0) {
        float cp[NCAND + 1];
#pragma unroll
        for (int i = 0; i <= NCAND; ++i) cp[i] = red[0][i] + red[1][i] + red[2][i] + red[3][i];
        int loc = 0; float best = cp[0];
#pragma unroll
        for (int c = 1; c < NCAND; ++c) if (cp[c] > best) { best = cp[c]; loc = c; }
        out[b] = (float)lc[loc];
        out[BATCH + b] = (float)loc;
        out[2 * BATCH + b] = cp[NCAND];
    }
}

__global__ void k_zero_out(float* out, int n) {
    int i = blockIdx.x * 256 + threadIdx.x;
    if (i < n) out[i] = 0.f;
}

extern "C" void kernel_launch(void* const* d_in, const int* in_sizes, int n_in,
                              void* d_out, int out_size, void* d_ws, size_t ws_size,
                              hipStream_t stream) {
    const int*   docs_input   = (const int*)d_in[0];
    const int*   docs_len     = (const int*)d_in[1];
    const float* doc_mask     = (const float*)d_in[2];
    const int*   querys_input = (const int*)d_in[3];
    const int*   querys_len   = (const int*)d_in[4];
    const float* query_mask   = (const float*)d_in[5];
    const int*   candidates   = (const int*)d_in[6];
    const int*   answers      = (const int*)d_in[7];
    const float* embedding    = (const float*)d_in[8];
    const float* w_ih_f = (const float*)d_in[9];
    const float* w_hh_f = (const float*)d_in[10];
    const float* b_ih_f = (const float*)d_in[11];
    const float* b_hh_f = (const float*)d_in[12];
    const float* w_ih_b = (const float*)d_in[13];
    const float* w_hh_b = (const float*)d_in[14];
    const float* b_ih_b = (const float*)d_in[15];
    const float* b_hh_b = (const float*)d_in[16];

    char* ws = (char*)d_ws;
    size_t off = 0;
    auto alloc = [&](size_t bytes) { size_t o = off; off = (off + bytes + 255) & ~(size_t)255; return o; };
    ushort* wprep = (ushort*)(ws + alloc((size_t)2 * 196608 * 2));
    float*  beff  = (float*)(ws + alloc((size_t)2 * G3 * 4));
    ushort* gxq_f = (ushort*)(ws + alloc((size_t)BATCH * QLEN * G3 * 2));
    ushort* gxq_b = (ushort*)(ws + alloc((size_t)BATCH * QLEN * G3 * 2));
    ushort* gxd_f = (ushort*)(ws + alloc((size_t)BATCH * DLEN * G3 * 2));
    ushort* gxd_b = (ushort*)(ws + alloc((size_t)BATCH * DLEN * G3 * 2));
    float* dosb  = (float*)(ws + alloc((size_t)BATCH * DLEN * 2 * HID * 4));
    float* qosb  = (float*)(ws + alloc((size_t)BATCH * QLEN * 2 * HID * 4));
    float* Mbuf  = (float*)(ws + alloc((size_t)BATCH * DLEN * QLEN * 4));
    float* avgb  = (float*)(ws + alloc((size_t)BATCH * QLEN * 4));
    float* mxb   = (float*)(ws + alloc((size_t)BATCH * QLEN * 4));
    float* csb   = (float*)(ws + alloc((size_t)BATCH * QLEN * 4));
    float* sbuf  = (float*)(ws + alloc((size_t)BATCH * DLEN * 4));

    if (ws_size < off) {
        k_zero_out<<<1, 256, 0, stream>>>((float*)d_out, out_size);
        return;
    }

    // effective biases (b_ih + b_hh for r/z) and weight fragments
    k_bias<<<6, 256, 0, stream>>>(b_ih_f, b_hh_f, b_ih_b, b_hh_b, beff);
    k_prep<<<1536, 256, 0, stream>>>(w_hh_f, w_hh_b, wprep);

    // gx for queries and docs, both directions (bf16 lane-major permuted out)
    k_gx<<<dim3(12, (BATCH * QLEN) / 64, 2), 256, 0, stream>>>(querys_input, embedding,
        w_ih_f, beff, gxq_f, w_ih_b, beff + G3, gxq_b);
    k_gx<<<dim3(12, (BATCH * DLEN) / 64, 2), 256, 0, stream>>>(docs_input, embedding,
        w_ih_f, beff, gxd_f, w_ih_b, beff + G3, gxd_b);

    // all four BiGRU scans (doc/query x fwd/bwd), batch split in halves of 16
    k_gru6<<<8, 256, 0, stream>>>(gxd_f, gxd_b, gxq_f, gxq_b, wprep,
                                  b_hh_f, b_hh_b, docs_len, querys_len, dosb, qosb);

    // attention-over-attention
    k_mgemm<<<dim3(DLEN / 64, BATCH), 256, 0, stream>>>(dosb, qosb, Mbuf);
    k_avgbeta<<<BATCH, 256, 0, stream>>>(Mbuf, doc_mask, query_mask, docs_len, avgb);
    k_colstats<<<BATCH, 256, 0, stream>>>(Mbuf, doc_mask, mxb, csb);
    k_s<<<dim3(DLEN / 256, BATCH), 256, 0, stream>>>(Mbuf, mxb, csb, avgb, query_mask, doc_mask, sbuf);
    k_final<<<BATCH, 256, 0, stream>>>(sbuf, docs_input, candidates, answers, (float*)d_out);
}

// Round 10
// 2961.111 us; speedup vs baseline: 1.7766x; 1.7766x over previous
//
#include <hip/hip_runtime.h>
#include <hip/hip_bf16.h>
#include <math.h>

// AoA Reader v8: r6 base (512thr, 2 waves/SIMD, 4 reg + 2 LDS weight tiles, plain
// __syncthreads) + deferred h-store + lane-major 16B gx loads + bias folding.
// V=50000 E=384 H=256 B=32 D=1024 Q=64 C=10.
#define BATCH 32
#define DLEN 1024
#define QLEN 64
#define EMB 384
#define HID 256
#define G3 768   // 3*H
#define NCAND 10

typedef __attribute__((ext_vector_type(8))) short bf16x8;
typedef __attribute__((ext_vector_type(8))) unsigned short u16x8;
typedef __attribute__((ext_vector_type(4))) float f32x4;
#define MFMA16 __builtin_amdgcn_mfma_f32_16x16x32_bf16

__device__ __forceinline__ float bf2f(ushort u) {
    union { float f; unsigned v; } x; x.v = ((unsigned)u) << 16; return x.f;
}
__device__ __forceinline__ ushort f2bf(float f) {
    union { float f; unsigned v; } x; x.f = f;
    unsigned r = x.v + 0x7FFF + ((x.v >> 16) & 1);
    return (ushort)(r >> 16);
}
__device__ __forceinline__ float sigf(float x) {
    return __builtin_amdgcn_rcpf(1.f + __expf(-x));
}
__device__ __forceinline__ float tanhf_(float x) {
    return 1.f - 2.f * __builtin_amdgcn_rcpf(1.f + __expf(2.f * x));
}

// ---------------- bias_eff[dir][768]: b_ih + (b_hh for r,z gates only) ----------------
__global__ __launch_bounds__(256) void k_bias(const float* __restrict__ bihf, const float* __restrict__ bhhf,
                                              const float* __restrict__ bihb, const float* __restrict__ bhhb,
                                              float* __restrict__ be) {
    int n = blockIdx.x * 256 + threadIdx.x;
    if (n >= 1536) return;
    int dir = n / G3, c = n - dir * G3;
    const float* bih = dir ? bihb : bihf;
    const float* bhh = dir ? bhhb : bhhf;
    be[n] = bih[c] + (c < 512 ? bhh[c] : 0.f);
}

// ---------------- prep: w_hh (768x256 f32) -> bf16 MFMA B-fragment order ----------------
// layout: [dir][wave(8)][tile(6)][ks(8)][lane(64)][e(8)] bf16; per dir 196608 elems.
__global__ __launch_bounds__(256) void k_prep(const float* __restrict__ whf, const float* __restrict__ whb,
                                              ushort* __restrict__ wprep) {
    int idx = blockIdx.x * 256 + threadIdx.x;   // < 393216
    int dir = idx / 196608;
    int r = idx - dir * 196608;
    int wv = r / 24576;  int r2 = r - wv * 24576;
    int tile = r2 / 4096; int r3 = r2 - tile * 4096;
    int ks = r3 / 512;    int r4 = r3 - ks * 512;
    int lane = r4 >> 3;   int e = r4 & 7;
    int g = (tile >> 1) * 256 + wv * 32 + (tile & 1) * 16 + (lane & 15);
    int k = ks * 32 + (lane >> 4) * 8 + e;
    const float* w = dir ? whb : whf;
    wprep[idx] = f2bf(w[g * 256 + k]);
}

// ---------------- gx GEMM with gather (fp32 compute, bf16 lane-major 16B-slot out) ----------------
// out row = 1024 ushorts: slot (wv, l15) at wv*128 + l15*8, holds [r0,z0,n0,r1,z1,n1,pad,pad]
// for gate-col n: gi=n>>8, c=n&255, wv=c>>5, p=(c>>4)&1, l15=c&15 -> idx = wv*128+l15*8+p*3+gi.
__global__ __launch_bounds__(256) void k_gx(const int* __restrict__ tokens,
                                            const float* __restrict__ emb,
                                            const float* __restrict__ w0, const float* __restrict__ bias0, ushort* __restrict__ out0,
                                            const float* __restrict__ w1, const float* __restrict__ bias1, ushort* __restrict__ out1) {
    __shared__ float As[16][68];
    __shared__ float Bs[16][68];
    const float* w   = blockIdx.z ? w1 : w0;
    const float* bia = blockIdx.z ? bias1 : bias0;
    ushort* out      = blockIdx.z ? out1 : out0;
    int tid = threadIdx.x;
    int n0 = blockIdx.x * 64;
    long m0 = (long)blockIdx.y * 64;
    int ml = tid >> 2, el = (tid & 3) << 2;
    long tok = tokens[m0 + ml];
    const float* arow = emb + tok * EMB;
    const float* brow = w + (long)(n0 + ml) * EMB;
    int ty = tid >> 4, tx = tid & 15;
    float acc[4][4] = {};
    for (int kt = 0; kt < EMB; kt += 16) {
        float4 av = *(const float4*)(arow + kt + el);
        float4 bv = *(const float4*)(brow + kt + el);
        __syncthreads();
        As[el + 0][ml] = av.x; As[el + 1][ml] = av.y; As[el + 2][ml] = av.z; As[el + 3][ml] = av.w;
        Bs[el + 0][ml] = bv.x; Bs[el + 1][ml] = bv.y; Bs[el + 2][ml] = bv.z; Bs[el + 3][ml] = bv.w;
        __syncthreads();
#pragma unroll
        for (int k = 0; k < 16; ++k) {
            float4 a4 = *(const float4*)&As[k][ty << 2];
            float4 b4 = *(const float4*)&Bs[k][tx << 2];
            float a[4] = {a4.x, a4.y, a4.z, a4.w};
            float bb[4] = {b4.x, b4.y, b4.z, b4.w};
#pragma unroll
            for (int i = 0; i < 4; ++i)
#pragma unroll
                for (int j = 0; j < 4; ++j)
                    acc[i][j] = fmaf(a[i], bb[j], acc[i][j]);
        }
    }
#pragma unroll
    for (int i = 0; i < 4; ++i) {
        long m = m0 + (ty << 2) + i;
        ushort* orow = out + m * 1024;
#pragma unroll
        for (int jj = 0; jj < 4; ++jj) {
            int n = n0 + (tx << 2) + jj;
            int gi = n >> 8, c = n & 255;
            int wvv = c >> 5, p = (c >> 4) & 1, fl = c & 15;
            orow[wvv * 128 + fl * 8 + p * 3 + gi] = f2bf(acc[i][jj] + bia[n]);
        }
    }
}

// ---------------- MFMA GRU: grid 8 = (batch-half, dir, seq). 512 thr = 8 waves. ----------------
// 4 B-tiles in regs (AGPR-resident), 2 in LDS. Deferred h-store (prev step's h stored
// at step top, completes under MFMA). One 16B gx load per batch-row per step.
__global__ __attribute__((amdgpu_flat_work_group_size(512, 512), amdgpu_waves_per_eu(2, 2)))
void k_gru5(
    const ushort* __restrict__ gxd_f, const ushort* __restrict__ gxd_b,
    const ushort* __restrict__ gxq_f, const ushort* __restrict__ gxq_b,
    const ushort* __restrict__ wprep,
    const float* __restrict__ bhh_f, const float* __restrict__ bhh_b,
    const int* __restrict__ dlens, const int* __restrict__ qlens,
    float* __restrict__ dosb, float* __restrict__ qosb)
{
    int wg = blockIdx.x;
    int bhalf = wg & 1;
    int dir = (wg >> 1) & 1;
    int seq = wg >> 2;                   // 0=doc, 1=query
    int T = seq ? QLEN : DLEN;
    const ushort* gx = seq ? (dir ? gxq_b : gxq_f) : (dir ? gxd_b : gxd_f);
    const float* bhh = dir ? bhh_b : bhh_f;
    const int* lens = seq ? qlens : dlens;
    float* outbase = (seq ? qosb : dosb) + dir * HID;
    int boff = bhalf * 16;

    int tid = threadIdx.x;
    int wv = tid >> 6;
    int lane = tid & 63;
    int l15 = lane & 15;
    int lhi = lane >> 4;                 // 0..3
    int jw = wv * 32;

    __shared__ ushort hbuf[2][4096];             // 16 KB bf16 h, swizzled, dbuf
    __shared__ ushort Blds[8][2][8][512];        // 128 KB: tiles 4,5 per wave

    // ---- resident weights: tiles 0..3 in regs, tiles 4,5 in LDS ----
    const ushort* wp = wprep + (size_t)dir * 196608;
    bf16x8 B0[8], B1[8], B2[8], B3[8];
#pragma unroll
    for (int ks = 0; ks < 8; ++ks) {
        B0[ks] = *(const bf16x8*)(wp + ((((wv * 6 + 0) * 8 + ks) * 64 + lane) * 8));
        B1[ks] = *(const bf16x8*)(wp + ((((wv * 6 + 1) * 8 + ks) * 64 + lane) * 8));
        B2[ks] = *(const bf16x8*)(wp + ((((wv * 6 + 2) * 8 + ks) * 64 + lane) * 8));
        B3[ks] = *(const bf16x8*)(wp + ((((wv * 6 + 3) * 8 + ks) * 64 + lane) * 8));
    }
#pragma unroll
    for (int tt = 0; tt < 2; ++tt)
#pragma unroll
        for (int ks = 0; ks < 8; ++ks) {
            bf16x8 t5 = *(const bf16x8*)(wp + ((((wv * 6 + 4 + tt) * 8 + ks) * 64 + lane) * 8));
            *(bf16x8*)((char*)&Blds[0][0][0][0] + wv * 16384 + tt * 8192 + ks * 1024 + lane * 16) = t5;
        }

    float bhn0 = bhh[512 + jw + l15];
    float bhn1 = bhh[512 + jw + 16 + l15];
    int len[4];
#pragma unroll
    for (int i = 0; i < 4; ++i) len[i] = lens[boff + lhi * 4 + i];
    float hp[2][4] = {};

    // ---- precomputed static addresses (t-invariant) ----
    int a_addr[8];
#pragma unroll
    for (int ks = 0; ks < 8; ++ks)
        a_addr[ks] = l15 * 512 + (((ks * 4 + lhi) ^ (l15 & 7)) * 16);
    int wofs[2][4];
#pragma unroll
    for (int p = 0; p < 2; ++p)
#pragma unroll
        for (int i = 0; i < 4; ++i) {
            int row = lhi * 4 + i, j = jw + p * 16 + l15;
            wofs[p][i] = (row * 256 + (((j >> 3) ^ (row & 7)) * 8) + (j & 7)) * 2;
        }
    int blbase = wv * 16384 + lane * 16;
    int lbg[4], lbo[4];                          // 32-bit lane base byte-offsets
#pragma unroll
    for (int i = 0; i < 4; ++i) {
        int b = boff + lhi * 4 + i;
        lbg[i] = b * T * 2048 + wv * 256 + l15 * 16;   // gx: 1024-ushort rows, 16B slots
        lbo[i] = b * T * 2048 + (jw + l15) * 4;        // out: 512-f32 rows
    }

    for (int x = tid; x < 4096; x += 512) hbuf[0][x] = 0;
    __syncthreads();

    int voA[4], voB[4];

#define GSTEP(RB, WB, TT, VPRE, VCUR)                                             \
    {                                                                             \
        u16x8 gxu[4];                                                             \
        _Pragma("unroll")                                                         \
        for (int i = 0; i < 4; ++i) {                                             \
            int p_ = (TT);                                                        \
            if (dir) p_ = ((TT) < len[i]) ? (len[i] - 1 - (TT)) : (TT);           \
            gxu[i] = *(const u16x8*)((const char*)gx + (lbg[i] + p_ * 2048));     \
            VCUR[i] = lbo[i] + p_ * 2048;                                         \
        }                                                                         \
        if ((TT) != 0) {                                                          \
            _Pragma("unroll")                                                     \
            for (int i = 0; i < 4; ++i) {                                         \
                float* o = (float*)((char*)outbase + VPRE[i]);                    \
                o[0] = hp[0][i];                                                  \
                o[16] = hp[1][i];                                                 \
            }                                                                     \
        }                                                                         \
        f32x4 acc0 = {0.f,0.f,0.f,0.f}, acc1 = acc0, acc2 = acc0, acc3 = acc0;    \
        f32x4 acc4 = {bhn0, bhn0, bhn0, bhn0};                                    \
        f32x4 acc5 = {bhn1, bhn1, bhn1, bhn1};                                    \
        _Pragma("unroll")                                                         \
        for (int ks = 0; ks < 8; ++ks) {                                          \
            bf16x8 a = *(const bf16x8*)((const char*)&hbuf[RB][0] + a_addr[ks]);  \
            acc0 = MFMA16(a, B0[ks], acc0, 0, 0, 0);                              \
            acc1 = MFMA16(a, B1[ks], acc1, 0, 0, 0);                              \
            acc2 = MFMA16(a, B2[ks], acc2, 0, 0, 0);                              \
            acc3 = MFMA16(a, B3[ks], acc3, 0, 0, 0);                              \
            bf16x8 b4 = *(const bf16x8*)((const char*)&Blds[0][0][0][0] + blbase + ks * 1024);        \
            bf16x8 b5 = *(const bf16x8*)((const char*)&Blds[0][0][0][0] + blbase + 8192 + ks * 1024); \
            acc4 = MFMA16(a, b4, acc4, 0, 0, 0);                                  \
            acc5 = MFMA16(a, b5, acc5, 0, 0, 0);                                  \
        }                                                                         \
        _Pragma("unroll")                                                         \
        for (int i = 0; i < 4; ++i) {                                             \
            float h2[2];                                                          \
            _Pragma("unroll")                                                     \
            for (int p = 0; p < 2; ++p) {                                         \
                float ar = p ? acc1[i] : acc0[i];                                 \
                float az = p ? acc3[i] : acc2[i];                                 \
                float an = p ? acc5[i] : acc4[i];                                 \
                float rx = bf2f(gxu[i][p * 3 + 0]);                               \
                float zx = bf2f(gxu[i][p * 3 + 1]);                               \
                float nx = bf2f(gxu[i][p * 3 + 2]);                               \
                float r = sigf(rx + ar);                                          \
                float z = sigf(zx + az);                                          \
                float nn = tanhf_(nx + r * an);                                   \
                float h = (1.f - z) * nn + z * hp[p][i];                          \
                hp[p][i] = h;                                                     \
                h2[p] = h;                                                        \
            }                                                                     \
            unsigned pk;                                                          \
            asm("v_cvt_pk_bf16_f32 %0, %1, %2" : "=v"(pk) : "v"(h2[0]), "v"(h2[1])); \
            *(ushort*)((char*)&hbuf[WB][0] + wofs[0][i]) = (ushort)(pk & 0xffffu); \
            *(ushort*)((char*)&hbuf[WB][0] + wofs[1][i]) = (ushort)(pk >> 16);    \
        }                                                                         \
        __syncthreads();                                                          \
    }

    for (int t = 0; t < T; t += 2) {
        GSTEP(0, 1, t,     voB, voA)
        GSTEP(1, 0, t + 1, voA, voB)
    }
#undef GSTEP
    // epilogue: store h(T-1)
#pragma unroll
    for (int i = 0; i < 4; ++i) {
        float* o = (float*)((char*)outbase + voB[i]);
        o[0] = hp[0][i];
        o[16] = hp[1][i];
    }
}

// ---------------- M[b,d,q] = dos[b,d,:] . qos[b,q,:]  (K=512) ----------------
__global__ __launch_bounds__(256) void k_mgemm(const float* __restrict__ dos, const float* __restrict__ qos,
                                               float* __restrict__ Mm) {
    __shared__ float As[16][68];
    __shared__ float Bs[16][68];
    int tid = threadIdx.x;
    int b = blockIdx.y;
    long m0 = (long)blockIdx.x * 64;
    int ml = tid >> 2, el = (tid & 3) << 2;
    const float* arow = dos + ((long)b * DLEN + m0 + ml) * (2 * HID);
    const float* brow = qos + ((long)b * QLEN + ml) * (2 * HID);
    int ty = tid >> 4, tx = tid & 15;
    float acc[4][4] = {};
    for (int kt = 0; kt < 2 * HID; kt += 16) {
        float4 av = *(const float4*)(arow + kt + el);
        float4 bv = *(const float4*)(brow + kt + el);
        __syncthreads();
        As[el + 0][ml] = av.x; As[el + 1][ml] = av.y; As[el + 2][ml] = av.z; As[el + 3][ml] = av.w;
        Bs[el + 0][ml] = bv.x; Bs[el + 1][ml] = bv.y; Bs[el + 2][ml] = bv.z; Bs[el + 3][ml] = bv.w;
        __syncthreads();
#pragma unroll
        for (int k = 0; k < 16; ++k) {
            float4 a4 = *(const float4*)&As[k][ty << 2];
            float4 b4 = *(const float4*)&Bs[k][tx << 2];
            float a[4] = {a4.x, a4.y, a4.z, a4.w};
            float bb[4] = {b4.x, b4.y, b4.z, b4.w};
#pragma unroll
            for (int i = 0; i < 4; ++i)
#pragma unroll
                for (int j = 0; j < 4; ++j)
                    acc[i][j] = fmaf(a[i], bb[j], acc[i][j]);
        }
    }
#pragma unroll
    for (int i = 0; i < 4; ++i) {
        long m = m0 + (ty << 2) + i;
#pragma unroll
        for (int j = 0; j < 4; ++j) {
            int n = (tx << 2) + j;
            Mm[((long)b * DLEN + m) * QLEN + n] = acc[i][j];
        }
    }
}

// ---------------- avg_beta ----------------
__global__ __launch_bounds__(256) void k_avgbeta(const float* __restrict__ Mm, const float* __restrict__ dmask,
                                                 const float* __restrict__ qmask, const int* __restrict__ dlens,
                                                 float* __restrict__ avgb) {
    int b = blockIdx.x, tid = threadIdx.x;
    int lane = tid & 63, wid = tid >> 6;
    float qm = qmask[b * QLEN + lane];
    float acc = 0.f;
    for (int d = wid; d < DLEN; d += 4) {
        float x = Mm[((long)b * DLEN + d) * QLEN + lane];
        float mx = x;
#pragma unroll
        for (int o = 32; o; o >>= 1) mx = fmaxf(mx, __shfl_xor(mx, o));
        float e = expf(x - mx) * dmask[b * DLEN + d] * qm;
        float sm = e;
#pragma unroll
        for (int o = 32; o; o >>= 1) sm += __shfl_xor(sm, o);
        acc += e / (sm + 1e-12f);
    }
    __shared__ float red[4][QLEN];
    red[wid][lane] = acc;
    __syncthreads();
    if (tid < QLEN) {
        float tot = red[0][tid] + red[1][tid] + red[2][tid] + red[3][tid];
        avgb[b * QLEN + tid] = tot / (float)dlens[b];
    }
}

// ---------------- column stats over d ----------------
__global__ __launch_bounds__(256) void k_colstats(const float* __restrict__ Mm, const float* __restrict__ dmask,
                                                  float* __restrict__ mx, float* __restrict__ cs) {
    int b = blockIdx.x, tid = threadIdx.x;
    int q = tid & 63, dg = tid >> 6;
    float m = -INFINITY, ssum = 0.f;
    for (int d = dg; d < DLEN; d += 4) {
        float x = Mm[((long)b * DLEN + d) * QLEN + q];
        float dm = dmask[b * DLEN + d];
        float mn = fmaxf(m, x);
        ssum = ssum * expf(m - mn) + expf(x - mn) * dm;
        m = mn;
    }
    __shared__ float mS[4][QLEN], sS[4][QLEN];
    mS[dg][q] = m; sS[dg][q] = ssum;
    __syncthreads();
    if (tid < QLEN) {
        float M0 = fmaxf(fmaxf(mS[0][tid], mS[1][tid]), fmaxf(mS[2][tid], mS[3][tid]));
        float S = 0.f;
#pragma unroll
        for (int i = 0; i < 4; ++i) S += sS[i][tid] * expf(mS[i][tid] - M0);
        mx[b * QLEN + tid] = M0;
        cs[b * QLEN + tid] = S;
    }
}

// ---------------- s[b,d] ----------------
__global__ __launch_bounds__(256) void k_s(const float* __restrict__ Mm, const float* __restrict__ mxv, const float* __restrict__ cs,
                                           const float* __restrict__ avgb, const float* __restrict__ qmask, const float* __restrict__ dmask,
                                           float* __restrict__ s) {
    int b = blockIdx.y, tid = threadIdx.x;
    __shared__ float wq[QLEN], mxs[QLEN];
    if (tid < QLEN) {
        float part = cs[b * QLEN + tid];
        wq[tid] = (qmask[b * QLEN + tid] > 0.f) ? (avgb[b * QLEN + tid] / (part + 1e-12f)) : 0.f;
        mxs[tid] = mxv[b * QLEN + tid];
    }
    __syncthreads();
    long d = (long)blockIdx.x * 256 + tid;
    const float* row = Mm + ((long)b * DLEN + d) * QLEN;
    float acc = 0.f;
#pragma unroll
    for (int q = 0; q < QLEN; q += 4) {
        float4 v = *(const float4*)(row + q);
        acc += expf(v.x - mxs[q + 0]) * wq[q + 0];
        acc += expf(v.y - mxs[q + 1]) * wq[q + 1];
        acc += expf(v.z - mxs[q + 2]) * wq[q + 2];
        acc += expf(v.w - mxs[q + 3]) * wq[q + 3];
    }
    s[b * DLEN + d] = dmask[b * DLEN + d] * acc;
}

// ---------------- final ----------------
__global__ __launch_bounds__(256) void k_final(const float* __restrict__ s, const int* __restrict__ doc,
                                               const int* __restrict__ cand, const int* __restrict__ ans,
                                               float* __restrict__ out) {
    int b = blockIdx.x, tid = threadIdx.x;
    __shared__ int lc[NCAND];
    __shared__ int la;
    __shared__ float red[4][NCAND + 1];
    if (tid < NCAND) lc[tid] = cand[b * NCAND + tid];
    if (tid == NCAND) la = ans[b];
    __syncthreads();
    float accs[NCAND + 1] = {};
    for (int d = tid; d < DLEN; d += 256) {
        int tk = doc[b * DLEN + d];
        float sv = s[b * DLEN + d];
#pragma unroll
        for (int c = 0; c < NCAND; ++c)
            if (tk == lc[c]) accs[c] += sv;
        if (tk == la) accs[NCAND] += sv;
    }
    int lane = tid & 63, wid = tid >> 6;
#pragma unroll
    for (int i = 0; i <= NCAND; ++i) {
        float v = accs[i];
#pragma unroll
        for (int o = 32; o; o >>= 1) v += __shfl_xor(v, o);
        if (lane == 0) red[wid][i] = v;
    }
    __syncthreads();
    if (tid == 0) {
        float cp[NCAND + 1];
#pragma unroll
        for (int i = 0; i <= NCAND; ++i) cp[i] = red[0][i] + red[1][i] + red[2][i] + red[3][i];
        int loc = 0; float best = cp[0];
#pragma unroll
        for (int c = 1; c < NCAND; ++c) if (cp[c] > best) { best = cp[c]; loc = c; }
        out[b] = (float)lc[loc];
        out[BATCH + b] = (float)loc;
        out[2 * BATCH + b] = cp[NCAND];
    }
}

__global__ void k_zero_out(float* out, int n) {
    int i = blockIdx.x * 256 + threadIdx.x;
    if (i < n) out[i] = 0.f;
}

extern "C" void kernel_launch(void* const* d_in, const int* in_sizes, int n_in,
                              void* d_out, int out_size, void* d_ws, size_t ws_size,
                              hipStream_t stream) {
    const int*   docs_input   = (const int*)d_in[0];
    const int*   docs_len     = (const int*)d_in[1];
    const float* doc_mask     = (const float*)d_in[2];
    const int*   querys_input = (const int*)d_in[3];
    const int*   querys_len   = (const int*)d_in[4];
    const float* query_mask   = (const float*)d_in[5];
    const int*   candidates   = (const int*)d_in[6];
    const int*   answers      = (const int*)d_in[7];
    const float* embedding    = (const float*)d_in[8];
    const float* w_ih_f = (const float*)d_in[9];
    const float* w_hh_f = (const float*)d_in[10];
    const float* b_ih_f = (const float*)d_in[11];
    const float* b_hh_f = (const float*)d_in[12];
    const float* w_ih_b = (const float*)d_in[13];
    const float* w_hh_b = (const float*)d_in[14];
    const float* b_ih_b = (const float*)d_in[15];
    const float* b_hh_b = (const float*)d_in[16];

    char* ws = (char*)d_ws;
    size_t off = 0;
    auto alloc = [&](size_t bytes) { size_t o = off; off = (off + bytes + 255) & ~(size_t)255; return o; };
    ushort* wprep = (ushort*)(ws + alloc((size_t)2 * 196608 * 2));
    float*  beff  = (float*)(ws + alloc((size_t)2 * G3 * 4));
    ushort* gxq_f = (ushort*)(ws + alloc((size_t)BATCH * QLEN * 1024 * 2));
    ushort* gxq_b = (ushort*)(ws + alloc((size_t)BATCH * QLEN * 1024 * 2));
    ushort* gxd_f = (ushort*)(ws + alloc((size_t)BATCH * DLEN * 1024 * 2));
    ushort* gxd_b = (ushort*)(ws + alloc((size_t)BATCH * DLEN * 1024 * 2));
    float* dosb  = (float*)(ws + alloc((size_t)BATCH * DLEN * 2 * HID * 4));
    float* qosb  = (float*)(ws + alloc((size_t)BATCH * QLEN * 2 * HID * 4));
    float* Mbuf  = (float*)(ws + alloc((size_t)BATCH * DLEN * QLEN * 4));
    float* avgb  = (float*)(ws + alloc((size_t)BATCH * QLEN * 4));
    float* mxb   = (float*)(ws + alloc((size_t)BATCH * QLEN * 4));
    float* csb   = (float*)(ws + alloc((size_t)BATCH * QLEN * 4));
    float* sbuf  = (float*)(ws + alloc((size_t)BATCH * DLEN * 4));

    if (ws_size < off) {
        k_zero_out<<<1, 256, 0, stream>>>((float*)d_out, out_size);
        return;
    }

    // effective biases (b_ih + b_hh for r/z) and weight fragments
    k_bias<<<6, 256, 0, stream>>>(b_ih_f, b_hh_f, b_ih_b, b_hh_b, beff);
    k_prep<<<1536, 256, 0, stream>>>(w_hh_f, w_hh_b, wprep);

    // gx for queries and docs, both directions (bf16 lane-major 16B-slot out)
    k_gx<<<dim3(12, (BATCH * QLEN) / 64, 2), 256, 0, stream>>>(querys_input, embedding,
        w_ih_f, beff, gxq_f, w_ih_b, beff + G3, gxq_b);
    k_gx<<<dim3(12, (BATCH * DLEN) / 64, 2), 256, 0, stream>>>(docs_input, embedding,
        w_ih_f, beff, gxd_f, w_ih_b, beff + G3, gxd_b);

    // all four BiGRU scans (doc/query x fwd/bwd), batch split in halves of 16
    k_gru5<<<8, 512, 0, stream>>>(gxd_f, gxd_b, gxq_f, gxq_b, wprep,
                                  b_hh_f, b_hh_b, docs_len, querys_len, dosb, qosb);

    // attention-over-attention
    k_mgemm<<<dim3(DLEN / 64, BATCH), 256, 0, stream>>>(dosb, qosb, Mbuf);
    k_avgbeta<<<BATCH, 256, 0, stream>>>(Mbuf, doc_mask, query_mask, docs_len, avgb);
    k_colstats<<<BATCH, 256, 0, stream>>>(Mbuf, doc_mask, mxb, csb);
    k_s<<<dim3(DLEN / 256, BATCH), 256, 0, stream>>>(Mbuf, mxb, csb, avgb, query_mask, doc_mask, sbuf);
    k_final<<<BATCH, 256, 0, stream>>>(sbuf, docs_input, candidates, answers, (float*)d_out);
}

// Round 11
// 2200.919 us; speedup vs baseline: 2.3902x; 1.3454x over previous
//
#include <hip/hip_runtime.h>
#include <hip/hip_bf16.h>
#include <math.h>

// AoA Reader v9: r10 base + batch-split nb=8 with EVEN-ROW batch placement
// (valid C rows = even acc-index at compile time -> update work truly halves
// per lane; all 64 lanes busy). 16 WGs: 8 doc + 8 query CUs.
// V=50000 E=384 H=256 B=32 D=1024 Q=64 C=10.
#define BATCH 32
#define DLEN 1024
#define QLEN 64
#define EMB 384
#define HID 256
#define G3 768   // 3*H
#define NCAND 10

typedef __attribute__((ext_vector_type(8))) short bf16x8;
typedef __attribute__((ext_vector_type(8))) unsigned short u16x8;
typedef __attribute__((ext_vector_type(4))) float f32x4;
#define MFMA16 __builtin_amdgcn_mfma_f32_16x16x32_bf16

__device__ __forceinline__ float bf2f(ushort u) {
    union { float f; unsigned v; } x; x.v = ((unsigned)u) << 16; return x.f;
}
__device__ __forceinline__ ushort f2bf(float f) {
    union { float f; unsigned v; } x; x.f = f;
    unsigned r = x.v + 0x7FFF + ((x.v >> 16) & 1);
    return (ushort)(r >> 16);
}
__device__ __forceinline__ float sigf(float x) {
    return __builtin_amdgcn_rcpf(1.f + __expf(-x));
}
__device__ __forceinline__ float tanhf_(float x) {
    return 1.f - 2.f * __builtin_amdgcn_rcpf(1.f + __expf(2.f * x));
}

// ---------------- bias_eff[dir][768]: b_ih + (b_hh for r,z gates only) ----------------
__global__ __launch_bounds__(256) void k_bias(const float* __restrict__ bihf, const float* __restrict__ bhhf,
                                              const float* __restrict__ bihb, const float* __restrict__ bhhb,
                                              float* __restrict__ be) {
    int n = blockIdx.x * 256 + threadIdx.x;
    if (n >= 1536) return;
    int dir = n / G3, c = n - dir * G3;
    const float* bih = dir ? bihb : bihf;
    const float* bhh = dir ? bhhb : bhhf;
    be[n] = bih[c] + (c < 512 ? bhh[c] : 0.f);
}

// ---------------- prep: w_hh (768x256 f32) -> bf16 MFMA B-fragment order ----------------
// layout: [dir][wave(8)][tile(6)][ks(8)][lane(64)][e(8)] bf16; per dir 196608 elems.
__global__ __launch_bounds__(256) void k_prep(const float* __restrict__ whf, const float* __restrict__ whb,
                                              ushort* __restrict__ wprep) {
    int idx = blockIdx.x * 256 + threadIdx.x;   // < 393216
    int dir = idx / 196608;
    int r = idx - dir * 196608;
    int wv = r / 24576;  int r2 = r - wv * 24576;
    int tile = r2 / 4096; int r3 = r2 - tile * 4096;
    int ks = r3 / 512;    int r4 = r3 - ks * 512;
    int lane = r4 >> 3;   int e = r4 & 7;
    int g = (tile >> 1) * 256 + wv * 32 + (tile & 1) * 16 + (lane & 15);
    int k = ks * 32 + (lane >> 4) * 8 + e;
    const float* w = dir ? whb : whf;
    wprep[idx] = f2bf(w[g * 256 + k]);
}

// ---------------- gx GEMM with gather (fp32 compute, bf16 lane-major 16B-slot out) ----------------
// out row = 1024 ushorts: slot (wv, l15) at wv*128 + l15*8, holds [r0,z0,n0,r1,z1,n1,pad,pad]
// for gate-col n: gi=n>>8, c=n&255, wv=c>>5, p=(c>>4)&1, l15=c&15 -> idx = wv*128+l15*8+p*3+gi.
__global__ __launch_bounds__(256) void k_gx(const int* __restrict__ tokens,
                                            const float* __restrict__ emb,
                                            const float* __restrict__ w0, const float* __restrict__ bias0, ushort* __restrict__ out0,
                                            const float* __restrict__ w1, const float* __restrict__ bias1, ushort* __restrict__ out1) {
    __shared__ float As[16][68];
    __shared__ float Bs[16][68];
    const float* w   = blockIdx.z ? w1 : w0;
    const float* bia = blockIdx.z ? bias1 : bias0;
    ushort* out      = blockIdx.z ? out1 : out0;
    int tid = threadIdx.x;
    int n0 = blockIdx.x * 64;
    long m0 = (long)blockIdx.y * 64;
    int ml = tid >> 2, el = (tid & 3) << 2;
    long tok = tokens[m0 + ml];
    const float* arow = emb + tok * EMB;
    const float* brow = w + (long)(n0 + ml) * EMB;
    int ty = tid >> 4, tx = tid & 15;
    float acc[4][4] = {};
    for (int kt = 0; kt < EMB; kt += 16) {
        float4 av = *(const float4*)(arow + kt + el);
        float4 bv = *(const float4*)(brow + kt + el);
        __syncthreads();
        As[el + 0][ml] = av.x; As[el + 1][ml] = av.y; As[el + 2][ml] = av.z; As[el + 3][ml] = av.w;
        Bs[el + 0][ml] = bv.x; Bs[el + 1][ml] = bv.y; Bs[el + 2][ml] = bv.z; Bs[el + 3][ml] = bv.w;
        __syncthreads();
#pragma unroll
        for (int k = 0; k < 16; ++k) {
            float4 a4 = *(const float4*)&As[k][ty << 2];
            float4 b4 = *(const float4*)&Bs[k][tx << 2];
            float a[4] = {a4.x, a4.y, a4.z, a4.w};
            float bb[4] = {b4.x, b4.y, b4.z, b4.w};
#pragma unroll
            for (int i = 0; i < 4; ++i)
#pragma unroll
                for (int j = 0; j < 4; ++j)
                    acc[i][j] = fmaf(a[i], bb[j], acc[i][j]);
        }
    }
#pragma unroll
    for (int i = 0; i < 4; ++i) {
        long m = m0 + (ty << 2) + i;
        ushort* orow = out + m * 1024;
#pragma unroll
        for (int jj = 0; jj < 4; ++jj) {
            int n = n0 + (tx << 2) + jj;
            int gi = n >> 8, c = n & 255;
            int wvv = c >> 5, p = (c >> 4) & 1, fl = c & 15;
            orow[wvv * 128 + fl * 8 + p * 3 + gi] = f2bf(acc[i][jj] + bia[n]);
        }
    }
}

// ---------------- MFMA GRU: grid 16 = (bgroup(4), dir(2), seq(2)). 512 thr = 8 waves. ----------------
// nb=8 batches per WG, placed at EVEN A-rows (batch b -> row 2b). Valid C rows even
// => acc index i even at compile time => each lane updates 2 triples (all lanes busy).
// 4 B-tiles in regs (AGPR), 2 in LDS. Deferred h-store; 16B gx loads; bias folding.
__global__ __attribute__((amdgpu_flat_work_group_size(512, 512), amdgpu_waves_per_eu(2, 2)))
void k_gru5(
    const ushort* __restrict__ gxd_f, const ushort* __restrict__ gxd_b,
    const ushort* __restrict__ gxq_f, const ushort* __restrict__ gxq_b,
    const ushort* __restrict__ wprep,
    const float* __restrict__ bhh_f, const float* __restrict__ bhh_b,
    const int* __restrict__ dlens, const int* __restrict__ qlens,
    float* __restrict__ dosb, float* __restrict__ qosb)
{
    int wg = blockIdx.x;
    int bgroup = wg & 3;
    int dir = (wg >> 2) & 1;
    int seq = wg >> 3;                   // 0=doc, 1=query
    int T = seq ? QLEN : DLEN;
    const ushort* gx = seq ? (dir ? gxq_b : gxq_f) : (dir ? gxd_b : gxd_f);
    const float* bhh = dir ? bhh_b : bhh_f;
    const int* lens = seq ? qlens : dlens;
    float* outbase = (seq ? qosb : dosb) + dir * HID;
    int boff = bgroup * 8;

    int tid = threadIdx.x;
    int wv = tid >> 6;
    int lane = tid & 63;
    int l15 = lane & 15;
    int lhi = lane >> 4;                 // 0..3
    int jw = wv * 32;

    __shared__ ushort hbuf[2][4096];             // 16 KB bf16 h, swizzled, dbuf
    __shared__ ushort Blds[8][2][8][512];        // 128 KB: tiles 4,5 per wave

    // ---- resident weights: tiles 0..3 in regs, tiles 4,5 in LDS ----
    const ushort* wp = wprep + (size_t)dir * 196608;
    bf16x8 B0[8], B1[8], B2[8], B3[8];
#pragma unroll
    for (int ks = 0; ks < 8; ++ks) {
        B0[ks] = *(const bf16x8*)(wp + ((((wv * 6 + 0) * 8 + ks) * 64 + lane) * 8));
        B1[ks] = *(const bf16x8*)(wp + ((((wv * 6 + 1) * 8 + ks) * 64 + lane) * 8));
        B2[ks] = *(const bf16x8*)(wp + ((((wv * 6 + 2) * 8 + ks) * 64 + lane) * 8));
        B3[ks] = *(const bf16x8*)(wp + ((((wv * 6 + 3) * 8 + ks) * 64 + lane) * 8));
    }
#pragma unroll
    for (int tt = 0; tt < 2; ++tt)
#pragma unroll
        for (int ks = 0; ks < 8; ++ks) {
            bf16x8 t5 = *(const bf16x8*)(wp + ((((wv * 6 + 4 + tt) * 8 + ks) * 64 + lane) * 8));
            *(bf16x8*)((char*)&Blds[0][0][0][0] + wv * 16384 + tt * 8192 + ks * 1024 + lane * 16) = t5;
        }

    float bhn0 = bhh[512 + jw + l15];
    float bhn1 = bhh[512 + jw + 16 + l15];
    int len[2];
#pragma unroll
    for (int ii = 0; ii < 2; ++ii) len[ii] = lens[boff + lhi * 2 + ii];
    float hp[2][2] = {};                 // [p][ii]

    // ---- precomputed static addresses (t-invariant) ----
    int a_addr[8];
#pragma unroll
    for (int ks = 0; ks < 8; ++ks)
        a_addr[ks] = l15 * 512 + (((ks * 4 + lhi) ^ (l15 & 7)) * 16);
    int wofs[2][2];                      // [p][ii]; row = 2*(lhi*2+ii) (even rows)
#pragma unroll
    for (int p = 0; p < 2; ++p)
#pragma unroll
        for (int ii = 0; ii < 2; ++ii) {
            int row = (lhi * 2 + ii) * 2, j = jw + p * 16 + l15;
            wofs[p][ii] = (row * 256 + (((j >> 3) ^ (row & 7)) * 8) + (j & 7)) * 2;
        }
    int blbase = wv * 16384 + lane * 16;
    int lbg[2], lbo[2];
#pragma unroll
    for (int ii = 0; ii < 2; ++ii) {
        int b = boff + lhi * 2 + ii;
        lbg[ii] = b * T * 2048 + wv * 256 + l15 * 16;   // gx: 1024-ushort rows, 16B slots
        lbo[ii] = b * T * 2048 + (jw + l15) * 4;        // out: 512-f32 rows
    }

    for (int x = tid; x < 4096; x += 512) hbuf[0][x] = 0;   // odd rows stay 0 forever
    __syncthreads();

    int voA[2], voB[2];

#define GSTEP(RB, WB, TT, VPRE, VCUR)                                             \
    {                                                                             \
        u16x8 gxu[2];                                                             \
        _Pragma("unroll")                                                         \
        for (int ii = 0; ii < 2; ++ii) {                                          \
            int p_ = (TT);                                                        \
            if (dir) p_ = ((TT) < len[ii]) ? (len[ii] - 1 - (TT)) : (TT);         \
            gxu[ii] = *(const u16x8*)((const char*)gx + (lbg[ii] + p_ * 2048));   \
            VCUR[ii] = lbo[ii] + p_ * 2048;                                       \
        }                                                                         \
        if ((TT) != 0) {                                                          \
            _Pragma("unroll")                                                     \
            for (int ii = 0; ii < 2; ++ii) {                                      \
                float* o = (float*)((char*)outbase + VPRE[ii]);                   \
                o[0] = hp[0][ii];                                                 \
                o[16] = hp[1][ii];                                                \
            }                                                                     \
        }                                                                         \
        f32x4 acc0 = {0.f,0.f,0.f,0.f}, acc1 = acc0, acc2 = acc0, acc3 = acc0;    \
        f32x4 acc4 = {bhn0, bhn0, bhn0, bhn0};                                    \
        f32x4 acc5 = {bhn1, bhn1, bhn1, bhn1};                                    \
        _Pragma("unroll")                                                         \
        for (int ks = 0; ks < 8; ++ks) {                                          \
            bf16x8 a = *(const bf16x8*)((const char*)&hbuf[RB][0] + a_addr[ks]);  \
            acc0 = MFMA16(a, B0[ks], acc0, 0, 0, 0);                              \
            acc1 = MFMA16(a, B1[ks], acc1, 0, 0, 0);                              \
            acc2 = MFMA16(a, B2[ks], acc2, 0, 0, 0);                              \
            acc3 = MFMA16(a, B3[ks], acc3, 0, 0, 0);                              \
            bf16x8 b4 = *(const bf16x8*)((const char*)&Blds[0][0][0][0] + blbase + ks * 1024);        \
            bf16x8 b5 = *(const bf16x8*)((const char*)&Blds[0][0][0][0] + blbase + 8192 + ks * 1024); \
            acc4 = MFMA16(a, b4, acc4, 0, 0, 0);                                  \
            acc5 = MFMA16(a, b5, acc5, 0, 0, 0);                                  \
        }                                                                         \
        _Pragma("unroll")                                                         \
        for (int ii = 0; ii < 2; ++ii) {                                          \
            const int ci = 2 * ii;  /* even acc row = valid batch */              \
            float h2[2];                                                          \
            _Pragma("unroll")                                                     \
            for (int p = 0; p < 2; ++p) {                                         \
                float ar = p ? acc1[ci] : acc0[ci];                               \
                float az = p ? acc3[ci] : acc2[ci];                               \
                float an = p ? acc5[ci] : acc4[ci];                               \
                float rx = bf2f(gxu[ii][p * 3 + 0]);                              \
                float zx = bf2f(gxu[ii][p * 3 + 1]);                              \
                float nx = bf2f(gxu[ii][p * 3 + 2]);                              \
                float r = sigf(rx + ar);                                          \
                float z = sigf(zx + az);                                          \
                float nn = tanhf_(nx + r * an);                                   \
                float h = (1.f - z) * nn + z * hp[p][ii];                         \
                hp[p][ii] = h;                                                    \
                h2[p] = h;                                                        \
            }                                                                     \
            unsigned pk;                                                          \
            asm("v_cvt_pk_bf16_f32 %0, %1, %2" : "=v"(pk) : "v"(h2[0]), "v"(h2[1])); \
            *(ushort*)((char*)&hbuf[WB][0] + wofs[0][ii]) = (ushort)(pk & 0xffffu); \
            *(ushort*)((char*)&hbuf[WB][0] + wofs[1][ii]) = (ushort)(pk >> 16);   \
        }                                                                         \
        __syncthreads();                                                          \
    }

    for (int t = 0; t < T; t += 2) {
        GSTEP(0, 1, t,     voB, voA)
        GSTEP(1, 0, t + 1, voA, voB)
    }
#undef GSTEP
    // epilogue: store h(T-1)
#pragma unroll
    for (int ii = 0; ii < 2; ++ii) {
        float* o = (float*)((char*)outbase + voB[ii]);
        o[0] = hp[0][ii];
        o[16] = hp[1][ii];
    }
}

// ---------------- M[b,d,q] = dos[b,d,:] . qos[b,q,:]  (K=512) ----------------
__global__ __launch_bounds__(256) void k_mgemm(const float* __restrict__ dos, const float* __restrict__ qos,
                                               float* __restrict__ Mm) {
    __shared__ float As[16][68];
    __shared__ float Bs[16][68];
    int tid = threadIdx.x;
    int b = blockIdx.y;
    long m0 = (long)blockIdx.x * 64;
    int ml = tid >> 2, el = (tid & 3) << 2;
    const float* arow = dos + ((long)b * DLEN + m0 + ml) * (2 * HID);
    const float* brow = qos + ((long)b * QLEN + ml) * (2 * HID);
    int ty = tid >> 4, tx = tid & 15;
    float acc[4][4] = {};
    for (int kt = 0; kt < 2 * HID; kt += 16) {
        float4 av = *(const float4*)(arow + kt + el);
        float4 bv = *(const float4*)(brow + kt + el);
        __syncthreads();
        As[el + 0][ml] = av.x; As[el + 1][ml] = av.y; As[el + 2][ml] = av.z; As[el + 3][ml] = av.w;
        Bs[el + 0][ml] = bv.x; Bs[el + 1][ml] = bv.y; Bs[el + 2][ml] = bv.z; Bs[el + 3][ml] = bv.w;
        __syncthreads();
#pragma unroll
        for (int k = 0; k < 16; ++k) {
            float4 a4 = *(const float4*)&As[k][ty << 2];
            float4 b4 = *(const float4*)&Bs[k][tx << 2];
            float a[4] = {a4.x, a4.y, a4.z, a4.w};
            float bb[4] = {b4.x, b4.y, b4.z, b4.w};
#pragma unroll
            for (int i = 0; i < 4; ++i)
#pragma unroll
                for (int j = 0; j < 4; ++j)
                    acc[i][j] = fmaf(a[i], bb[j], acc[i][j]);
        }
    }
#pragma unroll
    for (int i = 0; i < 4; ++i) {
        long m = m0 + (ty << 2) + i;
#pragma unroll
        for (int j = 0; j < 4; ++j) {
            int n = (tx << 2) + j;
            Mm[((long)b * DLEN + m) * QLEN + n] = acc[i][j];
        }
    }
}

// ---------------- avg_beta ----------------
__global__ __launch_bounds__(256) void k_avgbeta(const float* __restrict__ Mm, const float* __restrict__ dmask,
                                                 const float* __restrict__ qmask, const int* __restrict__ dlens,
                                                 float* __restrict__ avgb) {
    int b = blockIdx.x, tid = threadIdx.x;
    int lane = tid & 63, wid = tid >> 6;
    float qm = qmask[b * QLEN + lane];
    float acc = 0.f;
    for (int d = wid; d < DLEN; d += 4) {
        float x = Mm[((long)b * DLEN + d) * QLEN + lane];
        float mx = x;
#pragma unroll
        for (int o = 32; o; o >>= 1) mx = fmaxf(mx, __shfl_xor(mx, o));
        float e = expf(x - mx) * dmask[b * DLEN + d] * qm;
        float sm = e;
#pragma unroll
        for (int o = 32; o; o >>= 1) sm += __shfl_xor(sm, o);
        acc += e / (sm + 1e-12f);
    }
    __shared__ float red[4][QLEN];
    red[wid][lane] = acc;
    __syncthreads();
    if (tid < QLEN) {
        float tot = red[0][tid] + red[1][tid] + red[2][tid] + red[3][tid];
        avgb[b * QLEN + tid] = tot / (float)dlens[b];
    }
}

// ---------------- column stats over d ----------------
__global__ __launch_bounds__(256) void k_colstats(const float* __restrict__ Mm, const float* __restrict__ dmask,
                                                  float* __restrict__ mx, float* __restrict__ cs) {
    int b = blockIdx.x, tid = threadIdx.x;
    int q = tid & 63, dg = tid >> 6;
    float m = -INFINITY, ssum = 0.f;
    for (int d = dg; d < DLEN; d += 4) {
        float x = Mm[((long)b * DLEN + d) * QLEN + q];
        float dm = dmask[b * DLEN + d];
        float mn = fmaxf(m, x);
        ssum = ssum * expf(m - mn) + expf(x - mn) * dm;
        m = mn;
    }
    __shared__ float mS[4][QLEN], sS[4][QLEN];
    mS[dg][q] = m; sS[dg][q] = ssum;
    __syncthreads();
    if (tid < QLEN) {
        float M0 = fmaxf(fmaxf(mS[0][tid], mS[1][tid]), fmaxf(mS[2][tid], mS[3][tid]));
        float S = 0.f;
#pragma unroll
        for (int i = 0; i < 4; ++i) S += sS[i][tid] * expf(mS[i][tid] - M0);
        mx[b * QLEN + tid] = M0;
        cs[b * QLEN + tid] = S;
    }
}

// ---------------- s[b,d] ----------------
__global__ __launch_bounds__(256) void k_s(const float* __restrict__ Mm, const float* __restrict__ mxv, const float* __restrict__ cs,
                                           const float* __restrict__ avgb, const float* __restrict__ qmask, const float* __restrict__ dmask,
                                           float* __restrict__ s) {
    int b = blockIdx.y, tid = threadIdx.x;
    __shared__ float wq[QLEN], mxs[QLEN];
    if (tid < QLEN) {
        float part = cs[b * QLEN + tid];
        wq[tid] = (qmask[b * QLEN + tid] > 0.f) ? (avgb[b * QLEN + tid] / (part + 1e-12f)) : 0.f;
        mxs[tid] = mxv[b * QLEN + tid];
    }
    __syncthreads();
    long d = (long)blockIdx.x * 256 + tid;
    const float* row = Mm + ((long)b * DLEN + d) * QLEN;
    float acc = 0.f;
#pragma unroll
    for (int q = 0; q < QLEN; q += 4) {
        float4 v = *(const float4*)(row + q);
        acc += expf(v.x - mxs[q + 0]) * wq[q + 0];
        acc += expf(v.y - mxs[q + 1]) * wq[q + 1];
        acc += expf(v.z - mxs[q + 2]) * wq[q + 2];
        acc += expf(v.w - mxs[q + 3]) * wq[q + 3];
    }
    s[b * DLEN + d] = dmask[b * DLEN + d] * acc;
}

// ---------------- final ----------------
__global__ __launch_bounds__(256) void k_final(const float* __restrict__ s, const int* __restrict__ doc,
                                               const int* __restrict__ cand, const int* __restrict__ ans,
                                               float* __restrict__ out) {
    int b = blockIdx.x, tid = threadIdx.x;
    __shared__ int lc[NCAND];
    __shared__ int la;
    __shared__ float red[4][NCAND + 1];
    if (tid < NCAND) lc[tid] = cand[b * NCAND + tid];
    if (tid == NCAND) la = ans[b];
    __syncthreads();
    float accs[NCAND + 1] = {};
    for (int d = tid; d < DLEN; d += 256) {
        int tk = doc[b * DLEN + d];
        float sv = s[b * DLEN + d];
#pragma unroll
        for (int c = 0; c < NCAND; ++c)
            if (tk == lc[c]) accs[c] += sv;
        if (tk == la) accs[NCAND] += sv;
    }
    int lane = tid & 63, wid = tid >> 6;
#pragma unroll
    for (int i = 0; i <= NCAND; ++i) {
        float v = accs[i];
#pragma unroll
        for (int o = 32; o; o >>= 1) v += __shfl_xor(v, o);
        if (lane == 0) red[wid][i] = v;
    }
    __syncthreads();
    if (tid == 0) {
        float cp[NCAND + 1];
#pragma unroll
        for (int i = 0; i <= NCAND; ++i) cp[i] = red[0][i] + red[1][i] + red[2][i] + red[3][i];
        int loc = 0; float best = cp[0];
#pragma unroll
        for (int c = 1; c < NCAND; ++c) if (cp[c] > best) { best = cp[c]; loc = c; }
        out[b] = (float)lc[loc];
        out[BATCH + b] = (float)loc;
        out[2 * BATCH + b] = cp[NCAND];
    }
}

__global__ void k_zero_out(float* out, int n) {
    int i = blockIdx.x * 256 + threadIdx.x;
    if (i < n) out[i] = 0.f;
}

extern "C" void kernel_launch(void* const* d_in, const int* in_sizes, int n_in,
                              void* d_out, int out_size, void* d_ws, size_t ws_size,
                              hipStream_t stream) {
    const int*   docs_input   = (const int*)d_in[0];
    const int*   docs_len     = (const int*)d_in[1];
    const float* doc_mask     = (const float*)d_in[2];
    const int*   querys_input = (const int*)d_in[3];
    const int*   querys_len   = (const int*)d_in[4];
    const float* query_mask   = (const float*)d_in[5];
    const int*   candidates   = (const int*)d_in[6];
    const int*   answers      = (const int*)d_in[7];
    const float* embedding    = (const float*)d_in[8];
    const float* w_ih_f = (const float*)d_in[9];
    const float* w_hh_f = (const float*)d_in[10];
    const float* b_ih_f = (const float*)d_in[11];
    const float* b_hh_f = (const float*)d_in[12];
    const float* w_ih_b = (const float*)d_in[13];
    const float* w_hh_b = (const float*)d_in[14];
    const float* b_ih_b = (const float*)d_in[15];
    const float* b_hh_b = (const float*)d_in[16];

    char* ws = (char*)d_ws;
    size_t off = 0;
    auto alloc = [&](size_t bytes) { size_t o = off; off = (off + bytes + 255) & ~(size_t)255; return o; };
    ushort* wprep = (ushort*)(ws + alloc((size_t)2 * 196608 * 2));
    float*  beff  = (float*)(ws + alloc((size_t)2 * G3 * 4));
    ushort* gxq_f = (ushort*)(ws + alloc((size_t)BATCH * QLEN * 1024 * 2));
    ushort* gxq_b = (ushort*)(ws + alloc((size_t)BATCH * QLEN * 1024 * 2));
    ushort* gxd_f = (ushort*)(ws + alloc((size_t)BATCH * DLEN * 1024 * 2));
    ushort* gxd_b = (ushort*)(ws + alloc((size_t)BATCH * DLEN * 1024 * 2));
    float* dosb  = (float*)(ws + alloc((size_t)BATCH * DLEN * 2 * HID * 4));
    float* qosb  = (float*)(ws + alloc((size_t)BATCH * QLEN * 2 * HID * 4));
    float* Mbuf  = (float*)(ws + alloc((size_t)BATCH * DLEN * QLEN * 4));
    float* avgb  = (float*)(ws + alloc((size_t)BATCH * QLEN * 4));
    float* mxb   = (float*)(ws + alloc((size_t)BATCH * QLEN * 4));
    float* csb   = (float*)(ws + alloc((size_t)BATCH * QLEN * 4));
    float* sbuf  = (float*)(ws + alloc((size_t)BATCH * DLEN * 4));

    if (ws_size < off) {
        k_zero_out<<<1, 256, 0, stream>>>((float*)d_out, out_size);
        return;
    }

    // effective biases (b_ih + b_hh for r/z) and weight fragments
    k_bias<<<6, 256, 0, stream>>>(b_ih_f, b_hh_f, b_ih_b, b_hh_b, beff);
    k_prep<<<1536, 256, 0, stream>>>(w_hh_f, w_hh_b, wprep);

    // gx for queries and docs, both directions (bf16 lane-major 16B-slot out)
    k_gx<<<dim3(12, (BATCH * QLEN) / 64, 2), 256, 0, stream>>>(querys_input, embedding,
        w_ih_f, beff, gxq_f, w_ih_b, beff + G3, gxq_b);
    k_gx<<<dim3(12, (BATCH * DLEN) / 64, 2), 256, 0, stream>>>(docs_input, embedding,
        w_ih_f, beff, gxd_f, w_ih_b, beff + G3, gxd_b);

    // all four BiGRU scans (doc/query x fwd/bwd), batch split in groups of 8
    k_gru5<<<16, 512, 0, stream>>>(gxd_f, gxd_b, gxq_f, gxq_b, wprep,
                                   b_hh_f, b_hh_b, docs_len, querys_len, dosb, qosb);

    // attention-over-attention
    k_mgemm<<<dim3(DLEN / 64, BATCH), 256, 0, stream>>>(dosb, qosb, Mbuf);
    k_avgbeta<<<BATCH, 256, 0, stream>>>(Mbuf, doc_mask, query_mask, docs_len, avgb);
    k_colstats<<<BATCH, 256, 0, stream>>>(Mbuf, doc_mask, mxb, csb);
    k_s<<<dim3(DLEN / 256, BATCH), 256, 0, stream>>>(Mbuf, mxb, csb, avgb, query_mask, doc_mask, sbuf);
    k_final<<<BATCH, 256, 0, stream>>>(sbuf, docs_input, candidates, answers, (float*)d_out);
}

// Round 12
// 1907.216 us; speedup vs baseline: 2.7583x; 1.1540x over previous
//
#include <hip/hip_runtime.h>
#include <hip/hip_bf16.h>
#include <math.h>

// AoA Reader v10: nb=4 GRU split (32 WGs, row=4b placement) + MFMA-ized k_gx
// (bf16 inputs, LDS-staged A, wave-per-n-tile). V=50000 E=384 H=256 B=32 D=1024 Q=64 C=10.
#define BATCH 32
#define DLEN 1024
#define QLEN 64
#define EMB 384
#define HID 256
#define G3 768   // 3*H
#define NCAND 10

typedef __attribute__((ext_vector_type(8))) short bf16x8;
typedef __attribute__((ext_vector_type(8))) unsigned short u16x8;
typedef __attribute__((ext_vector_type(4))) float f32x4;
#define MFMA16 __builtin_amdgcn_mfma_f32_16x16x32_bf16

__device__ __forceinline__ float bf2f(ushort u) {
    union { float f; unsigned v; } x; x.v = ((unsigned)u) << 16; return x.f;
}
__device__ __forceinline__ ushort f2bf(float f) {
    union { float f; unsigned v; } x; x.f = f;
    unsigned r = x.v + 0x7FFF + ((x.v >> 16) & 1);
    return (ushort)(r >> 16);
}
__device__ __forceinline__ float sigf(float x) {
    return __builtin_amdgcn_rcpf(1.f + __expf(-x));
}
__device__ __forceinline__ float tanhf_(float x) {
    return 1.f - 2.f * __builtin_amdgcn_rcpf(1.f + __expf(2.f * x));
}
__device__ __forceinline__ bf16x8 cvt8(float4 a, float4 b) {
    union { unsigned u[4]; bf16x8 v; } r;
    asm("v_cvt_pk_bf16_f32 %0, %1, %2" : "=v"(r.u[0]) : "v"(a.x), "v"(a.y));
    asm("v_cvt_pk_bf16_f32 %0, %1, %2" : "=v"(r.u[1]) : "v"(a.z), "v"(a.w));
    asm("v_cvt_pk_bf16_f32 %0, %1, %2" : "=v"(r.u[2]) : "v"(b.x), "v"(b.y));
    asm("v_cvt_pk_bf16_f32 %0, %1, %2" : "=v"(r.u[3]) : "v"(b.z), "v"(b.w));
    return r.v;
}

// ---------------- bias_eff[dir][768]: b_ih + (b_hh for r,z gates only) ----------------
__global__ __launch_bounds__(256) void k_bias(const float* __restrict__ bihf, const float* __restrict__ bhhf,
                                              const float* __restrict__ bihb, const float* __restrict__ bhhb,
                                              float* __restrict__ be) {
    int n = blockIdx.x * 256 + threadIdx.x;
    if (n >= 1536) return;
    int dir = n / G3, c = n - dir * G3;
    const float* bih = dir ? bihb : bihf;
    const float* bhh = dir ? bhhb : bhhf;
    be[n] = bih[c] + (c < 512 ? bhh[c] : 0.f);
}

// ---------------- prep: w_hh (768x256 f32) -> bf16 MFMA B-fragment order ----------------
// layout: [dir][wave(8)][tile(6)][ks(8)][lane(64)][e(8)] bf16; per dir 196608 elems.
__global__ __launch_bounds__(256) void k_prep(const float* __restrict__ whf, const float* __restrict__ whb,
                                              ushort* __restrict__ wprep) {
    int idx = blockIdx.x * 256 + threadIdx.x;   // < 393216
    int dir = idx / 196608;
    int r = idx - dir * 196608;
    int wv = r / 24576;  int r2 = r - wv * 24576;
    int tile = r2 / 4096; int r3 = r2 - tile * 4096;
    int ks = r3 / 512;    int r4 = r3 - ks * 512;
    int lane = r4 >> 3;   int e = r4 & 7;
    int g = (tile >> 1) * 256 + wv * 32 + (tile & 1) * 16 + (lane & 15);
    int k = ks * 32 + (lane >> 4) * 8 + e;
    const float* w = dir ? whb : whf;
    wprep[idx] = f2bf(w[g * 256 + k]);
}

// ---------------- gx GEMM with gather, MFMA bf16 (fp32 accum, bf16 lane-major 16B-slot out) ----------------
// grid (12, M/64, 2). 256 thr = 4 waves; wave wv owns n-tile n0+wv*16. A (emb rows)
// staged once into LDS as bf16 (rows padded +8 bf16 -> conflict-light). 48 MFMA/wave.
// out row = 1024 ushorts: n -> gi=n>>8,c=n&255,wvv=c>>5,p=(c>>4)&1,fl=c&15 -> wvv*128+fl*8+p*3+gi.
__global__ __launch_bounds__(256) void k_gx(const int* __restrict__ tokens,
                                            const float* __restrict__ emb,
                                            const float* __restrict__ w0, const float* __restrict__ bias0, ushort* __restrict__ out0,
                                            const float* __restrict__ w1, const float* __restrict__ bias1, ushort* __restrict__ out1) {
    __shared__ ushort Asl[64][392];              // 384 k + 8 pad, 50 KB
    const float* w   = blockIdx.z ? w1 : w0;
    const float* bia = blockIdx.z ? bias1 : bias0;
    ushort* out      = blockIdx.z ? out1 : out0;
    int tid = threadIdx.x;
    int n0 = blockIdx.x * 64;
    long m0 = (long)blockIdx.y * 64;
    int wv = tid >> 6;
    int lane = tid & 63;
    int l15 = lane & 15;
    int lhi = lane >> 4;

    // ---- stage A: 4 threads/row, each 12x8 floats -> bf16 ----
    {
        int row = tid >> 2, kq = tid & 3;
        long tok = tokens[m0 + row];
        const float* ar = emb + tok * EMB + kq * 96;
#pragma unroll
        for (int it = 0; it < 12; ++it) {
            float4 a = *(const float4*)(ar + it * 8);
            float4 b = *(const float4*)(ar + it * 8 + 4);
            *(bf16x8*)&Asl[row][kq * 96 + it * 8] = cvt8(a, b);
        }
    }
    __syncthreads();

    // ---- compute: wave wv = n-tile; 4 m-subtiles ----
    int n = n0 + wv * 16 + l15;
    const float* brow = w + (long)n * EMB;
    f32x4 acc[4] = {};
#pragma unroll
    for (int ks = 0; ks < 12; ++ks) {
        float4 b0 = *(const float4*)(brow + ks * 32 + lhi * 8);
        float4 b1 = *(const float4*)(brow + ks * 32 + lhi * 8 + 4);
        bf16x8 bf = cvt8(b0, b1);
#pragma unroll
        for (int mt = 0; mt < 4; ++mt) {
            bf16x8 a = *(const bf16x8*)&Asl[mt * 16 + l15][ks * 32 + lhi * 8];
            acc[mt] = MFMA16(a, bf, acc[mt], 0, 0, 0);
        }
    }

    // ---- epilogue: bias + permuted bf16 store ----
    float bias = bia[n];
    int gi = n >> 8, c = n & 255;
    int wvv = c >> 5, p = (c >> 4) & 1, fl = c & 15;
    int sidx = wvv * 128 + fl * 8 + p * 3 + gi;
#pragma unroll
    for (int mt = 0; mt < 4; ++mt)
#pragma unroll
        for (int r = 0; r < 4; ++r) {
            long m = m0 + mt * 16 + lhi * 4 + r;
            out[m * 1024 + sidx] = f2bf(acc[mt][r] + bias);
        }
}

// ---------------- MFMA GRU: grid 32 = (bgroup(8), dir(2), seq(2)). 512 thr = 8 waves. ----------------
// nb=4 batches per WG, batch b -> row 4b (valid C row => reg 0 at compile time).
// 4 B-tiles in regs (AGPR), 2 in LDS. Deferred h-store; 16B gx loads; bias folding.
__global__ __attribute__((amdgpu_flat_work_group_size(512, 512), amdgpu_waves_per_eu(2, 2)))
void k_gru5(
    const ushort* __restrict__ gxd_f, const ushort* __restrict__ gxd_b,
    const ushort* __restrict__ gxq_f, const ushort* __restrict__ gxq_b,
    const ushort* __restrict__ wprep,
    const float* __restrict__ bhh_f, const float* __restrict__ bhh_b,
    const int* __restrict__ dlens, const int* __restrict__ qlens,
    float* __restrict__ dosb, float* __restrict__ qosb)
{
    int wg = blockIdx.x;
    int bgroup = wg & 7;
    int dir = (wg >> 3) & 1;
    int seq = wg >> 4;                   // 0=doc, 1=query
    int T = seq ? QLEN : DLEN;
    const ushort* gx = seq ? (dir ? gxq_b : gxq_f) : (dir ? gxd_b : gxd_f);
    const float* bhh = dir ? bhh_b : bhh_f;
    const int* lens = seq ? qlens : dlens;
    float* outbase = (seq ? qosb : dosb) + dir * HID;
    int boff = bgroup * 4;

    int tid = threadIdx.x;
    int wv = tid >> 6;
    int lane = tid & 63;
    int l15 = lane & 15;
    int lhi = lane >> 4;                 // 0..3 = local batch
    int jw = wv * 32;

    __shared__ ushort hbuf[2][4096];             // 16 KB bf16 h, swizzled, dbuf
    __shared__ ushort Blds[8][2][8][512];        // 128 KB: tiles 4,5 per wave

    // ---- resident weights: tiles 0..3 in regs, tiles 4,5 in LDS ----
    const ushort* wp = wprep + (size_t)dir * 196608;
    bf16x8 B0[8], B1[8], B2[8], B3[8];
#pragma unroll
    for (int ks = 0; ks < 8; ++ks) {
        B0[ks] = *(const bf16x8*)(wp + ((((wv * 6 + 0) * 8 + ks) * 64 + lane) * 8));
        B1[ks] = *(const bf16x8*)(wp + ((((wv * 6 + 1) * 8 + ks) * 64 + lane) * 8));
        B2[ks] = *(const bf16x8*)(wp + ((((wv * 6 + 2) * 8 + ks) * 64 + lane) * 8));
        B3[ks] = *(const bf16x8*)(wp + ((((wv * 6 + 3) * 8 + ks) * 64 + lane) * 8));
    }
#pragma unroll
    for (int tt = 0; tt < 2; ++tt)
#pragma unroll
        for (int ks = 0; ks < 8; ++ks) {
            bf16x8 t5 = *(const bf16x8*)(wp + ((((wv * 6 + 4 + tt) * 8 + ks) * 64 + lane) * 8));
            *(bf16x8*)((char*)&Blds[0][0][0][0] + wv * 16384 + tt * 8192 + ks * 1024 + lane * 16) = t5;
        }

    float bhn0 = bhh[512 + jw + l15];
    float bhn1 = bhh[512 + jw + 16 + l15];
    int len = lens[boff + lhi];
    float hp[2] = {};                    // [p]

    // ---- precomputed static addresses (t-invariant) ----
    int a_addr[8];
#pragma unroll
    for (int ks = 0; ks < 8; ++ks)
        a_addr[ks] = l15 * 512 + (((ks * 4 + lhi) ^ (l15 & 7)) * 16);
    int wofs[2];                         // [p]; row = 4*lhi
#pragma unroll
    for (int p = 0; p < 2; ++p) {
        int row = lhi * 4, j = jw + p * 16 + l15;
        wofs[p] = (row * 256 + (((j >> 3) ^ (row & 7)) * 8) + (j & 7)) * 2;
    }
    int blbase = wv * 16384 + lane * 16;
    int b = boff + lhi;
    int lbg = b * T * 2048 + wv * 256 + l15 * 16;   // gx: 1024-ushort rows, 16B slots
    int lbo = b * T * 2048 + (jw + l15) * 4;        // out: 512-f32 rows

    for (int x = tid; x < 4096; x += 512) hbuf[0][x] = 0;   // rows %4!=0 stay 0 forever
    __syncthreads();

    int voA, voB;

#define GSTEP(RB, WB, TT, VPRE, VCUR)                                             \
    {                                                                             \
        int p_ = (TT);                                                            \
        if (dir) p_ = ((TT) < len) ? (len - 1 - (TT)) : (TT);                     \
        u16x8 gxu = *(const u16x8*)((const char*)gx + (lbg + p_ * 2048));         \
        VCUR = lbo + p_ * 2048;                                                   \
        if ((TT) != 0) {                                                          \
            float* o = (float*)((char*)outbase + VPRE);                           \
            o[0] = hp[0];                                                         \
            o[16] = hp[1];                                                        \
        }                                                                         \
        f32x4 acc0 = {0.f,0.f,0.f,0.f}, acc1 = acc0, acc2 = acc0, acc3 = acc0;    \
        f32x4 acc4 = {bhn0, bhn0, bhn0, bhn0};                                    \
        f32x4 acc5 = {bhn1, bhn1, bhn1, bhn1};                                    \
        _Pragma("unroll")                                                         \
        for (int ks = 0; ks < 8; ++ks) {                                          \
            bf16x8 a = *(const bf16x8*)((const char*)&hbuf[RB][0] + a_addr[ks]);  \
            acc0 = MFMA16(a, B0[ks], acc0, 0, 0, 0);                              \
            acc1 = MFMA16(a, B1[ks], acc1, 0, 0, 0);                              \
            acc2 = MFMA16(a, B2[ks], acc2, 0, 0, 0);                              \
            acc3 = MFMA16(a, B3[ks], acc3, 0, 0, 0);                              \
            bf16x8 b4 = *(const bf16x8*)((const char*)&Blds[0][0][0][0] + blbase + ks * 1024);        \
            bf16x8 b5 = *(const bf16x8*)((const char*)&Blds[0][0][0][0] + blbase + 8192 + ks * 1024); \
            acc4 = MFMA16(a, b4, acc4, 0, 0, 0);                                  \
            acc5 = MFMA16(a, b5, acc5, 0, 0, 0);                                  \
        }                                                                         \
        {                                                                         \
            float h2[2];                                                          \
            _Pragma("unroll")                                                     \
            for (int p = 0; p < 2; ++p) {                                         \
                float ar = p ? acc1[0] : acc0[0];                                 \
                float az = p ? acc3[0] : acc2[0];                                 \
                float an = p ? acc5[0] : acc4[0];                                 \
                float rx = bf2f(gxu[p * 3 + 0]);                                  \
                float zx = bf2f(gxu[p * 3 + 1]);                                  \
                float nx = bf2f(gxu[p * 3 + 2]);                                  \
                float r = sigf(rx + ar);                                          \
                float z = sigf(zx + az);                                          \
                float nn = tanhf_(nx + r * an);                                   \
                float h = (1.f - z) * nn + z * hp[p];                             \
                hp[p] = h;                                                        \
                h2[p] = h;                                                        \
            }                                                                     \
            unsigned pk;                                                          \
            asm("v_cvt_pk_bf16_f32 %0, %1, %2" : "=v"(pk) : "v"(h2[0]), "v"(h2[1])); \
            *(ushort*)((char*)&hbuf[WB][0] + wofs[0]) = (ushort)(pk & 0xffffu);   \
            *(ushort*)((char*)&hbuf[WB][0] + wofs[1]) = (ushort)(pk >> 16);       \
        }                                                                         \
        __syncthreads();                                                          \
    }

    for (int t = 0; t < T; t += 2) {
        GSTEP(0, 1, t,     voB, voA)
        GSTEP(1, 0, t + 1, voA, voB)
    }
#undef GSTEP
    // epilogue: store h(T-1)
    {
        float* o = (float*)((char*)outbase + voB);
        o[0] = hp[0];
        o[16] = hp[1];
    }
}

// ---------------- M[b,d,q] = dos[b,d,:] . qos[b,q,:]  (K=512) ----------------
__global__ __launch_bounds__(256) void k_mgemm(const float* __restrict__ dos, const float* __restrict__ qos,
                                               float* __restrict__ Mm) {
    __shared__ float As[16][68];
    __shared__ float Bs[16][68];
    int tid = threadIdx.x;
    int b = blockIdx.y;
    long m0 = (long)blockIdx.x * 64;
    int ml = tid >> 2, el = (tid & 3) << 2;
    const float* arow = dos + ((long)b * DLEN + m0 + ml) * (2 * HID);
    const float* brow = qos + ((long)b * QLEN + ml) * (2 * HID);
    int ty = tid >> 4, tx = tid & 15;
    float acc[4][4] = {};
    for (int kt = 0; kt < 2 * HID; kt += 16) {
        float4 av = *(const float4*)(arow + kt + el);
        float4 bv = *(const float4*)(brow + kt + el);
        __syncthreads();
        As[el + 0][ml] = av.x; As[el + 1][ml] = av.y; As[el + 2][ml] = av.z; As[el + 3][ml] = av.w;
        Bs[el + 0][ml] = bv.x; Bs[el + 1][ml] = bv.y; Bs[el + 2][ml] = bv.z; Bs[el + 3][ml] = bv.w;
        __syncthreads();
#pragma unroll
        for (int k = 0; k < 16; ++k) {
            float4 a4 = *(const float4*)&As[k][ty << 2];
            float4 b4 = *(const float4*)&Bs[k][tx << 2];
            float a[4] = {a4.x, a4.y, a4.z, a4.w};
            float bb[4] = {b4.x, b4.y, b4.z, b4.w};
#pragma unroll
            for (int i = 0; i < 4; ++i)
#pragma unroll
                for (int j = 0; j < 4; ++j)
                    acc[i][j] = fmaf(a[i], bb[j], acc[i][j]);
        }
    }
#pragma unroll
    for (int i = 0; i < 4; ++i) {
        long m = m0 + (ty << 2) + i;
#pragma unroll
        for (int j = 0; j < 4; ++j) {
            int n = (tx << 2) + j;
            Mm[((long)b * DLEN + m) * QLEN + n] = acc[i][j];
        }
    }
}

// ---------------- avg_beta ----------------
__global__ __launch_bounds__(256) void k_avgbeta(const float* __restrict__ Mm, const float* __restrict__ dmask,
                                                 const float* __restrict__ qmask, const int* __restrict__ dlens,
                                                 float* __restrict__ avgb) {
    int b = blockIdx.x, tid = threadIdx.x;
    int lane = tid & 63, wid = tid >> 6;
    float qm = qmask[b * QLEN + lane];
    float acc = 0.f;
    for (int d = wid; d < DLEN; d += 4) {
        float x = Mm[((long)b * DLEN + d) * QLEN + lane];
        float mx = x;
#pragma unroll
        for (int o = 32; o; o >>= 1) mx = fmaxf(mx, __shfl_xor(mx, o));
        float e = expf(x - mx) * dmask[b * DLEN + d] * qm;
        float sm = e;
#pragma unroll
        for (int o = 32; o; o >>= 1) sm += __shfl_xor(sm, o);
        acc += e / (sm + 1e-12f);
    }
    __shared__ float red[4][QLEN];
    red[wid][lane] = acc;
    __syncthreads();
    if (tid < QLEN) {
        float tot = red[0][tid] + red[1][tid] + red[2][tid] + red[3][tid];
        avgb[b * QLEN + tid] = tot / (float)dlens[b];
    }
}

// ---------------- column stats over d ----------------
__global__ __launch_bounds__(256) void k_colstats(const float* __restrict__ Mm, const float* __restrict__ dmask,
                                                  float* __restrict__ mx, float* __restrict__ cs) {
    int b = blockIdx.x, tid = threadIdx.x;
    int q = tid & 63, dg = tid >> 6;
    float m = -INFINITY, ssum = 0.f;
    for (int d = dg; d < DLEN; d += 4) {
        float x = Mm[((long)b * DLEN + d) * QLEN + q];
        float dm = dmask[b * DLEN + d];
        float mn = fmaxf(m, x);
        ssum = ssum * expf(m - mn) + expf(x - mn) * dm;
        m = mn;
    }
    __shared__ float mS[4][QLEN], sS[4][QLEN];
    mS[dg][q] = m; sS[dg][q] = ssum;
    __syncthreads();
    if (tid < QLEN) {
        float M0 = fmaxf(fmaxf(mS[0][tid], mS[1][tid]), fmaxf(mS[2][tid], mS[3][tid]));
        float S = 0.f;
#pragma unroll
        for (int i = 0; i < 4; ++i) S += sS[i][tid] * expf(mS[i][tid] - M0);
        mx[b * QLEN + tid] = M0;
        cs[b * QLEN + tid] = S;
    }
}

// ---------------- s[b,d] ----------------
__global__ __launch_bounds__(256) void k_s(const float* __restrict__ Mm, const float* __restrict__ mxv, const float* __restrict__ cs,
                                           const float* __restrict__ avgb, const float* __restrict__ qmask, const float* __restrict__ dmask,
                                           float* __restrict__ s) {
    int b = blockIdx.y, tid = threadIdx.x;
    __shared__ float wq[QLEN], mxs[QLEN];
    if (tid < QLEN) {
        float part = cs[b * QLEN + tid];
        wq[tid] = (qmask[b * QLEN + tid] > 0.f) ? (avgb[b * QLEN + tid] / (part + 1e-12f)) : 0.f;
        mxs[tid] = mxv[b * QLEN + tid];
    }
    __syncthreads();
    long d = (long)blockIdx.x * 256 + tid;
    const float* row = Mm + ((long)b * DLEN + d) * QLEN;
    float acc = 0.f;
#pragma unroll
    for (int q = 0; q < QLEN; q += 4) {
        float4 v = *(const float4*)(row + q);
        acc += expf(v.x - mxs[q + 0]) * wq[q + 0];
        acc += expf(v.y - mxs[q + 1]) * wq[q + 1];
        acc += expf(v.z - mxs[q + 2]) * wq[q + 2];
        acc += expf(v.w - mxs[q + 3]) * wq[q + 3];
    }
    s[b * DLEN + d] = dmask[b * DLEN + d] * acc;
}

// ---------------- final ----------------
__global__ __launch_bounds__(256) void k_final(const float* __restrict__ s, const int* __restrict__ doc,
                                               const int* __restrict__ cand, const int* __restrict__ ans,
                                               float* __restrict__ out) {
    int b = blockIdx.x, tid = threadIdx.x;
    __shared__ int lc[NCAND];
    __shared__ int la;
    __shared__ float red[4][NCAND + 1];
    if (tid < NCAND) lc[tid] = cand[b * NCAND + tid];
    if (tid == NCAND) la = ans[b];
    __syncthreads();
    float accs[NCAND + 1] = {};
    for (int d = tid; d < DLEN; d += 256) {
        int tk = doc[b * DLEN + d];
        float sv = s[b * DLEN + d];
#pragma unroll
        for (int c = 0; c < NCAND; ++c)
            if (tk == lc[c]) accs[c] += sv;
        if (tk == la) accs[NCAND] += sv;
    }
    int lane = tid & 63, wid = tid >> 6;
#pragma unroll
    for (int i = 0; i <= NCAND; ++i) {
        float v = accs[i];
#pragma unroll
        for (int o = 32; o; o >>= 1) v += __shfl_xor(v, o);
        if (lane == 0) red[wid][i] = v;
    }
    __syncthreads();
    if (tid == 0) {
        float cp[NCAND + 1];
#pragma unroll
        for (int i = 0; i <= NCAND; ++i) cp[i] = red[0][i] + red[1][i] + red[2][i] + red[3][i];
        int loc = 0; float best = cp[0];
#pragma unroll
        for (int c = 1; c < NCAND; ++c) if (cp[c] > best) { best = cp[c]; loc = c; }
        out[b] = (float)lc[loc];
        out[BATCH + b] = (float)loc;
        out[2 * BATCH + b] = cp[NCAND];
    }
}

__global__ void k_zero_out(float* out, int n) {
    int i = blockIdx.x * 256 + threadIdx.x;
    if (i < n) out[i] = 0.f;
}

extern "C" void kernel_launch(void* const* d_in, const int* in_sizes, int n_in,
                              void* d_out, int out_size, void* d_ws, size_t ws_size,
                              hipStream_t stream) {
    const int*   docs_input   = (const int*)d_in[0];
    const int*   docs_len     = (const int*)d_in[1];
    const float* doc_mask     = (const float*)d_in[2];
    const int*   querys_input = (const int*)d_in[3];
    const int*   querys_len   = (const int*)d_in[4];
    const float* query_mask   = (const float*)d_in[5];
    const int*   candidates   = (const int*)d_in[6];
    const int*   answers      = (const int*)d_in[7];
    const float* embedding    = (const float*)d_in[8];
    const float* w_ih_f = (const float*)d_in[9];
    const float* w_hh_f = (const float*)d_in[10];
    const float* b_ih_f = (const float*)d_in[11];
    const float* b_hh_f = (const float*)d_in[12];
    const float* w_ih_b = (const float*)d_in[13];
    const float* w_hh_b = (const float*)d_in[14];
    const float* b_ih_b = (const float*)d_in[15];
    const float* b_hh_b = (const float*)d_in[16];

    char* ws = (char*)d_ws;
    size_t off = 0;
    auto alloc = [&](size_t bytes) { size_t o = off; off = (off + bytes + 255) & ~(size_t)255; return o; };
    ushort* wprep = (ushort*)(ws + alloc((size_t)2 * 196608 * 2));
    float*  beff  = (float*)(ws + alloc((size_t)2 * G3 * 4));
    ushort* gxq_f = (ushort*)(ws + alloc((size_t)BATCH * QLEN * 1024 * 2));
    ushort* gxq_b = (ushort*)(ws + alloc((size_t)BATCH * QLEN * 1024 * 2));
    ushort* gxd_f = (ushort*)(ws + alloc((size_t)BATCH * DLEN * 1024 * 2));
    ushort* gxd_b = (ushort*)(ws + alloc((size_t)BATCH * DLEN * 1024 * 2));
    float* dosb  = (float*)(ws + alloc((size_t)BATCH * DLEN * 2 * HID * 4));
    float* qosb  = (float*)(ws + alloc((size_t)BATCH * QLEN * 2 * HID * 4));
    float* Mbuf  = (float*)(ws + alloc((size_t)BATCH * DLEN * QLEN * 4));
    float* avgb  = (float*)(ws + alloc((size_t)BATCH * QLEN * 4));
    float* mxb   = (float*)(ws + alloc((size_t)BATCH * QLEN * 4));
    float* csb   = (float*)(ws + alloc((size_t)BATCH * QLEN * 4));
    float* sbuf  = (float*)(ws + alloc((size_t)BATCH * DLEN * 4));

    if (ws_size < off) {
        k_zero_out<<<1, 256, 0, stream>>>((float*)d_out, out_size);
        return;
    }

    // effective biases (b_ih + b_hh for r/z) and weight fragments
    k_bias<<<6, 256, 0, stream>>>(b_ih_f, b_hh_f, b_ih_b, b_hh_b, beff);
    k_prep<<<1536, 256, 0, stream>>>(w_hh_f, w_hh_b, wprep);

    // gx for queries and docs, both directions (MFMA bf16, lane-major 16B-slot out)
    k_gx<<<dim3(12, (BATCH * QLEN) / 64, 2), 256, 0, stream>>>(querys_input, embedding,
        w_ih_f, beff, gxq_f, w_ih_b, beff + G3, gxq_b);
    k_gx<<<dim3(12, (BATCH * DLEN) / 64, 2), 256, 0, stream>>>(docs_input, embedding,
        w_ih_f, beff, gxd_f, w_ih_b, beff + G3, gxd_b);

    // all four BiGRU scans (doc/query x fwd/bwd), batch split in groups of 4
    k_gru5<<<32, 512, 0, stream>>>(gxd_f, gxd_b, gxq_f, gxq_b, wprep,
                                   b_hh_f, b_hh_b, docs_len, querys_len, dosb, qosb);

    // attention-over-attention
    k_mgemm<<<dim3(DLEN / 64, BATCH), 256, 0, stream>>>(dosb, qosb, Mbuf);
    k_avgbeta<<<BATCH, 256, 0, stream>>>(Mbuf, doc_mask, query_mask, docs_len, avgb);
    k_colstats<<<BATCH, 256, 0, stream>>>(Mbuf, doc_mask, mxb, csb);
    k_s<<<dim3(DLEN / 256, BATCH), 256, 0, stream>>>(Mbuf, mxb, csb, avgb, query_mask, doc_mask, sbuf);
    k_final<<<BATCH, 256, 0, stream>>>(sbuf, docs_input, candidates, answers, (float*)d_out);
}

// Round 14
// 1858.923 us; speedup vs baseline: 2.8300x; 1.0260x over previous
//
#include <hip/hip_runtime.h>
#include <hip/hip_bf16.h>
#include <math.h>

// AoA Reader v11 (resubmit after infra failure): r12 base + ALL 6 weight tiles
// register-resident (AGPR unified file). LDS = 16KB hbuf only.
// V=50000 E=384 H=256 B=32 D=1024 Q=64 C=10.
#define BATCH 32
#define DLEN 1024
#define QLEN 64
#define EMB 384
#define HID 256
#define G3 768   // 3*H
#define NCAND 10

typedef __attribute__((ext_vector_type(8))) short bf16x8;
typedef __attribute__((ext_vector_type(8))) unsigned short u16x8;
typedef __attribute__((ext_vector_type(4))) float f32x4;
#define MFMA16 __builtin_amdgcn_mfma_f32_16x16x32_bf16

__device__ __forceinline__ float bf2f(ushort u) {
    union { float f; unsigned v; } x; x.v = ((unsigned)u) << 16; return x.f;
}
__device__ __forceinline__ ushort f2bf(float f) {
    union { float f; unsigned v; } x; x.f = f;
    unsigned r = x.v + 0x7FFF + ((x.v >> 16) & 1);
    return (ushort)(r >> 16);
}
__device__ __forceinline__ float sigf(float x) {
    return __builtin_amdgcn_rcpf(1.f + __expf(-x));
}
__device__ __forceinline__ float tanhf_(float x) {
    return 1.f - 2.f * __builtin_amdgcn_rcpf(1.f + __expf(2.f * x));
}
__device__ __forceinline__ bf16x8 cvt8(float4 a, float4 b) {
    union { unsigned u[4]; bf16x8 v; } r;
    asm("v_cvt_pk_bf16_f32 %0, %1, %2" : "=v"(r.u[0]) : "v"(a.x), "v"(a.y));
    asm("v_cvt_pk_bf16_f32 %0, %1, %2" : "=v"(r.u[1]) : "v"(a.z), "v"(a.w));
    asm("v_cvt_pk_bf16_f32 %0, %1, %2" : "=v"(r.u[2]) : "v"(b.x), "v"(b.y));
    asm("v_cvt_pk_bf16_f32 %0, %1, %2" : "=v"(r.u[3]) : "v"(b.z), "v"(b.w));
    return r.v;
}

// ---------------- bias_eff[dir][768]: b_ih + (b_hh for r,z gates only) ----------------
__global__ __launch_bounds__(256) void k_bias(const float* __restrict__ bihf, const float* __restrict__ bhhf,
                                              const float* __restrict__ bihb, const float* __restrict__ bhhb,
                                              float* __restrict__ be) {
    int n = blockIdx.x * 256 + threadIdx.x;
    if (n >= 1536) return;
    int dir = n / G3, c = n - dir * G3;
    const float* bih = dir ? bihb : bihf;
    const float* bhh = dir ? bhhb : bhhf;
    be[n] = bih[c] + (c < 512 ? bhh[c] : 0.f);
}

// ---------------- prep: w_hh (768x256 f32) -> bf16 MFMA B-fragment order ----------------
// layout: [dir][wave(8)][tile(6)][ks(8)][lane(64)][e(8)] bf16; per dir 196608 elems.
__global__ __launch_bounds__(256) void k_prep(const float* __restrict__ whf, const float* __restrict__ whb,
                                              ushort* __restrict__ wprep) {
    int idx = blockIdx.x * 256 + threadIdx.x;   // < 393216
    int dir = idx / 196608;
    int r = idx - dir * 196608;
    int wv = r / 24576;  int r2 = r - wv * 24576;
    int tile = r2 / 4096; int r3 = r2 - tile * 4096;
    int ks = r3 / 512;    int r4 = r3 - ks * 512;
    int lane = r4 >> 3;   int e = r4 & 7;
    int g = (tile >> 1) * 256 + wv * 32 + (tile & 1) * 16 + (lane & 15);
    int k = ks * 32 + (lane >> 4) * 8 + e;
    const float* w = dir ? whb : whf;
    wprep[idx] = f2bf(w[g * 256 + k]);
}

// ---------------- gx GEMM with gather, MFMA bf16 (fp32 accum, bf16 lane-major 16B-slot out) ----------------
__global__ __launch_bounds__(256) void k_gx(const int* __restrict__ tokens,
                                            const float* __restrict__ emb,
                                            const float* __restrict__ w0, const float* __restrict__ bias0, ushort* __restrict__ out0,
                                            const float* __restrict__ w1, const float* __restrict__ bias1, ushort* __restrict__ out1) {
    __shared__ ushort Asl[64][392];              // 384 k + 8 pad, 50 KB
    const float* w   = blockIdx.z ? w1 : w0;
    const float* bia = blockIdx.z ? bias1 : bias0;
    ushort* out      = blockIdx.z ? out1 : out0;
    int tid = threadIdx.x;
    int n0 = blockIdx.x * 64;
    long m0 = (long)blockIdx.y * 64;
    int wv = tid >> 6;
    int lane = tid & 63;
    int l15 = lane & 15;
    int lhi = lane >> 4;

    // ---- stage A: 4 threads/row, each 12x8 floats -> bf16 ----
    {
        int row = tid >> 2, kq = tid & 3;
        long tok = tokens[m0 + row];
        const float* ar = emb + tok * EMB + kq * 96;
#pragma unroll
        for (int it = 0; it < 12; ++it) {
            float4 a = *(const float4*)(ar + it * 8);
            float4 b = *(const float4*)(ar + it * 8 + 4);
            *(bf16x8*)&Asl[row][kq * 96 + it * 8] = cvt8(a, b);
        }
    }
    __syncthreads();

    // ---- compute: wave wv = n-tile; 4 m-subtiles ----
    int n = n0 + wv * 16 + l15;
    const float* brow = w + (long)n * EMB;
    f32x4 acc[4] = {};
#pragma unroll
    for (int ks = 0; ks < 12; ++ks) {
        float4 b0 = *(const float4*)(brow + ks * 32 + lhi * 8);
        float4 b1 = *(const float4*)(brow + ks * 32 + lhi * 8 + 4);
        bf16x8 bf = cvt8(b0, b1);
#pragma unroll
        for (int mt = 0; mt < 4; ++mt) {
            bf16x8 a = *(const bf16x8*)&Asl[mt * 16 + l15][ks * 32 + lhi * 8];
            acc[mt] = MFMA16(a, bf, acc[mt], 0, 0, 0);
        }
    }

    // ---- epilogue: bias + permuted bf16 store ----
    float bias = bia[n];
    int gi = n >> 8, c = n & 255;
    int wvv = c >> 5, p = (c >> 4) & 1, fl = c & 15;
    int sidx = wvv * 128 + fl * 8 + p * 3 + gi;
#pragma unroll
    for (int mt = 0; mt < 4; ++mt)
#pragma unroll
        for (int r = 0; r < 4; ++r) {
            long m = m0 + mt * 16 + lhi * 4 + r;
            out[m * 1024 + sidx] = f2bf(acc[mt][r] + bias);
        }
}

// ---------------- MFMA GRU: grid 32 = (bgroup(8), dir(2), seq(2)). 512 thr = 8 waves. ----------------
// nb=4 batches per WG, batch b -> row 4b (valid C row => reg 0 at compile time).
// ALL 6 B-tiles in registers (AGPR). LDS = 16KB h dbuf only.
__global__ __attribute__((amdgpu_flat_work_group_size(512, 512), amdgpu_waves_per_eu(2, 2)))
void k_gru5(
    const ushort* __restrict__ gxd_f, const ushort* __restrict__ gxd_b,
    const ushort* __restrict__ gxq_f, const ushort* __restrict__ gxq_b,
    const ushort* __restrict__ wprep,
    const float* __restrict__ bhh_f, const float* __restrict__ bhh_b,
    const int* __restrict__ dlens, const int* __restrict__ qlens,
    float* __restrict__ dosb, float* __restrict__ qosb)
{
    int wg = blockIdx.x;
    int bgroup = wg & 7;
    int dir = (wg >> 3) & 1;
    int seq = wg >> 4;                   // 0=doc, 1=query
    int T = seq ? QLEN : DLEN;
    const ushort* gx = seq ? (dir ? gxq_b : gxq_f) : (dir ? gxd_b : gxd_f);
    const float* bhh = dir ? bhh_b : bhh_f;
    const int* lens = seq ? qlens : dlens;
    float* outbase = (seq ? qosb : dosb) + dir * HID;
    int boff = bgroup * 4;

    int tid = threadIdx.x;
    int wv = tid >> 6;
    int lane = tid & 63;
    int l15 = lane & 15;
    int lhi = lane >> 4;                 // 0..3 = local batch
    int jw = wv * 32;

    __shared__ ushort hbuf[2][4096];     // 16 KB bf16 h, swizzled, dbuf

    // ---- resident weights: ALL 6 tiles in registers (192 regs, AGPR-eligible) ----
    const ushort* wp = wprep + (size_t)dir * 196608;
    bf16x8 B0[8], B1[8], B2[8], B3[8], B4[8], B5[8];
#pragma unroll
    for (int ks = 0; ks < 8; ++ks) {
        B0[ks] = *(const bf16x8*)(wp + ((((wv * 6 + 0) * 8 + ks) * 64 + lane) * 8));
        B1[ks] = *(const bf16x8*)(wp + ((((wv * 6 + 1) * 8 + ks) * 64 + lane) * 8));
        B2[ks] = *(const bf16x8*)(wp + ((((wv * 6 + 2) * 8 + ks) * 64 + lane) * 8));
        B3[ks] = *(const bf16x8*)(wp + ((((wv * 6 + 3) * 8 + ks) * 64 + lane) * 8));
        B4[ks] = *(const bf16x8*)(wp + ((((wv * 6 + 4) * 8 + ks) * 64 + lane) * 8));
        B5[ks] = *(const bf16x8*)(wp + ((((wv * 6 + 5) * 8 + ks) * 64 + lane) * 8));
    }

    float bhn0 = bhh[512 + jw + l15];
    float bhn1 = bhh[512 + jw + 16 + l15];
    int len = lens[boff + lhi];
    float hp[2] = {};                    // [p]

    // ---- precomputed static addresses (t-invariant) ----
    int a_addr[8];
#pragma unroll
    for (int ks = 0; ks < 8; ++ks)
        a_addr[ks] = l15 * 512 + (((ks * 4 + lhi) ^ (l15 & 7)) * 16);
    int wofs[2];                         // [p]; row = 4*lhi
#pragma unroll
    for (int p = 0; p < 2; ++p) {
        int row = lhi * 4, j = jw + p * 16 + l15;
        wofs[p] = (row * 256 + (((j >> 3) ^ (row & 7)) * 8) + (j & 7)) * 2;
    }
    int b = boff + lhi;
    int lbg = b * T * 2048 + wv * 256 + l15 * 16;   // gx: 1024-ushort rows, 16B slots
    int lbo = b * T * 2048 + (jw + l15) * 4;        // out: 512-f32 rows

    for (int x = tid; x < 4096; x += 512) hbuf[0][x] = 0;   // rows %4!=0 stay 0 forever
    __syncthreads();

    int voA, voB;

#define GSTEP(RB, WB, TT, VPRE, VCUR)                                             \
    {                                                                             \
        int p_ = (TT);                                                            \
        if (dir) p_ = ((TT) < len) ? (len - 1 - (TT)) : (TT);                     \
        u16x8 gxu = *(const u16x8*)((const char*)gx + (lbg + p_ * 2048));         \
        VCUR = lbo + p_ * 2048;                                                   \
        if ((TT) != 0) {                                                          \
            float* o = (float*)((char*)outbase + VPRE);                           \
            o[0] = hp[0];                                                         \
            o[16] = hp[1];                                                        \
        }                                                                         \
        f32x4 acc0 = {0.f,0.f,0.f,0.f}, acc1 = acc0, acc2 = acc0, acc3 = acc0;    \
        f32x4 acc4 = {bhn0, bhn0, bhn0, bhn0};                                    \
        f32x4 acc5 = {bhn1, bhn1, bhn1, bhn1};                                    \
        _Pragma("unroll")                                                         \
        for (int ks = 0; ks < 8; ++ks) {                                          \
            bf16x8 a = *(const bf16x8*)((const char*)&hbuf[RB][0] + a_addr[ks]);  \
            acc0 = MFMA16(a, B0[ks], acc0, 0, 0, 0);                              \
            acc1 = MFMA16(a, B1[ks], acc1, 0, 0, 0);                              \
            acc2 = MFMA16(a, B2[ks], acc2, 0, 0, 0);                              \
            acc3 = MFMA16(a, B3[ks], acc3, 0, 0, 0);                              \
            acc4 = MFMA16(a, B4[ks], acc4, 0, 0, 0);                              \
            acc5 = MFMA16(a, B5[ks], acc5, 0, 0, 0);                              \
        }                                                                         \
        {                                                                         \
            float h2[2];                                                          \
            _Pragma("unroll")                                                     \
            for (int p = 0; p < 2; ++p) {                                         \
                float ar = p ? acc1[0] : acc0[0];                                 \
                float az = p ? acc3[0] : acc2[0];                                 \
                float an = p ? acc5[0] : acc4[0];                                 \
                float rx = bf2f(gxu[p * 3 + 0]);                                  \
                float zx = bf2f(gxu[p * 3 + 1]);                                  \
                float nx = bf2f(gxu[p * 3 + 2]);                                  \
                float r = sigf(rx + ar);                                          \
                float z = sigf(zx + az);                                          \
                float nn = tanhf_(nx + r * an);                                   \
                float h = (1.f - z) * nn + z * hp[p];                             \
                hp[p] = h;                                                        \
                h2[p] = h;                                                        \
            }                                                                     \
            unsigned pk;                                                          \
            asm("v_cvt_pk_bf16_f32 %0, %1, %2" : "=v"(pk) : "v"(h2[0]), "v"(h2[1])); \
            *(ushort*)((char*)&hbuf[WB][0] + wofs[0]) = (ushort)(pk & 0xffffu);   \
            *(ushort*)((char*)&hbuf[WB][0] + wofs[1]) = (ushort)(pk >> 16);       \
        }                                                                         \
        __syncthreads();                                                          \
    }

    for (int t = 0; t < T; t += 2) {
        GSTEP(0, 1, t,     voB, voA)
        GSTEP(1, 0, t + 1, voA, voB)
    }
#undef GSTEP
    // epilogue: store h(T-1)
    {
        float* o = (float*)((char*)outbase + voB);
        o[0] = hp[0];
        o[16] = hp[1];
    }
}

// ---------------- M[b,d,q] = dos[b,d,:] . qos[b,q,:]  (K=512) ----------------
__global__ __launch_bounds__(256) void k_mgemm(const float* __restrict__ dos, const float* __restrict__ qos,
                                               float* __restrict__ Mm) {
    __shared__ float As[16][68];
    __shared__ float Bs[16][68];
    int tid = threadIdx.x;
    int b = blockIdx.y;
    long m0 = (long)blockIdx.x * 64;
    int ml = tid >> 2, el = (tid & 3) << 2;
    const float* arow = dos + ((long)b * DLEN + m0 + ml) * (2 * HID);
    const float* brow = qos + ((long)b * QLEN + ml) * (2 * HID);
    int ty = tid >> 4, tx = tid & 15;
    float acc[4][4] = {};
    for (int kt = 0; kt < 2 * HID; kt += 16) {
        float4 av = *(const float4*)(arow + kt + el);
        float4 bv = *(const float4*)(brow + kt + el);
        __syncthreads();
        As[el + 0][ml] = av.x; As[el + 1][ml] = av.y; As[el + 2][ml] = av.z; As[el + 3][ml] = av.w;
        Bs[el + 0][ml] = bv.x; Bs[el + 1][ml] = bv.y; Bs[el + 2][ml] = bv.z; Bs[el + 3][ml] = bv.w;
        __syncthreads();
#pragma unroll
        for (int k = 0; k < 16; ++k) {
            float4 a4 = *(const float4*)&As[k][ty << 2];
            float4 b4 = *(const float4*)&Bs[k][tx << 2];
            float a[4] = {a4.x, a4.y, a4.z, a4.w};
            float bb[4] = {b4.x, b4.y, b4.z, b4.w};
#pragma unroll
            for (int i = 0; i < 4; ++i)
#pragma unroll
                for (int j = 0; j < 4; ++j)
                    acc[i][j] = fmaf(a[i], bb[j], acc[i][j]);
        }
    }
#pragma unroll
    for (int i = 0; i < 4; ++i) {
        long m = m0 + (ty << 2) + i;
#pragma unroll
        for (int j = 0; j < 4; ++j) {
            int n = (tx << 2) + j;
            Mm[((long)b * DLEN + m) * QLEN + n] = acc[i][j];
        }
    }
}

// ---------------- avg_beta ----------------
__global__ __launch_bounds__(256) void k_avgbeta(const float* __restrict__ Mm, const float* __restrict__ dmask,
                                                 const float* __restrict__ qmask, const int* __restrict__ dlens,
                                                 float* __restrict__ avgb) {
    int b = blockIdx.x, tid = threadIdx.x;
    int lane = tid & 63, wid = tid >> 6;
    float qm = qmask[b * QLEN + lane];
    float acc = 0.f;
    for (int d = wid; d < DLEN; d += 4) {
        float x = Mm[((long)b * DLEN + d) * QLEN + lane];
        float mx = x;
#pragma unroll
        for (int o = 32; o; o >>= 1) mx = fmaxf(mx, __shfl_xor(mx, o));
        float e = expf(x - mx) * dmask[b * DLEN + d] * qm;
        float sm = e;
#pragma unroll
        for (int o = 32; o; o >>= 1) sm += __shfl_xor(sm, o);
        acc += e / (sm + 1e-12f);
    }
    __shared__ float red[4][QLEN];
    red[wid][lane] = acc;
    __syncthreads();
    if (tid < QLEN) {
        float tot = red[0][tid] + red[1][tid] + red[2][tid] + red[3][tid];
        avgb[b * QLEN + tid] = tot / (float)dlens[b];
    }
}

// ---------------- column stats over d ----------------
__global__ __launch_bounds__(256) void k_colstats(const float* __restrict__ Mm, const float* __restrict__ dmask,
                                                  float* __restrict__ mx, float* __restrict__ cs) {
    int b = blockIdx.x, tid = threadIdx.x;
    int q = tid & 63, dg = tid >> 6;
    float m = -INFINITY, ssum = 0.f;
    for (int d = dg; d < DLEN; d += 4) {
        float x = Mm[((long)b * DLEN + d) * QLEN + q];
        float dm = dmask[b * DLEN + d];
        float mn = fmaxf(m, x);
        ssum = ssum * expf(m - mn) + expf(x - mn) * dm;
        m = mn;
    }
    __shared__ float mS[4][QLEN], sS[4][QLEN];
    mS[dg][q] = m; sS[dg][q] = ssum;
    __syncthreads();
    if (tid < QLEN) {
        float M0 = fmaxf(fmaxf(mS[0][tid], mS[1][tid]), fmaxf(mS[2][tid], mS[3][tid]));
        float S = 0.f;
#pragma unroll
        for (int i = 0; i < 4; ++i) S += sS[i][tid] * expf(mS[i][tid] - M0);
        mx[b * QLEN + tid] = M0;
        cs[b * QLEN + tid] = S;
    }
}

// ---------------- s[b,d] ----------------
__global__ __launch_bounds__(256) void k_s(const float* __restrict__ Mm, const float* __restrict__ mxv, const float* __restrict__ cs,
                                           const float* __restrict__ avgb, const float* __restrict__ qmask, const float* __restrict__ dmask,
                                           float* __restrict__ s) {
    int b = blockIdx.y, tid = threadIdx.x;
    __shared__ float wq[QLEN], mxs[QLEN];
    if (tid < QLEN) {
        float part = cs[b * QLEN + tid];
        wq[tid] = (qmask[b * QLEN + tid] > 0.f) ? (avgb[b * QLEN + tid] / (part + 1e-12f)) : 0.f;
        mxs[tid] = mxv[b * QLEN + tid];
    }
    __syncthreads();
    long d = (long)blockIdx.x * 256 + tid;
    const float* row = Mm + ((long)b * DLEN + d) * QLEN;
    float acc = 0.f;
#pragma unroll
    for (int q = 0; q < QLEN; q += 4) {
        float4 v = *(const float4*)(row + q);
        acc += expf(v.x - mxs[q + 0]) * wq[q + 0];
        acc += expf(v.y - mxs[q + 1]) * wq[q + 1];
        acc += expf(v.z - mxs[q + 2]) * wq[q + 2];
        acc += expf(v.w - mxs[q + 3]) * wq[q + 3];
    }
    s[b * DLEN + d] = dmask[b * DLEN + d] * acc;
}

// ---------------- final ----------------
__global__ __launch_bounds__(256) void k_final(const float* __restrict__ s, const int* __restrict__ doc,
                                               const int* __restrict__ cand, const int* __restrict__ ans,
                                               float* __restrict__ out) {
    int b = blockIdx.x, tid = threadIdx.x;
    __shared__ int lc[NCAND];
    __shared__ int la;
    __shared__ float red[4][NCAND + 1];
    if (tid < NCAND) lc[tid] = cand[b * NCAND + tid];
    if (tid == NCAND) la = ans[b];
    __syncthreads();
    float accs[NCAND + 1] = {};
    for (int d = tid; d < DLEN; d += 256) {
        int tk = doc[b * DLEN + d];
        float sv = s[b * DLEN + d];
#pragma unroll
        for (int c = 0; c < NCAND; ++c)
            if (tk == lc[c]) accs[c] += sv;
        if (tk == la) accs[NCAND] += sv;
    }
    int lane = tid & 63, wid = tid >> 6;
#pragma unroll
    for (int i = 0; i <= NCAND; ++i) {
        float v = accs[i];
#pragma unroll
        for (int o = 32; o; o >>= 1) v += __shfl_xor(v, o);
        if (lane == 0) red[wid][i] = v;
    }
    __syncthreads();
    if (tid == 0) {
        float cp[NCAND + 1];
#pragma unroll
        for (int i = 0; i <= NCAND; ++i) cp[i] = red[0][i] + red[1][i] + red[2][i] + red[3][i];
        int loc = 0; float best = cp[0];
#pragma unroll
        for (int c = 1; c < NCAND; ++c) if (cp[c] > best) { best = cp[c]; loc = c; }
        out[b] = (float)lc[loc];
        out[BATCH + b] = (float)loc;
        out[2 * BATCH + b] = cp[NCAND];
    }
}

__global__ void k_zero_out(float* out, int n) {
    int i = blockIdx.x * 256 + threadIdx.x;
    if (i < n) out[i] = 0.f;
}

extern "C" void kernel_launch(void* const* d_in, const int* in_sizes, int n_in,
                              void* d_out, int out_size, void* d_ws, size_t ws_size,
                              hipStream_t stream) {
    const int*   docs_input   = (const int*)d_in[0];
    const int*   docs_len     = (const int*)d_in[1];
    const float* doc_mask     = (const float*)d_in[2];
    const int*   querys_input = (const int*)d_in[3];
    const int*   querys_len   = (const int*)d_in[4];
    const float* query_mask   = (const float*)d_in[5];
    const int*   candidates   = (const int*)d_in[6];
    const int*   answers      = (const int*)d_in[7];
    const float* embedding    = (const float*)d_in[8];
    const float* w_ih_f = (const float*)d_in[9];
    const float* w_hh_f = (const float*)d_in[10];
    const float* b_ih_f = (const float*)d_in[11];
    const float* b_hh_f = (const float*)d_in[12];
    const float* w_ih_b = (const float*)d_in[13];
    const float* w_hh_b = (const float*)d_in[14];
    const float* b_ih_b = (const float*)d_in[15];
    const float* b_hh_b = (const float*)d_in[16];

    char* ws = (char*)d_ws;
    size_t off = 0;
    auto alloc = [&](size_t bytes) { size_t o = off; off = (off + bytes + 255) & ~(size_t)255; return o; };
    ushort* wprep = (ushort*)(ws + alloc((size_t)2 * 196608 * 2));
    float*  beff  = (float*)(ws + alloc((size_t)2 * G3 * 4));
    ushort* gxq_f = (ushort*)(ws + alloc((size_t)BATCH * QLEN * 1024 * 2));
    ushort* gxq_b = (ushort*)(ws + alloc((size_t)BATCH * QLEN * 1024 * 2));
    ushort* gxd_f = (ushort*)(ws + alloc((size_t)BATCH * DLEN * 1024 * 2));
    ushort* gxd_b = (ushort*)(ws + alloc((size_t)BATCH * DLEN * 1024 * 2));
    float* dosb  = (float*)(ws + alloc((size_t)BATCH * DLEN * 2 * HID * 4));
    float* qosb  = (float*)(ws + alloc((size_t)BATCH * QLEN * 2 * HID * 4));
    float* Mbuf  = (float*)(ws + alloc((size_t)BATCH * DLEN * QLEN * 4));
    float* avgb  = (float*)(ws + alloc((size_t)BATCH * QLEN * 4));
    float* mxb   = (float*)(ws + alloc((size_t)BATCH * QLEN * 4));
    float* csb   = (float*)(ws + alloc((size_t)BATCH * QLEN * 4));
    float* sbuf  = (float*)(ws + alloc((size_t)BATCH * DLEN * 4));

    if (ws_size < off) {
        k_zero_out<<<1, 256, 0, stream>>>((float*)d_out, out_size);
        return;
    }

    // effective biases (b_ih + b_hh for r/z) and weight fragments
    k_bias<<<6, 256, 0, stream>>>(b_ih_f, b_hh_f, b_ih_b, b_hh_b, beff);
    k_prep<<<1536, 256, 0, stream>>>(w_hh_f, w_hh_b, wprep);

    // gx for queries and docs, both directions (MFMA bf16, lane-major 16B-slot out)
    k_gx<<<dim3(12, (BATCH * QLEN) / 64, 2), 256, 0, stream>>>(querys_input, embedding,
        w_ih_f, beff, gxq_f, w_ih_b, beff + G3, gxq_b);
    k_gx<<<dim3(12, (BATCH * DLEN) / 64, 2), 256, 0, stream>>>(docs_input, embedding,
        w_ih_f, beff, gxd_f, w_ih_b, beff + G3, gxd_b);

    // all four BiGRU scans (doc/query x fwd/bwd), batch split in groups of 4
    k_gru5<<<32, 512, 0, stream>>>(gxd_f, gxd_b, gxq_f, gxq_b, wprep,
                                   b_hh_f, b_hh_b, docs_len, querys_len, dosb, qosb);

    // attention-over-attention
    k_mgemm<<<dim3(DLEN / 64, BATCH), 256, 0, stream>>>(dosb, qosb, Mbuf);
    k_avgbeta<<<BATCH, 256, 0, stream>>>(Mbuf, doc_mask, query_mask, docs_len, avgb);
    k_colstats<<<BATCH, 256, 0, stream>>>(Mbuf, doc_mask, mxb, csb);
    k_s<<<dim3(DLEN / 256, BATCH), 256, 0, stream>>>(Mbuf, mxb, csb, avgb, query_mask, doc_mask, sbuf);
    k_final<<<BATCH, 256, 0, stream>>>(sbuf, docs_input, candidates, answers, (float*)d_out);
}

// Round 15
// 1767.567 us; speedup vs baseline: 2.9762x; 1.0517x over previous
//
#include <hip/hip_runtime.h>
#include <hip/hip_bf16.h>
#include <math.h>

// AoA Reader v12: nb=2 GRU (1 triple/lane, h row-duplicated), MFMA k_mgemm (bf16 LDS
// swizzled), fused attention epilogue k_aoa. V=50000 E=384 H=256 B=32 D=1024 Q=64 C=10.
#define BATCH 32
#define DLEN 1024
#define QLEN 64
#define EMB 384
#define HID 256
#define G3 768   // 3*H
#define NCAND 10

typedef __attribute__((ext_vector_type(8))) short bf16x8;
typedef __attribute__((ext_vector_type(8))) unsigned short u16x8;
typedef __attribute__((ext_vector_type(4))) float f32x4;
#define MFMA16 __builtin_amdgcn_mfma_f32_16x16x32_bf16

__device__ __forceinline__ float bf2f(ushort u) {
    union { float f; unsigned v; } x; x.v = ((unsigned)u) << 16; return x.f;
}
__device__ __forceinline__ ushort f2bf(float f) {
    union { float f; unsigned v; } x; x.f = f;
    unsigned r = x.v + 0x7FFF + ((x.v >> 16) & 1);
    return (ushort)(r >> 16);
}
__device__ __forceinline__ float sigf(float x) {
    return __builtin_amdgcn_rcpf(1.f + __expf(-x));
}
__device__ __forceinline__ float tanhf_(float x) {
    return 1.f - 2.f * __builtin_amdgcn_rcpf(1.f + __expf(2.f * x));
}
__device__ __forceinline__ bf16x8 cvt8(float4 a, float4 b) {
    union { unsigned u[4]; bf16x8 v; } r;
    asm("v_cvt_pk_bf16_f32 %0, %1, %2" : "=v"(r.u[0]) : "v"(a.x), "v"(a.y));
    asm("v_cvt_pk_bf16_f32 %0, %1, %2" : "=v"(r.u[1]) : "v"(a.z), "v"(a.w));
    asm("v_cvt_pk_bf16_f32 %0, %1, %2" : "=v"(r.u[2]) : "v"(b.x), "v"(b.y));
    asm("v_cvt_pk_bf16_f32 %0, %1, %2" : "=v"(r.u[3]) : "v"(b.z), "v"(b.w));
    return r.v;
}

// ---------------- bias_eff[dir][768]: b_ih + (b_hh for r,z gates only) ----------------
__global__ __launch_bounds__(256) void k_bias(const float* __restrict__ bihf, const float* __restrict__ bhhf,
                                              const float* __restrict__ bihb, const float* __restrict__ bhhb,
                                              float* __restrict__ be) {
    int n = blockIdx.x * 256 + threadIdx.x;
    if (n >= 1536) return;
    int dir = n / G3, c = n - dir * G3;
    const float* bih = dir ? bihb : bihf;
    const float* bhh = dir ? bhhb : bhhf;
    be[n] = bih[c] + (c < 512 ? bhh[c] : 0.f);
}

// ---------------- prep: w_hh (768x256 f32) -> bf16 MFMA B-fragment order ----------------
__global__ __launch_bounds__(256) void k_prep(const float* __restrict__ whf, const float* __restrict__ whb,
                                              ushort* __restrict__ wprep) {
    int idx = blockIdx.x * 256 + threadIdx.x;   // < 393216
    int dir = idx / 196608;
    int r = idx - dir * 196608;
    int wv = r / 24576;  int r2 = r - wv * 24576;
    int tile = r2 / 4096; int r3 = r2 - tile * 4096;
    int ks = r3 / 512;    int r4 = r3 - ks * 512;
    int lane = r4 >> 3;   int e = r4 & 7;
    int g = (tile >> 1) * 256 + wv * 32 + (tile & 1) * 16 + (lane & 15);
    int k = ks * 32 + (lane >> 4) * 8 + e;
    const float* w = dir ? whb : whf;
    wprep[idx] = f2bf(w[g * 256 + k]);
}

// ---------------- gx GEMM with gather, MFMA bf16 (fp32 accum, bf16 lane-major 16B-slot out) ----------------
__global__ __launch_bounds__(256) void k_gx(const int* __restrict__ tokens,
                                            const float* __restrict__ emb,
                                            const float* __restrict__ w0, const float* __restrict__ bias0, ushort* __restrict__ out0,
                                            const float* __restrict__ w1, const float* __restrict__ bias1, ushort* __restrict__ out1) {
    __shared__ ushort Asl[64][392];              // 384 k + 8 pad, 50 KB
    const float* w   = blockIdx.z ? w1 : w0;
    const float* bia = blockIdx.z ? bias1 : bias0;
    ushort* out      = blockIdx.z ? out1 : out0;
    int tid = threadIdx.x;
    int n0 = blockIdx.x * 64;
    long m0 = (long)blockIdx.y * 64;
    int wv = tid >> 6;
    int lane = tid & 63;
    int l15 = lane & 15;
    int lhi = lane >> 4;

    {
        int row = tid >> 2, kq = tid & 3;
        long tok = tokens[m0 + row];
        const float* ar = emb + tok * EMB + kq * 96;
#pragma unroll
        for (int it = 0; it < 12; ++it) {
            float4 a = *(const float4*)(ar + it * 8);
            float4 b = *(const float4*)(ar + it * 8 + 4);
            *(bf16x8*)&Asl[row][kq * 96 + it * 8] = cvt8(a, b);
        }
    }
    __syncthreads();

    int n = n0 + wv * 16 + l15;
    const float* brow = w + (long)n * EMB;
    f32x4 acc[4] = {};
#pragma unroll
    for (int ks = 0; ks < 12; ++ks) {
        float4 b0 = *(const float4*)(brow + ks * 32 + lhi * 8);
        float4 b1 = *(const float4*)(brow + ks * 32 + lhi * 8 + 4);
        bf16x8 bf = cvt8(b0, b1);
#pragma unroll
        for (int mt = 0; mt < 4; ++mt) {
            bf16x8 a = *(const bf16x8*)&Asl[mt * 16 + l15][ks * 32 + lhi * 8];
            acc[mt] = MFMA16(a, bf, acc[mt], 0, 0, 0);
        }
    }

    float bias = bia[n];
    int gi = n >> 8, c = n & 255;
    int wvv = c >> 5, p = (c >> 4) & 1, fl = c & 15;
    int sidx = wvv * 128 + fl * 8 + p * 3 + gi;
#pragma unroll
    for (int mt = 0; mt < 4; ++mt)
#pragma unroll
        for (int r = 0; r < 4; ++r) {
            long m = m0 + mt * 16 + lhi * 4 + r;
            out[m * 1024 + sidx] = f2bf(acc[mt][r] + bias);
        }
}

// ---------------- MFMA GRU: grid 64 = (bgroup(16), dir(2), seq(2)). 512 thr = 8 waves. ----------------
// nb=2; batch bi -> A-rows bi*4 and bi*4+8 (two h copies). Lane (l15,lhi): bi=lhi&1,
// p=lhi>>1 -> exactly ONE (batch,j,p) triple per lane. All 6 B-tiles in registers.
__global__ __attribute__((amdgpu_flat_work_group_size(512, 512), amdgpu_waves_per_eu(2, 2)))
void k_gru5(
    const ushort* __restrict__ gxd_f, const ushort* __restrict__ gxd_b,
    const ushort* __restrict__ gxq_f, const ushort* __restrict__ gxq_b,
    const ushort* __restrict__ wprep,
    const float* __restrict__ bhh_f, const float* __restrict__ bhh_b,
    const int* __restrict__ dlens, const int* __restrict__ qlens,
    float* __restrict__ dosb, float* __restrict__ qosb)
{
    int wg = blockIdx.x;
    int bgroup = wg & 15;
    int dir = (wg >> 4) & 1;
    int seq = wg >> 5;                   // 0=doc, 1=query
    int T = seq ? QLEN : DLEN;
    const ushort* gx = seq ? (dir ? gxq_b : gxq_f) : (dir ? gxd_b : gxd_f);
    const float* bhh = dir ? bhh_b : bhh_f;
    const int* lens = seq ? qlens : dlens;
    float* outbase = (seq ? qosb : dosb) + dir * HID;
    int boff = bgroup * 2;

    int tid = threadIdx.x;
    int wv = tid >> 6;
    int lane = tid & 63;
    int l15 = lane & 15;
    int lhi = lane >> 4;
    int bi = lhi & 1;                    // local batch
    int p  = lhi >> 1;                   // j-half
    int jw = wv * 32;

    __shared__ ushort hbuf[2][4096];     // 16 KB bf16 h, swizzled, dbuf

    // ---- resident weights: ALL 6 tiles in registers ----
    const ushort* wp = wprep + (size_t)dir * 196608;
    bf16x8 B0[8], B1[8], B2[8], B3[8], B4[8], B5[8];
#pragma unroll
    for (int ks = 0; ks < 8; ++ks) {
        B0[ks] = *(const bf16x8*)(wp + ((((wv * 6 + 0) * 8 + ks) * 64 + lane) * 8));
        B1[ks] = *(const bf16x8*)(wp + ((((wv * 6 + 1) * 8 + ks) * 64 + lane) * 8));
        B2[ks] = *(const bf16x8*)(wp + ((((wv * 6 + 2) * 8 + ks) * 64 + lane) * 8));
        B3[ks] = *(const bf16x8*)(wp + ((((wv * 6 + 3) * 8 + ks) * 64 + lane) * 8));
        B4[ks] = *(const bf16x8*)(wp + ((((wv * 6 + 4) * 8 + ks) * 64 + lane) * 8));
        B5[ks] = *(const bf16x8*)(wp + ((((wv * 6 + 5) * 8 + ks) * 64 + lane) * 8));
    }

    float bhn0 = bhh[512 + jw + l15];
    float bhn1 = bhh[512 + jw + 16 + l15];
    int len = lens[boff + bi];
    float hp = 0.f;

    // ---- precomputed static addresses (t-invariant) ----
    int a_addr[8];
#pragma unroll
    for (int ks = 0; ks < 8; ++ks)
        a_addr[ks] = l15 * 512 + (((ks * 4 + lhi) ^ (l15 & 7)) * 16);
    int j = jw + p * 16 + l15;
    int row0 = bi * 4;                   // second copy at row0+8 (= +4096 bytes)
    int wofs = (row0 * 256 + (((j >> 3) ^ (row0 & 7)) * 8) + (j & 7)) * 2;
    int b = boff + bi;
    int lbg = b * T * 2048 + wv * 256 + l15 * 16;   // gx: 1024-ushort rows, 16B slots
    int lbo = b * T * 2048 + j * 4;                 // out: 512-f32 rows

    for (int x = tid; x < 4096; x += 512) hbuf[0][x] = 0;
    __syncthreads();

    int voA, voB;

#define GSTEP(RB, WB, TT, VPRE, VCUR)                                             \
    {                                                                             \
        int p_ = (TT);                                                            \
        if (dir) p_ = ((TT) < len) ? (len - 1 - (TT)) : (TT);                     \
        u16x8 gxu = *(const u16x8*)((const char*)gx + (lbg + p_ * 2048));         \
        VCUR = lbo + p_ * 2048;                                                   \
        if ((TT) != 0) {                                                          \
            *(float*)((char*)outbase + VPRE) = hp;                                \
        }                                                                         \
        f32x4 acc0 = {0.f,0.f,0.f,0.f}, acc1 = acc0, acc2 = acc0, acc3 = acc0;    \
        f32x4 acc4 = {bhn0, bhn0, bhn0, bhn0};                                    \
        f32x4 acc5 = {bhn1, bhn1, bhn1, bhn1};                                    \
        _Pragma("unroll")                                                         \
        for (int ks = 0; ks < 8; ++ks) {                                          \
            bf16x8 a = *(const bf16x8*)((const char*)&hbuf[RB][0] + a_addr[ks]);  \
            acc0 = MFMA16(a, B0[ks], acc0, 0, 0, 0);                              \
            acc1 = MFMA16(a, B1[ks], acc1, 0, 0, 0);                              \
            acc2 = MFMA16(a, B2[ks], acc2, 0, 0, 0);                              \
            acc3 = MFMA16(a, B3[ks], acc3, 0, 0, 0);                              \
            acc4 = MFMA16(a, B4[ks], acc4, 0, 0, 0);                              \
            acc5 = MFMA16(a, B5[ks], acc5, 0, 0, 0);                              \
        }                                                                         \
        {                                                                         \
            float ar = p ? acc1[0] : acc0[0];                                     \
            float az = p ? acc3[0] : acc2[0];                                     \
            float an = p ? acc5[0] : acc4[0];                                     \
            float rx = bf2f(p ? gxu[3] : gxu[0]);                                 \
            float zx = bf2f(p ? gxu[4] : gxu[1]);                                 \
            float nx = bf2f(p ? gxu[5] : gxu[2]);                                 \
            float r = sigf(rx + ar);                                              \
            float z = sigf(zx + az);                                              \
            float nn = tanhf_(nx + r * an);                                       \
            float h = (1.f - z) * nn + z * hp;                                    \
            hp = h;                                                               \
            unsigned pk;                                                          \
            asm("v_cvt_pk_bf16_f32 %0, %1, %2" : "=v"(pk) : "v"(h), "v"(h));      \
            *(ushort*)((char*)&hbuf[WB][0] + wofs) = (ushort)(pk & 0xffffu);      \
            *(ushort*)((char*)&hbuf[WB][0] + wofs + 4096) = (ushort)(pk & 0xffffu); \
        }                                                                         \
        __syncthreads();                                                          \
    }

    for (int t = 0; t < T; t += 2) {
        GSTEP(0, 1, t,     voB, voA)
        GSTEP(1, 0, t + 1, voA, voB)
    }
#undef GSTEP
    *(float*)((char*)outbase + voB) = hp;   // epilogue: h(T-1)
}

// ---------------- MFMA M-GEMM: M[b,d,q] = dos[b,d,:] . qos[b,q,:]  (K=512, bf16) ----------------
// grid (16, 32). 256 thr = 4 waves; wave wv owns d-rows wv*16..+16, all 64 q.
// dos/qos staged to LDS bf16 with XOR chunk swizzle (conflict-free ds_read_b128).
__global__ __launch_bounds__(256) void k_mgemm(const float* __restrict__ dos, const float* __restrict__ qos,
                                               float* __restrict__ Mm) {
    __shared__ ushort Asl[64 * 512];   // 64 KB
    __shared__ ushort Bsl[64 * 512];   // 64 KB
    int tid = threadIdx.x;
    int b = blockIdx.y;
    int m0 = blockIdx.x * 64;
    int wv = tid >> 6;
    int lane = tid & 63;
    int l15 = lane & 15;
    int lhi = lane >> 4;

    // ---- stage dos tile + qos (f32 -> bf16, swizzled chunks) ----
    {
        int row = tid >> 2, kq = tid & 3;
        const float* ar = dos + ((long)b * DLEN + m0 + row) * 512 + kq * 128;
        const float* br = qos + ((long)b * QLEN + row) * 512 + kq * 128;
#pragma unroll
        for (int it = 0; it < 16; ++it) {
            int c = kq * 16 + it;
            int dst = row * 512 + ((c ^ (row & 7)) * 8);
            float4 a0 = *(const float4*)(ar + it * 8);
            float4 a1 = *(const float4*)(ar + it * 8 + 4);
            *(bf16x8*)&Asl[dst] = cvt8(a0, a1);
            float4 b0 = *(const float4*)(br + it * 8);
            float4 b1 = *(const float4*)(br + it * 8 + 4);
            *(bf16x8*)&Bsl[dst] = cvt8(b0, b1);
        }
    }
    __syncthreads();

    f32x4 acc[4] = {};
#pragma unroll
    for (int ks = 0; ks < 16; ++ks) {
        int arow = wv * 16 + l15;
        bf16x8 a = *(const bf16x8*)&Asl[arow * 512 + (((ks * 4 + lhi) ^ (l15 & 7)) * 8)];
#pragma unroll
        for (int nt = 0; nt < 4; ++nt) {
            int brow = nt * 16 + l15;
            bf16x8 bv = *(const bf16x8*)&Bsl[brow * 512 + (((ks * 4 + lhi) ^ (l15 & 7)) * 8)];
            acc[nt] = MFMA16(a, bv, acc[nt], 0, 0, 0);
        }
    }

#pragma unroll
    for (int nt = 0; nt < 4; ++nt)
#pragma unroll
        for (int i = 0; i < 4; ++i) {
            long m = (long)b * DLEN + m0 + wv * 16 + lhi * 4 + i;
            Mm[m * QLEN + nt * 16 + l15] = acc[nt][i];
        }
}

// ---------------- fused attention epilogue: avgbeta + colstats -> s (LDS) -> final ----------------
// grid (BATCH). 256 thr. M stays L2-resident between the two passes.
__global__ __launch_bounds__(256) void k_aoa(const float* __restrict__ Mm, const float* __restrict__ dmask,
                                             const float* __restrict__ qmask, const int* __restrict__ dlens,
                                             const int* __restrict__ doc, const int* __restrict__ cand,
                                             const int* __restrict__ ans, float* __restrict__ out) {
    int b = blockIdx.x, tid = threadIdx.x;
    int lane = tid & 63, wid = tid >> 6;
    float qm = qmask[b * QLEN + lane];

    // pass 1: per-row softmax accumulation (beta) + online column stats (alpha denom)
    float accA = 0.f;
    float mrun = -INFINITY, srun = 0.f;
    for (int d = wid; d < DLEN; d += 4) {
        float x = Mm[((long)b * DLEN + d) * QLEN + lane];
        float dm = dmask[b * DLEN + d];
        float mx = x;
#pragma unroll
        for (int o = 32; o; o >>= 1) mx = fmaxf(mx, __shfl_xor(mx, o));
        float e = expf(x - mx) * dm * qm;
        float sm = e;
#pragma unroll
        for (int o = 32; o; o >>= 1) sm += __shfl_xor(sm, o);
        accA += e / (sm + 1e-12f);
        float mn = fmaxf(mrun, x);
        srun = srun * expf(mrun - mn) + expf(x - mn) * dm;
        mrun = mn;
    }
    __shared__ float redA[4][QLEN], mS[4][QLEN], sS[4][QLEN];
    __shared__ float wq[QLEN], mxs[QLEN];
    __shared__ float sL[DLEN];
    redA[wid][lane] = accA;
    mS[wid][lane] = mrun;
    sS[wid][lane] = srun;
    __syncthreads();
    if (tid < QLEN) {
        float M0 = fmaxf(fmaxf(mS[0][tid], mS[1][tid]), fmaxf(mS[2][tid], mS[3][tid]));
        float S = 0.f;
#pragma unroll
        for (int i = 0; i < 4; ++i) S += sS[i][tid] * expf(mS[i][tid] - M0);
        float avgbv = (redA[0][tid] + redA[1][tid] + redA[2][tid] + redA[3][tid]) / (float)dlens[b];
        wq[tid] = (qm > 0.f) ? (avgbv / (S + 1e-12f)) : 0.f;   // qm==qmask[b,tid] since tid<64
        mxs[tid] = M0;
    }
    __syncthreads();

    // pass 2: s[d] = dm * sum_q exp(M - mxs_q) * wq_q   (M rows L2-hot)
    for (int d = tid; d < DLEN; d += 256) {
        const float* row = Mm + ((long)b * DLEN + d) * QLEN;
        float acc = 0.f;
#pragma unroll
        for (int q = 0; q < QLEN; q += 4) {
            float4 v = *(const float4*)(row + q);
            acc += expf(v.x - mxs[q + 0]) * wq[q + 0];
            acc += expf(v.y - mxs[q + 1]) * wq[q + 1];
            acc += expf(v.z - mxs[q + 2]) * wq[q + 2];
            acc += expf(v.w - mxs[q + 3]) * wq[q + 3];
        }
        sL[d] = dmask[b * DLEN + d] * acc;
    }
    __syncthreads();

    // final: candidate scores + argmax + probs
    __shared__ int lc[NCAND];
    __shared__ int la;
    __shared__ float red[4][NCAND + 1];
    if (tid < NCAND) lc[tid] = cand[b * NCAND + tid];
    if (tid == NCAND) la = ans[b];
    __syncthreads();
    float accs[NCAND + 1] = {};
    for (int d = tid; d < DLEN; d += 256) {
        int tk = doc[b * DLEN + d];
        float sv = sL[d];
#pragma unroll
        for (int c = 0; c < NCAND; ++c)
            if (tk == lc[c]) accs[c] += sv;
        if (tk == la) accs[NCAND] += sv;
    }
#pragma unroll
    for (int i = 0; i <= NCAND; ++i) {
        float v = accs[i];
#pragma unroll
        for (int o = 32; o; o >>= 1) v += __shfl_xor(v, o);
        if (lane == 0) red[wid][i] = v;
    }
    __syncthreads();
    if (tid == 0) {
        float cp[NCAND + 1];
#pragma unroll
        for (int i = 0; i <= NCAND; ++i) cp[i] = red[0][i] + red[1][i] + red[2][i] + red[3][i];
        int loc = 0; float best = cp[0];
#pragma unroll
        for (int c = 1; c < NCAND; ++c) if (cp[c] > best) { best = cp[c]; loc = c; }
        out[b] = (float)lc[loc];
        out[BATCH + b] = (float)loc;
        out[2 * BATCH + b] = cp[NCAND];
    }
}

__global__ void k_zero_out(float* out, int n) {
    int i = blockIdx.x * 256 + threadIdx.x;
    if (i < n) out[i] = 0.f;
}

extern "C" void kernel_launch(void* const* d_in, const int* in_sizes, int n_in,
                              void* d_out, int out_size, void* d_ws, size_t ws_size,
                              hipStream_t stream) {
    const int*   docs_input   = (const int*)d_in[0];
    const int*   docs_len     = (const int*)d_in[1];
    const float* doc_mask     = (const float*)d_in[2];
    const int*   querys_input = (const int*)d_in[3];
    const int*   querys_len   = (const int*)d_in[4];
    const float* query_mask   = (const float*)d_in[5];
    const int*   candidates   = (const int*)d_in[6];
    const int*   answers      = (const int*)d_in[7];
    const float* embedding    = (const float*)d_in[8];
    const float* w_ih_f = (const float*)d_in[9];
    const float* w_hh_f = (const float*)d_in[10];
    const float* b_ih_f = (const float*)d_in[11];
    const float* b_hh_f = (const float*)d_in[12];
    const float* w_ih_b = (const float*)d_in[13];
    const float* w_hh_b = (const float*)d_in[14];
    const float* b_ih_b = (const float*)d_in[15];
    const float* b_hh_b = (const float*)d_in[16];

    char* ws = (char*)d_ws;
    size_t off = 0;
    auto alloc = [&](size_t bytes) { size_t o = off; off = (off + bytes + 255) & ~(size_t)255; return o; };
    ushort* wprep = (ushort*)(ws + alloc((size_t)2 * 196608 * 2));
    float*  beff  = (float*)(ws + alloc((size_t)2 * G3 * 4));
    ushort* gxq_f = (ushort*)(ws + alloc((size_t)BATCH * QLEN * 1024 * 2));
    ushort* gxq_b = (ushort*)(ws + alloc((size_t)BATCH * QLEN * 1024 * 2));
    ushort* gxd_f = (ushort*)(ws + alloc((size_t)BATCH * DLEN * 1024 * 2));
    ushort* gxd_b = (ushort*)(ws + alloc((size_t)BATCH * DLEN * 1024 * 2));
    float* dosb  = (float*)(ws + alloc((size_t)BATCH * DLEN * 2 * HID * 4));
    float* qosb  = (float*)(ws + alloc((size_t)BATCH * QLEN * 2 * HID * 4));
    float* Mbuf  = (float*)(ws + alloc((size_t)BATCH * DLEN * QLEN * 4));

    if (ws_size < off) {
        k_zero_out<<<1, 256, 0, stream>>>((float*)d_out, out_size);
        return;
    }

    // effective biases (b_ih + b_hh for r/z) and weight fragments
    k_bias<<<6, 256, 0, stream>>>(b_ih_f, b_hh_f, b_ih_b, b_hh_b, beff);
    k_prep<<<1536, 256, 0, stream>>>(w_hh_f, w_hh_b, wprep);

    // gx for queries and docs, both directions (MFMA bf16, lane-major 16B-slot out)
    k_gx<<<dim3(12, (BATCH * QLEN) / 64, 2), 256, 0, stream>>>(querys_input, embedding,
        w_ih_f, beff, gxq_f, w_ih_b, beff + G3, gxq_b);
    k_gx<<<dim3(12, (BATCH * DLEN) / 64, 2), 256, 0, stream>>>(docs_input, embedding,
        w_ih_f, beff, gxd_f, w_ih_b, beff + G3, gxd_b);

    // all four BiGRU scans (doc/query x fwd/bwd), batch split in pairs
    k_gru5<<<64, 512, 0, stream>>>(gxd_f, gxd_b, gxq_f, gxq_b, wprep,
                                   b_hh_f, b_hh_b, docs_len, querys_len, dosb, qosb);

    // attention-over-attention
    k_mgemm<<<dim3(DLEN / 64, BATCH), 256, 0, stream>>>(dosb, qosb, Mbuf);
    k_aoa<<<BATCH, 256, 0, stream>>>(Mbuf, doc_mask, query_mask, docs_len,
                                     docs_input, candidates, answers, (float*)d_out);
}

// Round 18
// 1349.138 us; speedup vs baseline: 3.8993x; 1.3101x over previous
//
#include <hip/hip_runtime.h>
#include <hip/hip_bf16.h>
#include <math.h>

// AoA Reader v13 (resubmit #2 after repeated infra failures): r15 + s_setprio around
// GRU MFMA cluster + all-bf16 operand paths. V=50000 E=384 H=256 B=32 D=1024 Q=64 C=10.
#define BATCH 32
#define DLEN 1024
#define QLEN 64
#define EMB 384
#define HID 256
#define G3 768   // 3*H
#define NCAND 10
#define VOCAB 50000

typedef __attribute__((ext_vector_type(8))) short bf16x8;
typedef __attribute__((ext_vector_type(8))) unsigned short u16x8;
typedef __attribute__((ext_vector_type(4))) float f32x4;
#define MFMA16 __builtin_amdgcn_mfma_f32_16x16x32_bf16

__device__ __forceinline__ float bf2f(ushort u) {
    union { float f; unsigned v; } x; x.v = ((unsigned)u) << 16; return x.f;
}
__device__ __forceinline__ ushort f2bf(float f) {
    union { float f; unsigned v; } x; x.f = f;
    unsigned r = x.v + 0x7FFF + ((x.v >> 16) & 1);
    return (ushort)(r >> 16);
}
__device__ __forceinline__ float sigf(float x) {
    return __builtin_amdgcn_rcpf(1.f + __expf(-x));
}
__device__ __forceinline__ float tanhf_(float x) {
    return 1.f - 2.f * __builtin_amdgcn_rcpf(1.f + __expf(2.f * x));
}
__device__ __forceinline__ bf16x8 cvt8(float4 a, float4 b) {
    union { unsigned u[4]; bf16x8 v; } r;
    asm("v_cvt_pk_bf16_f32 %0, %1, %2" : "=v"(r.u[0]) : "v"(a.x), "v"(a.y));
    asm("v_cvt_pk_bf16_f32 %0, %1, %2" : "=v"(r.u[1]) : "v"(a.z), "v"(a.w));
    asm("v_cvt_pk_bf16_f32 %0, %1, %2" : "=v"(r.u[2]) : "v"(b.x), "v"(b.y));
    asm("v_cvt_pk_bf16_f32 %0, %1, %2" : "=v"(r.u[3]) : "v"(b.z), "v"(b.w));
    return r.v;
}

// ---------------- f32 -> bf16 bulk convert (emb table, w_ih) ----------------
__global__ __launch_bounds__(256) void k_embf(const float* __restrict__ in, ushort* __restrict__ out, int n8) {
    int i = blockIdx.x * 256 + threadIdx.x;
    if (i >= n8) return;
    const float* p = in + (size_t)i * 8;
    float4 a = *(const float4*)p;
    float4 b = *(const float4*)(p + 4);
    *(bf16x8*)(out + (size_t)i * 8) = cvt8(a, b);
}

// ---------------- bias_eff[dir][768]: b_ih + (b_hh for r,z gates only) ----------------
__global__ __launch_bounds__(256) void k_bias(const float* __restrict__ bihf, const float* __restrict__ bhhf,
                                              const float* __restrict__ bihb, const float* __restrict__ bhhb,
                                              float* __restrict__ be) {
    int n = blockIdx.x * 256 + threadIdx.x;
    if (n >= 1536) return;
    int dir = n / G3, c = n - dir * G3;
    const float* bih = dir ? bihb : bihf;
    const float* bhh = dir ? bhhb : bhhf;
    be[n] = bih[c] + (c < 512 ? bhh[c] : 0.f);
}

// ---------------- prep: w_hh (768x256 f32) -> bf16 MFMA B-fragment order ----------------
__global__ __launch_bounds__(256) void k_prep(const float* __restrict__ whf, const float* __restrict__ whb,
                                              ushort* __restrict__ wprep) {
    int idx = blockIdx.x * 256 + threadIdx.x;   // < 393216
    int dir = idx / 196608;
    int r = idx - dir * 196608;
    int wv = r / 24576;  int r2 = r - wv * 24576;
    int tile = r2 / 4096; int r3 = r2 - tile * 4096;
    int ks = r3 / 512;    int r4 = r3 - ks * 512;
    int lane = r4 >> 3;   int e = r4 & 7;
    int g = (tile >> 1) * 256 + wv * 32 + (tile & 1) * 16 + (lane & 15);
    int k = ks * 32 + (lane >> 4) * 8 + e;
    const float* w = dir ? whb : whf;
    wprep[idx] = f2bf(w[g * 256 + k]);
}

// ---------------- gx GEMM with gather, MFMA bf16 (all-bf16 sources) ----------------
__global__ __launch_bounds__(256) void k_gx(const int* __restrict__ tokens,
                                            const ushort* __restrict__ embB,
                                            const ushort* __restrict__ wih0, const float* __restrict__ bias0, ushort* __restrict__ out0,
                                            const ushort* __restrict__ wih1, const float* __restrict__ bias1, ushort* __restrict__ out1) {
    __shared__ ushort Asl[64][392];              // 384 k + 8 pad, 50 KB
    const ushort* wih = blockIdx.z ? wih1 : wih0;
    const float* bia  = blockIdx.z ? bias1 : bias0;
    ushort* out       = blockIdx.z ? out1 : out0;
    int tid = threadIdx.x;
    int n0 = blockIdx.x * 64;
    long m0 = (long)blockIdx.y * 64;
    int wv = tid >> 6;
    int lane = tid & 63;
    int l15 = lane & 15;
    int lhi = lane >> 4;

    // ---- stage A: 4 threads/row, 12 x 16B bf16 loads each ----
    {
        int row = tid >> 2, kq = tid & 3;
        long tok = tokens[m0 + row];
        const ushort* ar = embB + tok * EMB + kq * 96;
#pragma unroll
        for (int it = 0; it < 12; ++it)
            *(u16x8*)&Asl[row][kq * 96 + it * 8] = *(const u16x8*)(ar + it * 8);
    }
    __syncthreads();

    // ---- compute: wave wv = n-tile; 4 m-subtiles ----
    int n = n0 + wv * 16 + l15;
    const ushort* brow = wih + (long)n * EMB;
    f32x4 acc[4] = {};
#pragma unroll
    for (int ks = 0; ks < 12; ++ks) {
        bf16x8 bf = *(const bf16x8*)(brow + ks * 32 + lhi * 8);
#pragma unroll
        for (int mt = 0; mt < 4; ++mt) {
            bf16x8 a = *(const bf16x8*)&Asl[mt * 16 + l15][ks * 32 + lhi * 8];
            acc[mt] = MFMA16(a, bf, acc[mt], 0, 0, 0);
        }
    }

    // ---- epilogue: bias + permuted bf16 store ----
    float bias = bia[n];
    int gi = n >> 8, c = n & 255;
    int wvv = c >> 5, p = (c >> 4) & 1, fl = c & 15;
    int sidx = wvv * 128 + fl * 8 + p * 3 + gi;
#pragma unroll
    for (int mt = 0; mt < 4; ++mt)
#pragma unroll
        for (int r = 0; r < 4; ++r) {
            long m = m0 + mt * 16 + lhi * 4 + r;
            out[m * 1024 + sidx] = f2bf(acc[mt][r] + bias);
        }
}

// ---------------- MFMA GRU: grid 64 = (bgroup(16), dir(2), seq(2)). 512 thr = 8 waves. ----------------
// nb=2; batch bi -> A-rows bi*4 and bi*4+8. One (batch,j,p) triple per lane.
// All 6 B-tiles in registers. s_setprio(1) around MFMA cluster. Writes dos/qos as bf16.
__global__ __attribute__((amdgpu_flat_work_group_size(512, 512), amdgpu_waves_per_eu(2, 2)))
void k_gru5(
    const ushort* __restrict__ gxd_f, const ushort* __restrict__ gxd_b,
    const ushort* __restrict__ gxq_f, const ushort* __restrict__ gxq_b,
    const ushort* __restrict__ wprep,
    const float* __restrict__ bhh_f, const float* __restrict__ bhh_b,
    const int* __restrict__ dlens, const int* __restrict__ qlens,
    ushort* __restrict__ dosb, ushort* __restrict__ qosb)
{
    int wg = blockIdx.x;
    int bgroup = wg & 15;
    int dir = (wg >> 4) & 1;
    int seq = wg >> 5;                   // 0=doc, 1=query
    int T = seq ? QLEN : DLEN;
    const ushort* gx = seq ? (dir ? gxq_b : gxq_f) : (dir ? gxd_b : gxd_f);
    const float* bhh = dir ? bhh_b : bhh_f;
    const int* lens = seq ? qlens : dlens;
    ushort* outbase = (seq ? qosb : dosb) + dir * HID;
    int boff = bgroup * 2;

    int tid = threadIdx.x;
    int wv = tid >> 6;
    int lane = tid & 63;
    int l15 = lane & 15;
    int lhi = lane >> 4;
    int bi = lhi & 1;                    // local batch
    int p  = lhi >> 1;                   // j-half
    int jw = wv * 32;

    __shared__ ushort hbuf[2][4096];     // 16 KB bf16 h, swizzled, dbuf

    // ---- resident weights: ALL 6 tiles in registers ----
    const ushort* wp = wprep + (size_t)dir * 196608;
    bf16x8 B0[8], B1[8], B2[8], B3[8], B4[8], B5[8];
#pragma unroll
    for (int ks = 0; ks < 8; ++ks) {
        B0[ks] = *(const bf16x8*)(wp + ((((wv * 6 + 0) * 8 + ks) * 64 + lane) * 8));
        B1[ks] = *(const bf16x8*)(wp + ((((wv * 6 + 1) * 8 + ks) * 64 + lane) * 8));
        B2[ks] = *(const bf16x8*)(wp + ((((wv * 6 + 2) * 8 + ks) * 64 + lane) * 8));
        B3[ks] = *(const bf16x8*)(wp + ((((wv * 6 + 3) * 8 + ks) * 64 + lane) * 8));
        B4[ks] = *(const bf16x8*)(wp + ((((wv * 6 + 4) * 8 + ks) * 64 + lane) * 8));
        B5[ks] = *(const bf16x8*)(wp + ((((wv * 6 + 5) * 8 + ks) * 64 + lane) * 8));
    }

    float bhn0 = bhh[512 + jw + l15];
    float bhn1 = bhh[512 + jw + 16 + l15];
    int len = lens[boff + bi];
    float hp = 0.f;
    ushort hbf = 0;

    // ---- precomputed static addresses (t-invariant) ----
    int a_addr[8];
#pragma unroll
    for (int ks = 0; ks < 8; ++ks)
        a_addr[ks] = l15 * 512 + (((ks * 4 + lhi) ^ (l15 & 7)) * 16);
    int j = jw + p * 16 + l15;
    int row0 = bi * 4;                   // second copy at row0+8 (= +4096 bytes)
    int wofs = (row0 * 256 + (((j >> 3) ^ (row0 & 7)) * 8) + (j & 7)) * 2;
    int b = boff + bi;
    int lbg = b * T * 2048 + wv * 256 + l15 * 16;   // gx: 1024-ushort rows, 16B slots
    int lbo = b * T * 1024 + j * 2;                 // out: 512-bf16 rows (bytes)

    for (int x = tid; x < 4096; x += 512) hbuf[0][x] = 0;
    __syncthreads();

    int voA, voB;

#define GSTEP(RB, WB, TT, VPRE, VCUR)                                             \
    {                                                                             \
        int p_ = (TT);                                                            \
        if (dir) p_ = ((TT) < len) ? (len - 1 - (TT)) : (TT);                     \
        u16x8 gxu = *(const u16x8*)((const char*)gx + (lbg + p_ * 2048));         \
        VCUR = lbo + p_ * 1024;                                                   \
        if ((TT) != 0) {                                                          \
            *(ushort*)((char*)outbase + VPRE) = hbf;                              \
        }                                                                         \
        f32x4 acc0 = {0.f,0.f,0.f,0.f}, acc1 = acc0, acc2 = acc0, acc3 = acc0;    \
        f32x4 acc4 = {bhn0, bhn0, bhn0, bhn0};                                    \
        f32x4 acc5 = {bhn1, bhn1, bhn1, bhn1};                                    \
        __builtin_amdgcn_s_setprio(1);                                            \
        _Pragma("unroll")                                                         \
        for (int ks = 0; ks < 8; ++ks) {                                          \
            bf16x8 a = *(const bf16x8*)((const char*)&hbuf[RB][0] + a_addr[ks]);  \
            acc0 = MFMA16(a, B0[ks], acc0, 0, 0, 0);                              \
            acc1 = MFMA16(a, B1[ks], acc1, 0, 0, 0);                              \
            acc2 = MFMA16(a, B2[ks], acc2, 0, 0, 0);                              \
            acc3 = MFMA16(a, B3[ks], acc3, 0, 0, 0);                              \
            acc4 = MFMA16(a, B4[ks], acc4, 0, 0, 0);                              \
            acc5 = MFMA16(a, B5[ks], acc5, 0, 0, 0);                              \
        }                                                                         \
        __builtin_amdgcn_s_setprio(0);                                            \
        {                                                                         \
            float ar = p ? acc1[0] : acc0[0];                                     \
            float az = p ? acc3[0] : acc2[0];                                     \
            float an = p ? acc5[0] : acc4[0];                                     \
            float rx = bf2f(p ? gxu[3] : gxu[0]);                                 \
            float zx = bf2f(p ? gxu[4] : gxu[1]);                                 \
            float nx = bf2f(p ? gxu[5] : gxu[2]);                                 \
            float r = sigf(rx + ar);                                              \
            float z = sigf(zx + az);                                              \
            float nn = tanhf_(nx + r * an);                                       \
            float h = (1.f - z) * nn + z * hp;                                    \
            hp = h;                                                               \
            unsigned pk;                                                          \
            asm("v_cvt_pk_bf16_f32 %0, %1, %2" : "=v"(pk) : "v"(h), "v"(h));      \
            hbf = (ushort)(pk & 0xffffu);                                         \
            *(ushort*)((char*)&hbuf[WB][0] + wofs) = hbf;                         \
            *(ushort*)((char*)&hbuf[WB][0] + wofs + 4096) = hbf;                  \
        }                                                                         \
        __syncthreads();                                                          \
    }

    for (int t = 0; t < T; t += 2) {
        GSTEP(0, 1, t,     voB, voA)
        GSTEP(1, 0, t + 1, voA, voB)
    }
#undef GSTEP
    *(ushort*)((char*)outbase + voB) = hbf;   // epilogue: h(T-1)
}

// ---------------- MFMA M-GEMM: M[b,d,q] = dos[b,d,:] . qos[b,q,:]  (K=512, bf16 in) ----------------
__global__ __launch_bounds__(256) void k_mgemm(const ushort* __restrict__ dos, const ushort* __restrict__ qos,
                                               float* __restrict__ Mm) {
    __shared__ ushort Asl[64 * 512];   // 64 KB
    __shared__ ushort Bsl[64 * 512];   // 64 KB
    int tid = threadIdx.x;
    int b = blockIdx.y;
    int m0 = blockIdx.x * 64;
    int wv = tid >> 6;
    int lane = tid & 63;
    int l15 = lane & 15;
    int lhi = lane >> 4;

    // ---- stage dos tile + qos (bf16, swizzled chunks, no conversion) ----
    {
        int row = tid >> 2, kq = tid & 3;
        const ushort* ar = dos + ((long)b * DLEN + m0 + row) * 512 + kq * 128;
        const ushort* br = qos + ((long)b * QLEN + row) * 512 + kq * 128;
#pragma unroll
        for (int it = 0; it < 16; ++it) {
            int c = kq * 16 + it;
            int dst = row * 512 + ((c ^ (row & 7)) * 8);
            *(u16x8*)&Asl[dst] = *(const u16x8*)(ar + it * 8);
            *(u16x8*)&Bsl[dst] = *(const u16x8*)(br + it * 8);
        }
    }
    __syncthreads();

    f32x4 acc[4] = {};
#pragma unroll
    for (int ks = 0; ks < 16; ++ks) {
        int arow = wv * 16 + l15;
        bf16x8 a = *(const bf16x8*)&Asl[arow * 512 + (((ks * 4 + lhi) ^ (l15 & 7)) * 8)];
#pragma unroll
        for (int nt = 0; nt < 4; ++nt) {
            int brow = nt * 16 + l15;
            bf16x8 bv = *(const bf16x8*)&Bsl[brow * 512 + (((ks * 4 + lhi) ^ (l15 & 7)) * 8)];
            acc[nt] = MFMA16(a, bv, acc[nt], 0, 0, 0);
        }
    }

#pragma unroll
    for (int nt = 0; nt < 4; ++nt)
#pragma unroll
        for (int i = 0; i < 4; ++i) {
            long m = (long)b * DLEN + m0 + wv * 16 + lhi * 4 + i;
            Mm[m * QLEN + nt * 16 + l15] = acc[nt][i];
        }
}

// ---------------- fused attention epilogue: avgbeta + colstats -> s (LDS) -> final ----------------
__global__ __launch_bounds__(256) void k_aoa(const float* __restrict__ Mm, const float* __restrict__ dmask,
                                             const float* __restrict__ qmask, const int* __restrict__ dlens,
                                             const int* __restrict__ doc, const int* __restrict__ cand,
                                             const int* __restrict__ ans, float* __restrict__ out) {
    int b = blockIdx.x, tid = threadIdx.x;
    int lane = tid & 63, wid = tid >> 6;
    float qm = qmask[b * QLEN + lane];

    float accA = 0.f;
    float mrun = -INFINITY, srun = 0.f;
    for (int d = wid; d < DLEN; d += 4) {
        float x = Mm[((long)b * DLEN + d) * QLEN + lane];
        float dm = dmask[b * DLEN + d];
        float mx = x;
#pragma unroll
        for (int o = 32; o; o >>= 1) mx = fmaxf(mx, __shfl_xor(mx, o));
        float e = expf(x - mx) * dm * qm;
        float sm = e;
#pragma unroll
        for (int o = 32; o; o >>= 1) sm += __shfl_xor(sm, o);
        accA += e / (sm + 1e-12f);
        float mn = fmaxf(mrun, x);
        srun = srun * expf(mrun - mn) + expf(x - mn) * dm;
        mrun = mn;
    }
    __shared__ float redA[4][QLEN], mS[4][QLEN], sS[4][QLEN];
    __shared__ float wq[QLEN], mxs[QLEN];
    __shared__ float sL[DLEN];
    redA[wid][lane] = accA;
    mS[wid][lane] = mrun;
    sS[wid][lane] = srun;
    __syncthreads();
    if (tid < QLEN) {
        float M0 = fmaxf(fmaxf(mS[0][tid], mS[1][tid]), fmaxf(mS[2][tid], mS[3][tid]));
        float S = 0.f;
#pragma unroll
        for (int i = 0; i < 4; ++i) S += sS[i][tid] * expf(mS[i][tid] - M0);
        float avgbv = (redA[0][tid] + redA[1][tid] + redA[2][tid] + redA[3][tid]) / (float)dlens[b];
        wq[tid] = (qm > 0.f) ? (avgbv / (S + 1e-12f)) : 0.f;
        mxs[tid] = M0;
    }
    __syncthreads();

    for (int d = tid; d < DLEN; d += 256) {
        const float* row = Mm + ((long)b * DLEN + d) * QLEN;
        float acc = 0.f;
#pragma unroll
        for (int q = 0; q < QLEN; q += 4) {
            float4 v = *(const float4*)(row + q);
            acc += expf(v.x - mxs[q + 0]) * wq[q + 0];
            acc += expf(v.y - mxs[q + 1]) * wq[q + 1];
            acc += expf(v.z - mxs[q + 2]) * wq[q + 2];
            acc += expf(v.w - mxs[q + 3]) * wq[q + 3];
        }
        sL[d] = dmask[b * DLEN + d] * acc;
    }
    __syncthreads();

    __shared__ int lc[NCAND];
    __shared__ int la;
    __shared__ float red[4][NCAND + 1];
    if (tid < NCAND) lc[tid] = cand[b * NCAND + tid];
    if (tid == NCAND) la = ans[b];
    __syncthreads();
    float accs[NCAND + 1] = {};
    for (int d = tid; d < DLEN; d += 256) {
        int tk = doc[b * DLEN + d];
        float sv = sL[d];
#pragma unroll
        for (int c = 0; c < NCAND; ++c)
            if (tk == lc[c]) accs[c] += sv;
        if (tk == la) accs[NCAND] += sv;
    }
#pragma unroll
    for (int i = 0; i <= NCAND; ++i) {
        float v = accs[i];
#pragma unroll
        for (int o = 32; o; o >>= 1) v += __shfl_xor(v, o);
        if (lane == 0) red[wid][i] = v;
    }
    __syncthreads();
    if (tid == 0) {
        float cp[NCAND + 1];
#pragma unroll
        for (int i = 0; i <= NCAND; ++i) cp[i] = red[0][i] + red[1][i] + red[2][i] + red[3][i];
        int loc = 0; float best = cp[0];
#pragma unroll
        for (int c = 1; c < NCAND; ++c) if (cp[c] > best) { best = cp[c]; loc = c; }
        out[b] = (float)lc[loc];
        out[BATCH + b] = (float)loc;
        out[2 * BATCH + b] = cp[NCAND];
    }
}

__global__ void k_zero_out(float* out, int n) {
    int i = blockIdx.x * 256 + threadIdx.x;
    if (i < n) out[i] = 0.f;
}

extern "C" void kernel_launch(void* const* d_in, const int* in_sizes, int n_in,
                              void* d_out, int out_size, void* d_ws, size_t ws_size,
                              hipStream_t stream) {
    const int*   docs_input   = (const int*)d_in[0];
    const int*   docs_len     = (const int*)d_in[1];
    const float* doc_mask     = (const float*)d_in[2];
    const int*   querys_input = (const int*)d_in[3];
    const int*   querys_len   = (const int*)d_in[4];
    const float* query_mask   = (const float*)d_in[5];
    const int*   candidates   = (const int*)d_in[6];
    const int*   answers      = (const int*)d_in[7];
    const float* embedding    = (const float*)d_in[8];
    const float* w_ih_f = (const float*)d_in[9];
    const float* w_hh_f = (const float*)d_in[10];
    const float* b_ih_f = (const float*)d_in[11];
    const float* b_hh_f = (const float*)d_in[12];
    const float* w_ih_b = (const float*)d_in[13];
    const float* w_hh_b = (const float*)d_in[14];
    const float* b_ih_b = (const float*)d_in[15];
    const float* b_hh_b = (const float*)d_in[16];

    char* ws = (char*)d_ws;
    size_t off = 0;
    auto alloc = [&](size_t bytes) { size_t o = off; off = (off + bytes + 255) & ~(size_t)255; return o; };
    ushort* wprep = (ushort*)(ws + alloc((size_t)2 * 196608 * 2));
    float*  beff  = (float*)(ws + alloc((size_t)2 * G3 * 4));
    ushort* embB  = (ushort*)(ws + alloc((size_t)VOCAB * EMB * 2));
    ushort* wihB  = (ushort*)(ws + alloc((size_t)2 * G3 * EMB * 2));
    ushort* gxq_f = (ushort*)(ws + alloc((size_t)BATCH * QLEN * 1024 * 2));
    ushort* gxq_b = (ushort*)(ws + alloc((size_t)BATCH * QLEN * 1024 * 2));
    ushort* gxd_f = (ushort*)(ws + alloc((size_t)BATCH * DLEN * 1024 * 2));
    ushort* gxd_b = (ushort*)(ws + alloc((size_t)BATCH * DLEN * 1024 * 2));
    ushort* dosb  = (ushort*)(ws + alloc((size_t)BATCH * DLEN * 512 * 2));
    ushort* qosb  = (ushort*)(ws + alloc((size_t)BATCH * QLEN * 512 * 2));
    float* Mbuf   = (float*)(ws + alloc((size_t)BATCH * DLEN * QLEN * 4));

    if (ws_size < off) {
        k_zero_out<<<1, 256, 0, stream>>>((float*)d_out, out_size);
        return;
    }

    // one-time bf16 conversions + bias folding + w_hh fragment prep
    k_embf<<<(VOCAB * EMB / 8 + 255) / 256, 256, 0, stream>>>(embedding, embB, VOCAB * EMB / 8);
    k_embf<<<(G3 * EMB / 8 + 255) / 256, 256, 0, stream>>>(w_ih_f, wihB, G3 * EMB / 8);
    k_embf<<<(G3 * EMB / 8 + 255) / 256, 256, 0, stream>>>(w_ih_b, wihB + (size_t)G3 * EMB, G3 * EMB / 8);
    k_bias<<<6, 256, 0, stream>>>(b_ih_f, b_hh_f, b_ih_b, b_hh_b, beff);
    k_prep<<<1536, 256, 0, stream>>>(w_hh_f, w_hh_b, wprep);

    // gx for queries and docs, both directions (all-bf16 MFMA, lane-major 16B-slot out)
    k_gx<<<dim3(12, (BATCH * QLEN) / 64, 2), 256, 0, stream>>>(querys_input, embB,
        wihB, beff, gxq_f, wihB + (size_t)G3 * EMB, beff + G3, gxq_b);
    k_gx<<<dim3(12, (BATCH * DLEN) / 64, 2), 256, 0, stream>>>(docs_input, embB,
        wihB, beff, gxd_f, wihB + (size_t)G3 * EMB, beff + G3, gxd_b);

    // all four BiGRU scans (doc/query x fwd/bwd), batch split in pairs
    k_gru5<<<64, 512, 0, stream>>>(gxd_f, gxd_b, gxq_f, gxq_b, wprep,
                                   b_hh_f, b_hh_b, docs_len, querys_len, dosb, qosb);

    // attention-over-attention
    k_mgemm<<<dim3(DLEN / 64, BATCH), 256, 0, stream>>>(dosb, qosb, Mbuf);
    k_aoa<<<BATCH, 256, 0, stream>>>(Mbuf, doc_mask, query_mask, docs_len,
                                     docs_input, candidates, answers, (float*)d_out);
}

// Round 19
// 1343.424 us; speedup vs baseline: 3.9159x; 1.0043x over previous
//
#include <hip/hip_runtime.h>
#include <hip/hip_bf16.h>
#include <math.h>

// AoA Reader v14: r18 + single-h-write GRU (row-alias A-read, 8KB hbuf) + fused prep.
// V=50000 E=384 H=256 B=32 D=1024 Q=64 C=10.
#define BATCH 32
#define DLEN 1024
#define QLEN 64
#define EMB 384
#define HID 256
#define G3 768   // 3*H
#define NCAND 10
#define VOCAB 50000

typedef __attribute__((ext_vector_type(8))) short bf16x8;
typedef __attribute__((ext_vector_type(8))) unsigned short u16x8;
typedef __attribute__((ext_vector_type(4))) float f32x4;
#define MFMA16 __builtin_amdgcn_mfma_f32_16x16x32_bf16

__device__ __forceinline__ float bf2f(ushort u) {
    union { float f; unsigned v; } x; x.v = ((unsigned)u) << 16; return x.f;
}
__device__ __forceinline__ ushort f2bf(float f) {
    union { float f; unsigned v; } x; x.f = f;
    unsigned r = x.v + 0x7FFF + ((x.v >> 16) & 1);
    return (ushort)(r >> 16);
}
__device__ __forceinline__ float sigf(float x) {
    return __builtin_amdgcn_rcpf(1.f + __expf(-x));
}
__device__ __forceinline__ float tanhf_(float x) {
    return 1.f - 2.f * __builtin_amdgcn_rcpf(1.f + __expf(2.f * x));
}
__device__ __forceinline__ bf16x8 cvt8(float4 a, float4 b) {
    union { unsigned u[4]; bf16x8 v; } r;
    asm("v_cvt_pk_bf16_f32 %0, %1, %2" : "=v"(r.u[0]) : "v"(a.x), "v"(a.y));
    asm("v_cvt_pk_bf16_f32 %0, %1, %2" : "=v"(r.u[1]) : "v"(a.z), "v"(a.w));
    asm("v_cvt_pk_bf16_f32 %0, %1, %2" : "=v"(r.u[2]) : "v"(b.x), "v"(b.y));
    asm("v_cvt_pk_bf16_f32 %0, %1, %2" : "=v"(r.u[3]) : "v"(b.z), "v"(b.w));
    return r.v;
}

// ---------------- fused prep: embB + wihB(f,b) + bias_eff + wprep in ONE launch ----------------
// region layout (flat thread index i):
//   [0, NE8)                : embB chunk i (8 floats -> 8 bf16)
//   [NE8, NE8+NW8)          : wihB_f chunk
//   [.., +NW8)              : wihB_b chunk
//   [.., +1536)             : bias_eff elem
//   [.., +393216)           : wprep elem
#define NE8 (VOCAB * EMB / 8)
#define NW8 (G3 * EMB / 8)
__global__ __launch_bounds__(256) void k_prep_all(
    const float* __restrict__ emb, const float* __restrict__ wihf, const float* __restrict__ wihb,
    const float* __restrict__ bihf, const float* __restrict__ bhhf,
    const float* __restrict__ bihb, const float* __restrict__ bhhb,
    const float* __restrict__ whf, const float* __restrict__ whb,
    ushort* __restrict__ embB, ushort* __restrict__ wihB,
    float* __restrict__ be, ushort* __restrict__ wprep)
{
    long i = (long)blockIdx.x * 256 + threadIdx.x;
    if (i < NE8) {
        const float* p = emb + i * 8;
        *(bf16x8*)(embB + i * 8) = cvt8(*(const float4*)p, *(const float4*)(p + 4));
        return;
    }
    i -= NE8;
    if (i < 2 * NW8) {
        const float* w = (i < NW8) ? wihf : wihb;
        long c = (i < NW8) ? i : i - NW8;
        const float* p = w + c * 8;
        *(bf16x8*)(wihB + i * 8) = cvt8(*(const float4*)p, *(const float4*)(p + 4));
        return;
    }
    i -= 2 * NW8;
    if (i < 1536) {
        int dir = (int)i / G3, c = (int)i - dir * G3;
        const float* bih = dir ? bihb : bihf;
        const float* bhh = dir ? bhhb : bhhf;
        be[i] = bih[c] + (c < 512 ? bhh[c] : 0.f);
        return;
    }
    i -= 1536;
    if (i < 393216) {
        int idx = (int)i;
        int dir = idx / 196608;
        int r = idx - dir * 196608;
        int wv = r / 24576;  int r2 = r - wv * 24576;
        int tile = r2 / 4096; int r3 = r2 - tile * 4096;
        int ks = r3 / 512;    int r4 = r3 - ks * 512;
        int lane = r4 >> 3;   int e = r4 & 7;
        int g = (tile >> 1) * 256 + wv * 32 + (tile & 1) * 16 + (lane & 15);
        int k = ks * 32 + (lane >> 4) * 8 + e;
        const float* w = dir ? whb : whf;
        wprep[idx] = f2bf(w[g * 256 + k]);
    }
}
#define PREP_TOTAL ((long)NE8 + 2 * NW8 + 1536 + 393216)

// ---------------- gx GEMM with gather, MFMA bf16 (all-bf16 sources) ----------------
__global__ __launch_bounds__(256) void k_gx(const int* __restrict__ tokens,
                                            const ushort* __restrict__ embB,
                                            const ushort* __restrict__ wih0, const float* __restrict__ bias0, ushort* __restrict__ out0,
                                            const ushort* __restrict__ wih1, const float* __restrict__ bias1, ushort* __restrict__ out1) {
    __shared__ ushort Asl[64][392];              // 384 k + 8 pad, 50 KB
    const ushort* wih = blockIdx.z ? wih1 : wih0;
    const float* bia  = blockIdx.z ? bias1 : bias0;
    ushort* out       = blockIdx.z ? out1 : out0;
    int tid = threadIdx.x;
    int n0 = blockIdx.x * 64;
    long m0 = (long)blockIdx.y * 64;
    int wv = tid >> 6;
    int lane = tid & 63;
    int l15 = lane & 15;
    int lhi = lane >> 4;

    // ---- stage A: 4 threads/row, 12 x 16B bf16 loads each ----
    {
        int row = tid >> 2, kq = tid & 3;
        long tok = tokens[m0 + row];
        const ushort* ar = embB + tok * EMB + kq * 96;
#pragma unroll
        for (int it = 0; it < 12; ++it)
            *(u16x8*)&Asl[row][kq * 96 + it * 8] = *(const u16x8*)(ar + it * 8);
    }
    __syncthreads();

    // ---- compute: wave wv = n-tile; 4 m-subtiles ----
    int n = n0 + wv * 16 + l15;
    const ushort* brow = wih + (long)n * EMB;
    f32x4 acc[4] = {};
#pragma unroll
    for (int ks = 0; ks < 12; ++ks) {
        bf16x8 bf = *(const bf16x8*)(brow + ks * 32 + lhi * 8);
#pragma unroll
        for (int mt = 0; mt < 4; ++mt) {
            bf16x8 a = *(const bf16x8*)&Asl[mt * 16 + l15][ks * 32 + lhi * 8];
            acc[mt] = MFMA16(a, bf, acc[mt], 0, 0, 0);
        }
    }

    // ---- epilogue: bias + permuted bf16 store ----
    float bias = bia[n];
    int gi = n >> 8, c = n & 255;
    int wvv = c >> 5, p = (c >> 4) & 1, fl = c & 15;
    int sidx = wvv * 128 + fl * 8 + p * 3 + gi;
#pragma unroll
    for (int mt = 0; mt < 4; ++mt)
#pragma unroll
        for (int r = 0; r < 4; ++r) {
            long m = m0 + mt * 16 + lhi * 4 + r;
            out[m * 1024 + sidx] = f2bf(acc[mt][r] + bias);
        }
}

// ---------------- MFMA GRU: grid 64 = (bgroup(16), dir(2), seq(2)). 512 thr = 8 waves. ----------------
// nb=2; batch bi -> A-row bi*4 ONLY (A-read row = l15&7 aliases rows 8-15 onto 0-7:
// aliased lanes read the SAME address -> LDS broadcast, identical data, no dup write).
// All 6 B-tiles in registers. setprio around MFMA. bf16 dos/qos out.
__global__ __attribute__((amdgpu_flat_work_group_size(512, 512), amdgpu_waves_per_eu(2, 2)))
void k_gru5(
    const ushort* __restrict__ gxd_f, const ushort* __restrict__ gxd_b,
    const ushort* __restrict__ gxq_f, const ushort* __restrict__ gxq_b,
    const ushort* __restrict__ wprep,
    const float* __restrict__ bhh_f, const float* __restrict__ bhh_b,
    const int* __restrict__ dlens, const int* __restrict__ qlens,
    ushort* __restrict__ dosb, ushort* __restrict__ qosb)
{
    int wg = blockIdx.x;
    int bgroup = wg & 15;
    int dir = (wg >> 4) & 1;
    int seq = wg >> 5;                   // 0=doc, 1=query
    int T = seq ? QLEN : DLEN;
    const ushort* gx = seq ? (dir ? gxq_b : gxq_f) : (dir ? gxd_b : gxd_f);
    const float* bhh = dir ? bhh_b : bhh_f;
    const int* lens = seq ? qlens : dlens;
    ushort* outbase = (seq ? qosb : dosb) + dir * HID;
    int boff = bgroup * 2;

    int tid = threadIdx.x;
    int wv = tid >> 6;
    int lane = tid & 63;
    int l15 = lane & 15;
    int lhi = lane >> 4;
    int bi = lhi & 1;                    // local batch
    int p  = lhi >> 1;                   // j-half
    int jw = wv * 32;

    __shared__ ushort hbuf[2][2048];     // 8 KB bf16 h (8 rows), swizzled, dbuf

    // ---- resident weights: ALL 6 tiles in registers ----
    const ushort* wp = wprep + (size_t)dir * 196608;
    bf16x8 B0[8], B1[8], B2[8], B3[8], B4[8], B5[8];
#pragma unroll
    for (int ks = 0; ks < 8; ++ks) {
        B0[ks] = *(const bf16x8*)(wp + ((((wv * 6 + 0) * 8 + ks) * 64 + lane) * 8));
        B1[ks] = *(const bf16x8*)(wp + ((((wv * 6 + 1) * 8 + ks) * 64 + lane) * 8));
        B2[ks] = *(const bf16x8*)(wp + ((((wv * 6 + 2) * 8 + ks) * 64 + lane) * 8));
        B3[ks] = *(const bf16x8*)(wp + ((((wv * 6 + 3) * 8 + ks) * 64 + lane) * 8));
        B4[ks] = *(const bf16x8*)(wp + ((((wv * 6 + 4) * 8 + ks) * 64 + lane) * 8));
        B5[ks] = *(const bf16x8*)(wp + ((((wv * 6 + 5) * 8 + ks) * 64 + lane) * 8));
    }

    float bhn0 = bhh[512 + jw + l15];
    float bhn1 = bhh[512 + jw + 16 + l15];
    int len = lens[boff + bi];
    float hp = 0.f;
    ushort hbf = 0;

    // ---- precomputed static addresses (t-invariant) ----
    int rl = l15 & 7;                    // aliased A-row (8..15 -> 0..7, same data)
    int a_addr[8];
#pragma unroll
    for (int ks = 0; ks < 8; ++ks)
        a_addr[ks] = rl * 512 + (((ks * 4 + lhi) ^ rl) * 16);
    int j = jw + p * 16 + l15;
    int row0 = bi * 4;                   // single h copy at row bi*4
    int wofs = (row0 * 256 + (((j >> 3) ^ (row0 & 7)) * 8) + (j & 7)) * 2;
    int b = boff + bi;
    int lbg = b * T * 2048 + wv * 256 + l15 * 16;   // gx: 1024-ushort rows, 16B slots
    int lbo = b * T * 1024 + j * 2;                 // out: 512-bf16 rows (bytes)

    for (int x = tid; x < 2048; x += 512) hbuf[0][x] = 0;
    __syncthreads();

    int voA, voB;

#define GSTEP(RB, WB, TT, VPRE, VCUR)                                             \
    {                                                                             \
        int p_ = (TT);                                                            \
        if (dir) p_ = ((TT) < len) ? (len - 1 - (TT)) : (TT);                     \
        u16x8 gxu = *(const u16x8*)((const char*)gx + (lbg + p_ * 2048));         \
        VCUR = lbo + p_ * 1024;                                                   \
        if ((TT) != 0) {                                                          \
            *(ushort*)((char*)outbase + VPRE) = hbf;                              \
        }                                                                         \
        f32x4 acc0 = {0.f,0.f,0.f,0.f}, acc1 = acc0, acc2 = acc0, acc3 = acc0;    \
        f32x4 acc4 = {bhn0, bhn0, bhn0, bhn0};                                    \
        f32x4 acc5 = {bhn1, bhn1, bhn1, bhn1};                                    \
        __builtin_amdgcn_s_setprio(1);                                            \
        _Pragma("unroll")                                                         \
        for (int ks = 0; ks < 8; ++ks) {                                          \
            bf16x8 a = *(const bf16x8*)((const char*)&hbuf[RB][0] + a_addr[ks]);  \
            acc0 = MFMA16(a, B0[ks], acc0, 0, 0, 0);                              \
            acc1 = MFMA16(a, B1[ks], acc1, 0, 0, 0);                              \
            acc2 = MFMA16(a, B2[ks], acc2, 0, 0, 0);                              \
            acc3 = MFMA16(a, B3[ks], acc3, 0, 0, 0);                              \
            acc4 = MFMA16(a, B4[ks], acc4, 0, 0, 0);                              \
            acc5 = MFMA16(a, B5[ks], acc5, 0, 0, 0);                              \
        }                                                                         \
        __builtin_amdgcn_s_setprio(0);                                            \
        {                                                                         \
            float ar = p ? acc1[0] : acc0[0];                                     \
            float az = p ? acc3[0] : acc2[0];                                     \
            float an = p ? acc5[0] : acc4[0];                                     \
            float rx = bf2f(p ? gxu[3] : gxu[0]);                                 \
            float zx = bf2f(p ? gxu[4] : gxu[1]);                                 \
            float nx = bf2f(p ? gxu[5] : gxu[2]);                                 \
            float r = sigf(rx + ar);                                              \
            float z = sigf(zx + az);                                              \
            float nn = tanhf_(nx + r * an);                                       \
            float h = (1.f - z) * nn + z * hp;                                    \
            hp = h;                                                               \
            unsigned pk;                                                          \
            asm("v_cvt_pk_bf16_f32 %0, %1, %2" : "=v"(pk) : "v"(h), "v"(h));      \
            hbf = (ushort)(pk & 0xffffu);                                         \
            *(ushort*)((char*)&hbuf[WB][0] + wofs) = hbf;                         \
        }                                                                         \
        __syncthreads();                                                          \
    }

    for (int t = 0; t < T; t += 2) {
        GSTEP(0, 1, t,     voB, voA)
        GSTEP(1, 0, t + 1, voA, voB)
    }
#undef GSTEP
    *(ushort*)((char*)outbase + voB) = hbf;   // epilogue: h(T-1)
}

// ---------------- MFMA M-GEMM: M[b,d,q] = dos[b,d,:] . qos[b,q,:]  (K=512, bf16 in) ----------------
__global__ __launch_bounds__(256) void k_mgemm(const ushort* __restrict__ dos, const ushort* __restrict__ qos,
                                               float* __restrict__ Mm) {
    __shared__ ushort Asl[64 * 512];   // 64 KB
    __shared__ ushort Bsl[64 * 512];   // 64 KB
    int tid = threadIdx.x;
    int b = blockIdx.y;
    int m0 = blockIdx.x * 64;
    int wv = tid >> 6;
    int lane = tid & 63;
    int l15 = lane & 15;
    int lhi = lane >> 4;

    // ---- stage dos tile + qos (bf16, swizzled chunks, no conversion) ----
    {
        int row = tid >> 2, kq = tid & 3;
        const ushort* ar = dos + ((long)b * DLEN + m0 + row) * 512 + kq * 128;
        const ushort* br = qos + ((long)b * QLEN + row) * 512 + kq * 128;
#pragma unroll
        for (int it = 0; it < 16; ++it) {
            int c = kq * 16 + it;
            int dst = row * 512 + ((c ^ (row & 7)) * 8);
            *(u16x8*)&Asl[dst] = *(const u16x8*)(ar + it * 8);
            *(u16x8*)&Bsl[dst] = *(const u16x8*)(br + it * 8);
        }
    }
    __syncthreads();

    f32x4 acc[4] = {};
#pragma unroll
    for (int ks = 0; ks < 16; ++ks) {
        int arow = wv * 16 + l15;
        bf16x8 a = *(const bf16x8*)&Asl[arow * 512 + (((ks * 4 + lhi) ^ (l15 & 7)) * 8)];
#pragma unroll
        for (int nt = 0; nt < 4; ++nt) {
            int brow = nt * 16 + l15;
            bf16x8 bv = *(const bf16x8*)&Bsl[brow * 512 + (((ks * 4 + lhi) ^ (l15 & 7)) * 8)];
            acc[nt] = MFMA16(a, bv, acc[nt], 0, 0, 0);
        }
    }

#pragma unroll
    for (int nt = 0; nt < 4; ++nt)
#pragma unroll
        for (int i = 0; i < 4; ++i) {
            long m = (long)b * DLEN + m0 + wv * 16 + lhi * 4 + i;
            Mm[m * QLEN + nt * 16 + l15] = acc[nt][i];
        }
}

// ---------------- fused attention epilogue: avgbeta + colstats -> s (LDS) -> final ----------------
__global__ __launch_bounds__(256) void k_aoa(const float* __restrict__ Mm, const float* __restrict__ dmask,
                                             const float* __restrict__ qmask, const int* __restrict__ dlens,
                                             const int* __restrict__ doc, const int* __restrict__ cand,
                                             const int* __restrict__ ans, float* __restrict__ out) {
    int b = blockIdx.x, tid = threadIdx.x;
    int lane = tid & 63, wid = tid >> 6;
    float qm = qmask[b * QLEN + lane];

    float accA = 0.f;
    float mrun = -INFINITY, srun = 0.f;
    for (int d = wid; d < DLEN; d += 4) {
        float x = Mm[((long)b * DLEN + d) * QLEN + lane];
        float dm = dmask[b * DLEN + d];
        float mx = x;
#pragma unroll
        for (int o = 32; o; o >>= 1) mx = fmaxf(mx, __shfl_xor(mx, o));
        float e = expf(x - mx) * dm * qm;
        float sm = e;
#pragma unroll
        for (int o = 32; o; o >>= 1) sm += __shfl_xor(sm, o);
        accA += e / (sm + 1e-12f);
        float mn = fmaxf(mrun, x);
        srun = srun * expf(mrun - mn) + expf(x - mn) * dm;
        mrun = mn;
    }
    __shared__ float redA[4][QLEN], mS[4][QLEN], sS[4][QLEN];
    __shared__ float wq[QLEN], mxs[QLEN];
    __shared__ float sL[DLEN];
    redA[wid][lane] = accA;
    mS[wid][lane] = mrun;
    sS[wid][lane] = srun;
    __syncthreads();
    if (tid < QLEN) {
        float M0 = fmaxf(fmaxf(mS[0][tid], mS[1][tid]), fmaxf(mS[2][tid], mS[3][tid]));
        float S = 0.f;
#pragma unroll
        for (int i = 0; i < 4; ++i) S += sS[i][tid] * expf(mS[i][tid] - M0);
        float avgbv = (redA[0][tid] + redA[1][tid] + redA[2][tid] + redA[3][tid]) / (float)dlens[b];
        wq[tid] = (qm > 0.f) ? (avgbv / (S + 1e-12f)) : 0.f;
        mxs[tid] = M0;
    }
    __syncthreads();

    for (int d = tid; d < DLEN; d += 256) {
        const float* row = Mm + ((long)b * DLEN + d) * QLEN;
        float acc = 0.f;
#pragma unroll
        for (int q = 0; q < QLEN; q += 4) {
            float4 v = *(const float4*)(row + q);
            acc += expf(v.x - mxs[q + 0]) * wq[q + 0];
            acc += expf(v.y - mxs[q + 1]) * wq[q + 1];
            acc += expf(v.z - mxs[q + 2]) * wq[q + 2];
            acc += expf(v.w - mxs[q + 3]) * wq[q + 3];
        }
        sL[d] = dmask[b * DLEN + d] * acc;
    }
    __syncthreads();

    __shared__ int lc[NCAND];
    __shared__ int la;
    __shared__ float red[4][NCAND + 1];
    if (tid < NCAND) lc[tid] = cand[b * NCAND + tid];
    if (tid == NCAND) la = ans[b];
    __syncthreads();
    float accs[NCAND + 1] = {};
    for (int d = tid; d < DLEN; d += 256) {
        int tk = doc[b * DLEN + d];
        float sv = sL[d];
#pragma unroll
        for (int c = 0; c < NCAND; ++c)
            if (tk == lc[c]) accs[c] += sv;
        if (tk == la) accs[NCAND] += sv;
    }
#pragma unroll
    for (int i = 0; i <= NCAND; ++i) {
        float v = accs[i];
#pragma unroll
        for (int o = 32; o; o >>= 1) v += __shfl_xor(v, o);
        if (lane == 0) red[wid][i] = v;
    }
    __syncthreads();
    if (tid == 0) {
        float cp[NCAND + 1];
#pragma unroll
        for (int i = 0; i <= NCAND; ++i) cp[i] = red[0][i] + red[1][i] + red[2][i] + red[3][i];
        int loc = 0; float best = cp[0];
#pragma unroll
        for (int c = 1; c < NCAND; ++c) if (cp[c] > best) { best = cp[c]; loc = c; }
        out[b] = (float)lc[loc];
        out[BATCH + b] = (float)loc;
        out[2 * BATCH + b] = cp[NCAND];
    }
}

__global__ void k_zero_out(float* out, int n) {
    int i = blockIdx.x * 256 + threadIdx.x;
    if (i < n) out[i] = 0.f;
}

extern "C" void kernel_launch(void* const* d_in, const int* in_sizes, int n_in,
                              void* d_out, int out_size, void* d_ws, size_t ws_size,
                              hipStream_t stream) {
    const int*   docs_input   = (const int*)d_in[0];
    const int*   docs_len     = (const int*)d_in[1];
    const float* doc_mask     = (const float*)d_in[2];
    const int*   querys_input = (const int*)d_in[3];
    const int*   querys_len   = (const int*)d_in[4];
    const float* query_mask   = (const float*)d_in[5];
    const int*   candidates   = (const int*)d_in[6];
    const int*   answers      = (const int*)d_in[7];
    const float* embedding    = (const float*)d_in[8];
    const float* w_ih_f = (const float*)d_in[9];
    const float* w_hh_f = (const float*)d_in[10];
    const float* b_ih_f = (const float*)d_in[11];
    const float* b_hh_f = (const float*)d_in[12];
    const float* w_ih_b = (const float*)d_in[13];
    const float* w_hh_b = (const float*)d_in[14];
    const float* b_ih_b = (const float*)d_in[15];
    const float* b_hh_b = (const float*)d_in[16];

    char* ws = (char*)d_ws;
    size_t off = 0;
    auto alloc = [&](size_t bytes) { size_t o = off; off = (off + bytes + 255) & ~(size_t)255; return o; };
    ushort* wprep = (ushort*)(ws + alloc((size_t)2 * 196608 * 2));
    float*  beff  = (float*)(ws + alloc((size_t)2 * G3 * 4));
    ushort* embB  = (ushort*)(ws + alloc((size_t)VOCAB * EMB * 2));
    ushort* wihB  = (ushort*)(ws + alloc((size_t)2 * G3 * EMB * 2));
    ushort* gxq_f = (ushort*)(ws + alloc((size_t)BATCH * QLEN * 1024 * 2));
    ushort* gxq_b = (ushort*)(ws + alloc((size_t)BATCH * QLEN * 1024 * 2));
    ushort* gxd_f = (ushort*)(ws + alloc((size_t)BATCH * DLEN * 1024 * 2));
    ushort* gxd_b = (ushort*)(ws + alloc((size_t)BATCH * DLEN * 1024 * 2));
    ushort* dosb  = (ushort*)(ws + alloc((size_t)BATCH * DLEN * 512 * 2));
    ushort* qosb  = (ushort*)(ws + alloc((size_t)BATCH * QLEN * 512 * 2));
    float* Mbuf   = (float*)(ws + alloc((size_t)BATCH * DLEN * QLEN * 4));

    if (ws_size < off) {
        k_zero_out<<<1, 256, 0, stream>>>((float*)d_out, out_size);
        return;
    }

    // fused one-time prep (bf16 conversions + bias folding + w_hh fragments)
    k_prep_all<<<(int)((PREP_TOTAL + 255) / 256), 256, 0, stream>>>(
        embedding, w_ih_f, w_ih_b, b_ih_f, b_hh_f, b_ih_b, b_hh_b, w_hh_f, w_hh_b,
        embB, wihB, beff, wprep);

    // gx for queries and docs, both directions (all-bf16 MFMA, lane-major 16B-slot out)
    k_gx<<<dim3(12, (BATCH * QLEN) / 64, 2), 256, 0, stream>>>(querys_input, embB,
        wihB, beff, gxq_f, wihB + (size_t)G3 * EMB, beff + G3, gxq_b);
    k_gx<<<dim3(12, (BATCH * DLEN) / 64, 2), 256, 0, stream>>>(docs_input, embB,
        wihB, beff, gxd_f, wihB + (size_t)G3 * EMB, beff + G3, gxd_b);

    // all four BiGRU scans (doc/query x fwd/bwd), batch split in pairs
    k_gru5<<<64, 512, 0, stream>>>(gxd_f, gxd_b, gxq_f, gxq_b, wprep,
                                   b_hh_f, b_hh_b, docs_len, querys_len, dosb, qosb);

    // attention-over-attention
    k_mgemm<<<dim3(DLEN / 64, BATCH), 256, 0, stream>>>(dosb, qosb, Mbuf);
    k_aoa<<<BATCH, 256, 0, stream>>>(Mbuf, doc_mask, query_mask, docs_len,
                                     docs_input, candidates, answers, (float*)d_out);
}

// Round 20
// 1325.728 us; speedup vs baseline: 3.9682x; 1.0133x over previous
//
#include <hip/hip_runtime.h>
#include <hip/hip_bf16.h>
#include <math.h>

// AoA Reader v15: r19 + natural coalesced gx layout ([m][768]) + 3x2B gru gate loads.
// V=50000 E=384 H=256 B=32 D=1024 Q=64 C=10.
#define BATCH 32
#define DLEN 1024
#define QLEN 64
#define EMB 384
#define HID 256
#define G3 768   // 3*H
#define NCAND 10
#define VOCAB 50000

typedef __attribute__((ext_vector_type(8))) short bf16x8;
typedef __attribute__((ext_vector_type(8))) unsigned short u16x8;
typedef __attribute__((ext_vector_type(4))) float f32x4;
#define MFMA16 __builtin_amdgcn_mfma_f32_16x16x32_bf16

__device__ __forceinline__ float bf2f(ushort u) {
    union { float f; unsigned v; } x; x.v = ((unsigned)u) << 16; return x.f;
}
__device__ __forceinline__ ushort f2bf(float f) {
    union { float f; unsigned v; } x; x.f = f;
    unsigned r = x.v + 0x7FFF + ((x.v >> 16) & 1);
    return (ushort)(r >> 16);
}
__device__ __forceinline__ float sigf(float x) {
    return __builtin_amdgcn_rcpf(1.f + __expf(-x));
}
__device__ __forceinline__ float tanhf_(float x) {
    return 1.f - 2.f * __builtin_amdgcn_rcpf(1.f + __expf(2.f * x));
}
__device__ __forceinline__ bf16x8 cvt8(float4 a, float4 b) {
    union { unsigned u[4]; bf16x8 v; } r;
    asm("v_cvt_pk_bf16_f32 %0, %1, %2" : "=v"(r.u[0]) : "v"(a.x), "v"(a.y));
    asm("v_cvt_pk_bf16_f32 %0, %1, %2" : "=v"(r.u[1]) : "v"(a.z), "v"(a.w));
    asm("v_cvt_pk_bf16_f32 %0, %1, %2" : "=v"(r.u[2]) : "v"(b.x), "v"(b.y));
    asm("v_cvt_pk_bf16_f32 %0, %1, %2" : "=v"(r.u[3]) : "v"(b.z), "v"(b.w));
    return r.v;
}

// ---------------- fused prep: embB + wihB(f,b) + bias_eff + wprep in ONE launch ----------------
#define NE8 (VOCAB * EMB / 8)
#define NW8 (G3 * EMB / 8)
__global__ __launch_bounds__(256) void k_prep_all(
    const float* __restrict__ emb, const float* __restrict__ wihf, const float* __restrict__ wihb,
    const float* __restrict__ bihf, const float* __restrict__ bhhf,
    const float* __restrict__ bihb, const float* __restrict__ bhhb,
    const float* __restrict__ whf, const float* __restrict__ whb,
    ushort* __restrict__ embB, ushort* __restrict__ wihB,
    float* __restrict__ be, ushort* __restrict__ wprep)
{
    long i = (long)blockIdx.x * 256 + threadIdx.x;
    if (i < NE8) {
        const float* p = emb + i * 8;
        *(bf16x8*)(embB + i * 8) = cvt8(*(const float4*)p, *(const float4*)(p + 4));
        return;
    }
    i -= NE8;
    if (i < 2 * NW8) {
        const float* w = (i < NW8) ? wihf : wihb;
        long c = (i < NW8) ? i : i - NW8;
        const float* p = w + c * 8;
        *(bf16x8*)(wihB + i * 8) = cvt8(*(const float4*)p, *(const float4*)(p + 4));
        return;
    }
    i -= 2 * NW8;
    if (i < 1536) {
        int dir = (int)i / G3, c = (int)i - dir * G3;
        const float* bih = dir ? bihb : bihf;
        const float* bhh = dir ? bhhb : bhhf;
        be[i] = bih[c] + (c < 512 ? bhh[c] : 0.f);
        return;
    }
    i -= 1536;
    if (i < 393216) {
        int idx = (int)i;
        int dir = idx / 196608;
        int r = idx - dir * 196608;
        int wv = r / 24576;  int r2 = r - wv * 24576;
        int tile = r2 / 4096; int r3 = r2 - tile * 4096;
        int ks = r3 / 512;    int r4 = r3 - ks * 512;
        int lane = r4 >> 3;   int e = r4 & 7;
        int g = (tile >> 1) * 256 + wv * 32 + (tile & 1) * 16 + (lane & 15);
        int k = ks * 32 + (lane >> 4) * 8 + e;
        const float* w = dir ? whb : whf;
        wprep[idx] = f2bf(w[g * 256 + k]);
    }
}
#define PREP_TOTAL ((long)NE8 + 2 * NW8 + 1536 + 393216)

// ---------------- gx GEMM with gather, MFMA bf16 (all-bf16, NATURAL coalesced out) ----------------
__global__ __launch_bounds__(256) void k_gx(const int* __restrict__ tokens,
                                            const ushort* __restrict__ embB,
                                            const ushort* __restrict__ wih0, const float* __restrict__ bias0, ushort* __restrict__ out0,
                                            const ushort* __restrict__ wih1, const float* __restrict__ bias1, ushort* __restrict__ out1) {
    __shared__ ushort Asl[64][392];              // 384 k + 8 pad, 50 KB
    const ushort* wih = blockIdx.z ? wih1 : wih0;
    const float* bia  = blockIdx.z ? bias1 : bias0;
    ushort* out       = blockIdx.z ? out1 : out0;
    int tid = threadIdx.x;
    int n0 = blockIdx.x * 64;
    long m0 = (long)blockIdx.y * 64;
    int wv = tid >> 6;
    int lane = tid & 63;
    int l15 = lane & 15;
    int lhi = lane >> 4;

    // ---- stage A: 4 threads/row, 12 x 16B bf16 loads each ----
    {
        int row = tid >> 2, kq = tid & 3;
        long tok = tokens[m0 + row];
        const ushort* ar = embB + tok * EMB + kq * 96;
#pragma unroll
        for (int it = 0; it < 12; ++it)
            *(u16x8*)&Asl[row][kq * 96 + it * 8] = *(const u16x8*)(ar + it * 8);
    }
    __syncthreads();

    // ---- compute: wave wv = n-tile; 4 m-subtiles ----
    int n = n0 + wv * 16 + l15;
    const ushort* brow = wih + (long)n * EMB;
    f32x4 acc[4] = {};
#pragma unroll
    for (int ks = 0; ks < 12; ++ks) {
        bf16x8 bf = *(const bf16x8*)(brow + ks * 32 + lhi * 8);
#pragma unroll
        for (int mt = 0; mt < 4; ++mt) {
            bf16x8 a = *(const bf16x8*)&Asl[mt * 16 + l15][ks * 32 + lhi * 8];
            acc[mt] = MFMA16(a, bf, acc[mt], 0, 0, 0);
        }
    }

    // ---- epilogue: bias + NATURAL bf16 store (16 lanes -> 32B contiguous) ----
    float bias = bia[n];
#pragma unroll
    for (int mt = 0; mt < 4; ++mt)
#pragma unroll
        for (int r = 0; r < 4; ++r) {
            long m = m0 + mt * 16 + lhi * 4 + r;
            out[m * G3 + n] = f2bf(acc[mt][r] + bias);
        }
}

// ---------------- MFMA GRU: grid 64 = (bgroup(16), dir(2), seq(2)). 512 thr = 8 waves. ----------------
// nb=2; batch bi -> A-row bi*4 (row-alias A-read). All 6 B-tiles in registers.
// setprio around MFMA. gx read: 3 x 2B scalar gate loads (natural layout). bf16 dos/qos out.
__global__ __attribute__((amdgpu_flat_work_group_size(512, 512), amdgpu_waves_per_eu(2, 2)))
void k_gru5(
    const ushort* __restrict__ gxd_f, const ushort* __restrict__ gxd_b,
    const ushort* __restrict__ gxq_f, const ushort* __restrict__ gxq_b,
    const ushort* __restrict__ wprep,
    const float* __restrict__ bhh_f, const float* __restrict__ bhh_b,
    const int* __restrict__ dlens, const int* __restrict__ qlens,
    ushort* __restrict__ dosb, ushort* __restrict__ qosb)
{
    int wg = blockIdx.x;
    int bgroup = wg & 15;
    int dir = (wg >> 4) & 1;
    int seq = wg >> 5;                   // 0=doc, 1=query
    int T = seq ? QLEN : DLEN;
    const ushort* gx = seq ? (dir ? gxq_b : gxq_f) : (dir ? gxd_b : gxd_f);
    const float* bhh = dir ? bhh_b : bhh_f;
    const int* lens = seq ? qlens : dlens;
    ushort* outbase = (seq ? qosb : dosb) + dir * HID;
    int boff = bgroup * 2;

    int tid = threadIdx.x;
    int wv = tid >> 6;
    int lane = tid & 63;
    int l15 = lane & 15;
    int lhi = lane >> 4;
    int bi = lhi & 1;                    // local batch
    int p  = lhi >> 1;                   // j-half
    int jw = wv * 32;

    __shared__ ushort hbuf[2][2048];     // 8 KB bf16 h (8 rows), swizzled, dbuf

    // ---- resident weights: ALL 6 tiles in registers ----
    const ushort* wp = wprep + (size_t)dir * 196608;
    bf16x8 B0[8], B1[8], B2[8], B3[8], B4[8], B5[8];
#pragma unroll
    for (int ks = 0; ks < 8; ++ks) {
        B0[ks] = *(const bf16x8*)(wp + ((((wv * 6 + 0) * 8 + ks) * 64 + lane) * 8));
        B1[ks] = *(const bf16x8*)(wp + ((((wv * 6 + 1) * 8 + ks) * 64 + lane) * 8));
        B2[ks] = *(const bf16x8*)(wp + ((((wv * 6 + 2) * 8 + ks) * 64 + lane) * 8));
        B3[ks] = *(const bf16x8*)(wp + ((((wv * 6 + 3) * 8 + ks) * 64 + lane) * 8));
        B4[ks] = *(const bf16x8*)(wp + ((((wv * 6 + 4) * 8 + ks) * 64 + lane) * 8));
        B5[ks] = *(const bf16x8*)(wp + ((((wv * 6 + 5) * 8 + ks) * 64 + lane) * 8));
    }

    float bhn0 = bhh[512 + jw + l15];
    float bhn1 = bhh[512 + jw + 16 + l15];
    int len = lens[boff + bi];
    float hp = 0.f;
    ushort hbf = 0;

    // ---- precomputed static addresses (t-invariant) ----
    int rl = l15 & 7;                    // aliased A-row (8..15 -> 0..7, same data)
    int a_addr[8];
#pragma unroll
    for (int ks = 0; ks < 8; ++ks)
        a_addr[ks] = rl * 512 + (((ks * 4 + lhi) ^ rl) * 16);
    int j = jw + p * 16 + l15;
    int row0 = bi * 4;                   // single h copy at row bi*4
    int wofs = (row0 * 256 + (((j >> 3) ^ (row0 & 7)) * 8) + (j & 7)) * 2;
    int b = boff + bi;
    int lbg = b * T * 1536 + j * 2;      // gx: 768-ushort rows (bytes); gates at +0,+512,+1024
    int lbo = b * T * 1024 + j * 2;      // out: 512-bf16 rows (bytes)

    for (int x = tid; x < 2048; x += 512) hbuf[0][x] = 0;
    __syncthreads();

    int voA, voB;

#define GSTEP(RB, WB, TT, VPRE, VCUR)                                             \
    {                                                                             \
        int p_ = (TT);                                                            \
        if (dir) p_ = ((TT) < len) ? (len - 1 - (TT)) : (TT);                     \
        const char* grow = (const char*)gx + (lbg + p_ * 1536);                   \
        ushort rxu = *(const ushort*)grow;                                        \
        ushort zxu = *(const ushort*)(grow + 512);                                \
        ushort nxu = *(const ushort*)(grow + 1024);                               \
        VCUR = lbo + p_ * 1024;                                                   \
        if ((TT) != 0) {                                                          \
            *(ushort*)((char*)outbase + VPRE) = hbf;                              \
        }                                                                         \
        f32x4 acc0 = {0.f,0.f,0.f,0.f}, acc1 = acc0, acc2 = acc0, acc3 = acc0;    \
        f32x4 acc4 = {bhn0, bhn0, bhn0, bhn0};                                    \
        f32x4 acc5 = {bhn1, bhn1, bhn1, bhn1};                                    \
        __builtin_amdgcn_s_setprio(1);                                            \
        _Pragma("unroll")                                                         \
        for (int ks = 0; ks < 8; ++ks) {                                          \
            bf16x8 a = *(const bf16x8*)((const char*)&hbuf[RB][0] + a_addr[ks]);  \
            acc0 = MFMA16(a, B0[ks], acc0, 0, 0, 0);                              \
            acc1 = MFMA16(a, B1[ks], acc1, 0, 0, 0);                              \
            acc2 = MFMA16(a, B2[ks], acc2, 0, 0, 0);                              \
            acc3 = MFMA16(a, B3[ks], acc3, 0, 0, 0);                              \
            acc4 = MFMA16(a, B4[ks], acc4, 0, 0, 0);                              \
            acc5 = MFMA16(a, B5[ks], acc5, 0, 0, 0);                              \
        }                                                                         \
        __builtin_amdgcn_s_setprio(0);                                            \
        {                                                                         \
            float ar = p ? acc1[0] : acc0[0];                                     \
            float az = p ? acc3[0] : acc2[0];                                     \
            float an = p ? acc5[0] : acc4[0];                                     \
            float rx = bf2f(rxu);                                                 \
            float zx = bf2f(zxu);                                                 \
            float nx = bf2f(nxu);                                                 \
            float r = sigf(rx + ar);                                              \
            float z = sigf(zx + az);                                              \
            float nn = tanhf_(nx + r * an);                                       \
            float h = (1.f - z) * nn + z * hp;                                    \
            hp = h;                                                               \
            unsigned pk;                                                          \
            asm("v_cvt_pk_bf16_f32 %0, %1, %2" : "=v"(pk) : "v"(h), "v"(h));      \
            hbf = (ushort)(pk & 0xffffu);                                         \
            *(ushort*)((char*)&hbuf[WB][0] + wofs) = hbf;                         \
        }                                                                         \
        __syncthreads();                                                          \
    }

    for (int t = 0; t < T; t += 2) {
        GSTEP(0, 1, t,     voB, voA)
        GSTEP(1, 0, t + 1, voA, voB)
    }
#undef GSTEP
    *(ushort*)((char*)outbase + voB) = hbf;   // epilogue: h(T-1)
}

// ---------------- MFMA M-GEMM: M[b,d,q] = dos[b,d,:] . qos[b,q,:]  (K=512, bf16 in) ----------------
__global__ __launch_bounds__(256) void k_mgemm(const ushort* __restrict__ dos, const ushort* __restrict__ qos,
                                               float* __restrict__ Mm) {
    __shared__ ushort Asl[64 * 512];   // 64 KB
    __shared__ ushort Bsl[64 * 512];   // 64 KB
    int tid = threadIdx.x;
    int b = blockIdx.y;
    int m0 = blockIdx.x * 64;
    int wv = tid >> 6;
    int lane = tid & 63;
    int l15 = lane & 15;
    int lhi = lane >> 4;

    // ---- stage dos tile + qos (bf16, swizzled chunks, no conversion) ----
    {
        int row = tid >> 2, kq = tid & 3;
        const ushort* ar = dos + ((long)b * DLEN + m0 + row) * 512 + kq * 128;
        const ushort* br = qos + ((long)b * QLEN + row) * 512 + kq * 128;
#pragma unroll
        for (int it = 0; it < 16; ++it) {
            int c = kq * 16 + it;
            int dst = row * 512 + ((c ^ (row & 7)) * 8);
            *(u16x8*)&Asl[dst] = *(const u16x8*)(ar + it * 8);
            *(u16x8*)&Bsl[dst] = *(const u16x8*)(br + it * 8);
        }
    }
    __syncthreads();

    f32x4 acc[4] = {};
#pragma unroll
    for (int ks = 0; ks < 16; ++ks) {
        int arow = wv * 16 + l15;
        bf16x8 a = *(const bf16x8*)&Asl[arow * 512 + (((ks * 4 + lhi) ^ (l15 & 7)) * 8)];
#pragma unroll
        for (int nt = 0; nt < 4; ++nt) {
            int brow = nt * 16 + l15;
            bf16x8 bv = *(const bf16x8*)&Bsl[brow * 512 + (((ks * 4 + lhi) ^ (l15 & 7)) * 8)];
            acc[nt] = MFMA16(a, bv, acc[nt], 0, 0, 0);
        }
    }

#pragma unroll
    for (int nt = 0; nt < 4; ++nt)
#pragma unroll
        for (int i = 0; i < 4; ++i) {
            long m = (long)b * DLEN + m0 + wv * 16 + lhi * 4 + i;
            Mm[m * QLEN + nt * 16 + l15] = acc[nt][i];
        }
}

// ---------------- fused attention epilogue: avgbeta + colstats -> s (LDS) -> final ----------------
__global__ __launch_bounds__(256) void k_aoa(const float* __restrict__ Mm, const float* __restrict__ dmask,
                                             const float* __restrict__ qmask, const int* __restrict__ dlens,
                                             const int* __restrict__ doc, const int* __restrict__ cand,
                                             const int* __restrict__ ans, float* __restrict__ out) {
    int b = blockIdx.x, tid = threadIdx.x;
    int lane = tid & 63, wid = tid >> 6;
    float qm = qmask[b * QLEN + lane];

    float accA = 0.f;
    float mrun = -INFINITY, srun = 0.f;
    for (int d = wid; d < DLEN; d += 4) {
        float x = Mm[((long)b * DLEN + d) * QLEN + lane];
        float dm = dmask[b * DLEN + d];
        float mx = x;
#pragma unroll
        for (int o = 32; o; o >>= 1) mx = fmaxf(mx, __shfl_xor(mx, o));
        float e = expf(x - mx) * dm * qm;
        float sm = e;
#pragma unroll
        for (int o = 32; o; o >>= 1) sm += __shfl_xor(sm, o);
        accA += e / (sm + 1e-12f);
        float mn = fmaxf(mrun, x);
        srun = srun * expf(mrun - mn) + expf(x - mn) * dm;
        mrun = mn;
    }
    __shared__ float redA[4][QLEN], mS[4][QLEN], sS[4][QLEN];
    __shared__ float wq[QLEN], mxs[QLEN];
    __shared__ float sL[DLEN];
    redA[wid][lane] = accA;
    mS[wid][lane] = mrun;
    sS[wid][lane] = srun;
    __syncthreads();
    if (tid < QLEN) {
        float M0 = fmaxf(fmaxf(mS[0][tid], mS[1][tid]), fmaxf(mS[2][tid], mS[3][tid]));
        float S = 0.f;
#pragma unroll
        for (int i = 0; i < 4; ++i) S += sS[i][tid] * expf(mS[i][tid] - M0);
        float avgbv = (redA[0][tid] + redA[1][tid] + redA[2][tid] + redA[3][tid]) / (float)dlens[b];
        wq[tid] = (qm > 0.f) ? (avgbv / (S + 1e-12f)) : 0.f;
        mxs[tid] = M0;
    }
    __syncthreads();

    for (int d = tid; d < DLEN; d += 256) {
        const float* row = Mm + ((long)b * DLEN + d) * QLEN;
        float acc = 0.f;
#pragma unroll
        for (int q = 0; q < QLEN; q += 4) {
            float4 v = *(const float4*)(row + q);
            acc += expf(v.x - mxs[q + 0]) * wq[q + 0];
            acc += expf(v.y - mxs[q + 1]) * wq[q + 1];
            acc += expf(v.z - mxs[q + 2]) * wq[q + 2];
            acc += expf(v.w - mxs[q + 3]) * wq[q + 3];
        }
        sL[d] = dmask[b * DLEN + d] * acc;
    }
    __syncthreads();

    __shared__ int lc[NCAND];
    __shared__ int la;
    __shared__ float red[4][NCAND + 1];
    if (tid < NCAND) lc[tid] = cand[b * NCAND + tid];
    if (tid == NCAND) la = ans[b];
    __syncthreads();
    float accs[NCAND + 1] = {};
    for (int d = tid; d < DLEN; d += 256) {
        int tk = doc[b * DLEN + d];
        float sv = sL[d];
#pragma unroll
        for (int c = 0; c < NCAND; ++c)
            if (tk == lc[c]) accs[c] += sv;
        if (tk == la) accs[NCAND] += sv;
    }
#pragma unroll
    for (int i = 0; i <= NCAND; ++i) {
        float v = accs[i];
#pragma unroll
        for (int o = 32; o; o >>= 1) v += __shfl_xor(v, o);
        if (lane == 0) red[wid][i] = v;
    }
    __syncthreads();
    if (tid == 0) {
        float cp[NCAND + 1];
#pragma unroll
        for (int i = 0; i <= NCAND; ++i) cp[i] = red[0][i] + red[1][i] + red[2][i] + red[3][i];
        int loc = 0; float best = cp[0];
#pragma unroll
        for (int c = 1; c < NCAND; ++c) if (cp[c] > best) { best = cp[c]; loc = c; }
        out[b] = (float)lc[loc];
        out[BATCH + b] = (float)loc;
        out[2 * BATCH + b] = cp[NCAND];
    }
}

__global__ void k_zero_out(float* out, int n) {
    int i = blockIdx.x * 256 + threadIdx.x;
    if (i < n) out[i] = 0.f;
}

extern "C" void kernel_launch(void* const* d_in, const int* in_sizes, int n_in,
                              void* d_out, int out_size, void* d_ws, size_t ws_size,
                              hipStream_t stream) {
    const int*   docs_input   = (const int*)d_in[0];
    const int*   docs_len     = (const int*)d_in[1];
    const float* doc_mask     = (const float*)d_in[2];
    const int*   querys_input = (const int*)d_in[3];
    const int*   querys_len   = (const int*)d_in[4];
    const float* query_mask   = (const float*)d_in[5];
    const int*   candidates   = (const int*)d_in[6];
    const int*   answers      = (const int*)d_in[7];
    const float* embedding    = (const float*)d_in[8];
    const float* w_ih_f = (const float*)d_in[9];
    const float* w_hh_f = (const float*)d_in[10];
    const float* b_ih_f = (const float*)d_in[11];
    const float* b_hh_f = (const float*)d_in[12];
    const float* w_ih_b = (const float*)d_in[13];
    const float* w_hh_b = (const float*)d_in[14];
    const float* b_ih_b = (const float*)d_in[15];
    const float* b_hh_b = (const float*)d_in[16];

    char* ws = (char*)d_ws;
    size_t off = 0;
    auto alloc = [&](size_t bytes) { size_t o = off; off = (off + bytes + 255) & ~(size_t)255; return o; };
    ushort* wprep = (ushort*)(ws + alloc((size_t)2 * 196608 * 2));
    float*  beff  = (float*)(ws + alloc((size_t)2 * G3 * 4));
    ushort* embB  = (ushort*)(ws + alloc((size_t)VOCAB * EMB * 2));
    ushort* wihB  = (ushort*)(ws + alloc((size_t)2 * G3 * EMB * 2));
    ushort* gxq_f = (ushort*)(ws + alloc((size_t)BATCH * QLEN * G3 * 2));
    ushort* gxq_b = (ushort*)(ws + alloc((size_t)BATCH * QLEN * G3 * 2));
    ushort* gxd_f = (ushort*)(ws + alloc((size_t)BATCH * DLEN * G3 * 2));
    ushort* gxd_b = (ushort*)(ws + alloc((size_t)BATCH * DLEN * G3 * 2));
    ushort* dosb  = (ushort*)(ws + alloc((size_t)BATCH * DLEN * 512 * 2));
    ushort* qosb  = (ushort*)(ws + alloc((size_t)BATCH * QLEN * 512 * 2));
    float* Mbuf   = (float*)(ws + alloc((size_t)BATCH * DLEN * QLEN * 4));

    if (ws_size < off) {
        k_zero_out<<<1, 256, 0, stream>>>((float*)d_out, out_size);
        return;
    }

    // fused one-time prep (bf16 conversions + bias folding + w_hh fragments)
    k_prep_all<<<(int)((PREP_TOTAL + 255) / 256), 256, 0, stream>>>(
        embedding, w_ih_f, w_ih_b, b_ih_f, b_hh_f, b_ih_b, b_hh_b, w_hh_f, w_hh_b,
        embB, wihB, beff, wprep);

    // gx for queries and docs, both directions (all-bf16 MFMA, natural coalesced out)
    k_gx<<<dim3(12, (BATCH * QLEN) / 64, 2), 256, 0, stream>>>(querys_input, embB,
        wihB, beff, gxq_f, wihB + (size_t)G3 * EMB, beff + G3, gxq_b);
    k_gx<<<dim3(12, (BATCH * DLEN) / 64, 2), 256, 0, stream>>>(docs_input, embB,
        wihB, beff, gxd_f, wihB + (size_t)G3 * EMB, beff + G3, gxd_b);

    // all four BiGRU scans (doc/query x fwd/bwd), batch split in pairs
    k_gru5<<<64, 512, 0, stream>>>(gxd_f, gxd_b, gxq_f, gxq_b, wprep,
                                   b_hh_f, b_hh_b, docs_len, querys_len, dosb, qosb);

    // attention-over-attention
    k_mgemm<<<dim3(DLEN / 64, BATCH), 256, 0, stream>>>(dosb, qosb, Mbuf);
    k_aoa<<<BATCH, 256, 0, stream>>>(Mbuf, doc_mask, query_mask, docs_len,
                                     docs_input, candidates, answers, (float*)d_out);
}